// Round 2
// baseline (5656.429 us; speedup 1.0000x reference)
//
#include <hip/hip_runtime.h>

typedef unsigned short u16;
typedef __attribute__((ext_vector_type(4))) float f32x4;
typedef __attribute__((ext_vector_type(8))) __bf16 bf16x8;
typedef __attribute__((ext_vector_type(4))) unsigned short u16x4;
typedef __attribute__((ext_vector_type(8))) unsigned short u16x8;

constexpr int kT = 1024, kD = 1024, kH = 16, kHD = 64, kL = 3, kE = 8;
constexpr int kFF = 4096, kV = 32000, kBT = 2048, kSLOTS = 5120;

__device__ __forceinline__ u16 f2bf(float f) {
  union { float f; unsigned u; } v; v.f = f;
  unsigned r = v.u + 0x7FFFu + ((v.u >> 16) & 1u);   // RNE
  return (u16)(r >> 16);
}

__device__ __forceinline__ void ld_lds16(const void* g, void* l) {
  __builtin_amdgcn_global_load_lds((const __attribute__((address_space(1))) void*)g,
                                   (__attribute__((address_space(3))) void*)l, 16, 0, 0);
}

#define MFMA16(a, b, c) __builtin_amdgcn_mfma_f32_16x16x32_bf16(a, b, c, 0, 0, 0)

__device__ __forceinline__ float blockReduceSum256(float v) {
  #pragma unroll
  for (int m = 32; m >= 1; m >>= 1) v += __shfl_xor(v, m);
  __shared__ float sh_[4];
  int w = threadIdx.x >> 6;
  if ((threadIdx.x & 63) == 0) sh_[w] = v;
  __syncthreads();
  v = (sh_[0] + sh_[1]) + (sh_[2] + sh_[3]);
  __syncthreads();
  return v;
}

// ---------------- elementwise / small kernels ----------------

__global__ __launch_bounds__(256) void cast_bf16_k(const float* __restrict__ in,
                                                   u16* __restrict__ out, long n4) {
  long i = (long)blockIdx.x * 256 + threadIdx.x;
  long stride = (long)gridDim.x * 256;
  for (; i < n4; i += stride) {
    f32x4 v = ((const f32x4*)in)[i];
    u16x4 o; o[0] = f2bf(v[0]); o[1] = f2bf(v[1]); o[2] = f2bf(v[2]); o[3] = f2bf(v[3]);
    ((u16x4*)out)[i] = o;
  }
}

__global__ __launch_bounds__(256) void embed_rms_k(const int* __restrict__ idx,
    const float* __restrict__ wte, const float* __restrict__ wpe, float* __restrict__ x) {
  int tok = blockIdx.x, t = threadIdx.x;
  int id = idx[tok];
  int tt = tok & (kT - 1);
  f32x4 a = ((const f32x4*)(wte + (long)id * kD))[t];
  f32x4 p = ((const f32x4*)(wpe + (long)tt * kD))[t];
  f32x4 vv = a + p;
  float ss = vv[0]*vv[0] + vv[1]*vv[1] + vv[2]*vv[2] + vv[3]*vv[3];
  ss = blockReduceSum256(ss);
  float sc = rsqrtf(ss * (1.0f / kD) + 1e-5f);
  vv *= sc;
  ((f32x4*)(x + (long)tok * kD))[t] = vv;
}

__global__ __launch_bounds__(256) void rmsnorm2_k(const float* __restrict__ x,
    float* __restrict__ xnf, u16* __restrict__ xnb) {
  int tok = blockIdx.x, t = threadIdx.x;
  f32x4 vv = ((const f32x4*)(x + (long)tok * kD))[t];
  float ss = blockReduceSum256(vv[0]*vv[0] + vv[1]*vv[1] + vv[2]*vv[2] + vv[3]*vv[3]);
  float sc = rsqrtf(ss * (1.0f / kD) + 1e-5f);
  vv *= sc;
  ((f32x4*)(xnf + (long)tok * kD))[t] = vv;
  u16x4 o;
  o[0] = f2bf(vv[0]); o[1] = f2bf(vv[1]); o[2] = f2bf(vv[2]); o[3] = f2bf(vv[3]);
  ((u16x4*)(xnb + (long)tok * kD))[t] = o;
}

// gating in f32 (bf16 would flip top-2 selections on near-ties)
__global__ __launch_bounds__(256) void gate_topk_k(const float* __restrict__ x,
    const float* __restrict__ gate_l, float* __restrict__ probs, int* __restrict__ top2e,
    float* __restrict__ top2w, int* __restrict__ counts) {
  int tok = blockIdx.x, t = threadIdx.x;
  f32x4 xv = ((const f32x4*)(x + (long)tok * kD))[t];
  float ss = blockReduceSum256(xv[0]*xv[0] + xv[1]*xv[1] + xv[2]*xv[2] + xv[3]*xv[3]);
  float sc = rsqrtf(ss * (1.0f / kD) + 1e-5f);
  float a[kE];
  #pragma unroll
  for (int e = 0; e < kE; ++e) {
    f32x4 gv = ((const f32x4*)(gate_l + (long)e * kD))[t];
    a[e] = xv[0]*gv[0] + xv[1]*gv[1] + xv[2]*gv[2] + xv[3]*gv[3];
  }
  __shared__ float sh8[kE][4];
  int w = t >> 6, l = t & 63;
  #pragma unroll
  for (int e = 0; e < kE; ++e) {
    float v = a[e];
    #pragma unroll
    for (int m = 32; m >= 1; m >>= 1) v += __shfl_xor(v, m);
    if (l == 0) sh8[e][w] = v;
  }
  __syncthreads();
  if (t == 0) {
    float lg[kE], mx = -1e30f;
    #pragma unroll
    for (int e = 0; e < kE; ++e) {
      lg[e] = (sh8[e][0] + sh8[e][1] + sh8[e][2] + sh8[e][3]) * sc;
      mx = fmaxf(mx, lg[e]);
    }
    float pe[kE], s = 0.f;
    #pragma unroll
    for (int e = 0; e < kE; ++e) { pe[e] = __expf(lg[e] - mx); s += pe[e]; }
    float inv = 1.f / s;
    int i1 = 0;
    #pragma unroll
    for (int e = 1; e < kE; ++e) if (lg[e] > lg[i1]) i1 = e;
    int i2 = (i1 == 0) ? 1 : 0;
    #pragma unroll
    for (int e = 0; e < kE; ++e) if (e != i1 && lg[e] > lg[i2]) i2 = e;
    #pragma unroll
    for (int e = 0; e < kE; ++e) probs[(long)tok * kE + e] = pe[e] * inv;
    float p1 = pe[i1] * inv, p2 = pe[i2] * inv;
    float wn = p1 + p2;
    top2e[tok*2] = i1; top2e[tok*2+1] = i2;
    top2w[tok*2] = p1 / wn; top2w[tok*2+1] = p2 / wn;
    atomicAdd(&counts[i1], 1); atomicAdd(&counts[i2], 1);
  }
}

__global__ void calc_offsets_k(const int* __restrict__ counts, int* __restrict__ offsets) {
  if (threadIdx.x == 0) {
    int o = 0;
    #pragma unroll
    for (int e = 0; e < kE; ++e) { offsets[e] = o; o += (counts[e] + 127) & ~127; }
    offsets[kE] = o;
  }
}

__global__ __launch_bounds__(256) void fill_slots_k(const int* __restrict__ top2e,
    const int* __restrict__ offsets, int* __restrict__ cursors,
    int* __restrict__ rows, int* __restrict__ slotOf) {
  int tok = blockIdx.x * 256 + threadIdx.x;
  if (tok >= kBT) return;
  #pragma unroll
  for (int j = 0; j < 2; ++j) {
    int e = top2e[tok*2 + j];
    int pos = atomicAdd(&cursors[e], 1);
    int slot = offsets[e] + pos;
    rows[slot] = tok;
    slotOf[tok*2 + j] = slot;
  }
}

__global__ __launch_bounds__(256) void moe_combine_k(float* __restrict__ x,
    const float* __restrict__ outs, const int* __restrict__ slotOf,
    const float* __restrict__ top2w) {
  int tok = blockIdx.x, t = threadIdx.x;
  int s0 = slotOf[tok*2], s1 = slotOf[tok*2+1];
  float w0 = top2w[tok*2], w1 = top2w[tok*2+1];
  f32x4 a = ((const f32x4*)(outs + (long)s0 * kD))[t];
  f32x4 b = ((const f32x4*)(outs + (long)s1 * kD))[t];
  f32x4 xv = ((f32x4*)(x + (long)tok * kD))[t];
  xv += a * w0 + b * w1;
  ((f32x4*)(x + (long)tok * kD))[t] = xv;
}

__global__ __launch_bounds__(256) void aux_reduce_k(const float* __restrict__ probs,
                                                    float* __restrict__ aux) {
  int t = threadIdx.x;
  float part[kE] = {};
  for (int i = t; i < kBT; i += 256) {
    #pragma unroll
    for (int e = 0; e < kE; ++e) part[e] += probs[(long)i * kE + e];
  }
  __shared__ float sh8[kE][4];
  int w = t >> 6, l = t & 63;
  #pragma unroll
  for (int e = 0; e < kE; ++e) {
    float v = part[e];
    #pragma unroll
    for (int m = 32; m >= 1; m >>= 1) v += __shfl_xor(v, m);
    if (l == 0) sh8[e][w] = v;
  }
  __syncthreads();
  if (t == 0) {
    float acc = 0.f;
    #pragma unroll
    for (int e = 0; e < kE; ++e) {
      float frac = (sh8[e][0] + sh8[e][1] + sh8[e][2] + sh8[e][3]) * (1.0f / kBT);
      acc += frac * frac;
    }
    aux[0] += (float)kE * acc;
  }
}

__global__ void write_aux_k(const float* __restrict__ aux, float* __restrict__ out) {
  if (threadIdx.x == 0) out[0] = 0.01f * aux[0] / (float)kL;
}

// ---------------- f32 SGEMM: C(MxN) = A(MxK) * B(NxK)^T ----------------
// 128x128 tile, BK=32, 256 threads, 8x8 micro-tile per thread.

enum { P_BF16 = 0, P_BF16_RELU = 1, P_F32 = 2, P_F32_RESID = 3, P_F32_RELU = 4 };

template <int POST, bool GATHER, bool EXPERT>
__global__ __launch_bounds__(256) void sgemm_bt_k(
    const float* __restrict__ A, const float* __restrict__ B, float* __restrict__ C,
    const float* __restrict__ resid, const int* __restrict__ rows,
    const int* __restrict__ offsets, int N, int K, int lda, long eBstride) {
  constexpr int BM = 128, BN = 128, BK = 32;
  int m0 = blockIdx.x * BM, n0 = blockIdx.y * BN;
  if (EXPERT) {
    int total = offsets[kE];
    if (m0 >= total) return;
    int e = 0;
    while (offsets[e + 1] <= m0) ++e;
    B += (long)e * eBstride;
  }
  __shared__ float Ast[BK][BM];
  __shared__ float Bst[BK][BN];
  int t = threadIdx.x, tx = t & 15, ty = t >> 4;
  long asrc[4], bsrc[4];
  #pragma unroll
  for (int it = 0; it < 4; ++it) {
    int c = it * 256 + t;
    int row = c >> 3, kc = (c & 7) * 4;
    int gr = GATHER ? rows[m0 + row] : (m0 + row);
    asrc[it] = (long)gr * lda + kc;
    bsrc[it] = (long)(n0 + row) * K + kc;
  }
  f32x4 accv[8][2];
  #pragma unroll
  for (int i = 0; i < 8; ++i) { accv[i][0] = 0.f; accv[i][1] = 0.f; }

  for (int k0 = 0; k0 < K; k0 += BK) {
    #pragma unroll
    for (int it = 0; it < 4; ++it) {
      int c = it * 256 + t;
      int row = c >> 3, kc = (c & 7) * 4;
      f32x4 av = *(const f32x4*)(A + asrc[it] + k0);
      f32x4 bv = *(const f32x4*)(B + bsrc[it] + k0);
      #pragma unroll
      for (int j = 0; j < 4; ++j) { Ast[kc + j][row] = av[j]; Bst[kc + j][row] = bv[j]; }
    }
    __syncthreads();
    #pragma unroll
    for (int kk = 0; kk < BK; ++kk) {
      f32x4 a0 = *(const f32x4*)&Ast[kk][ty * 4];
      f32x4 a1 = *(const f32x4*)&Ast[kk][64 + ty * 4];
      f32x4 b0 = *(const f32x4*)&Bst[kk][tx * 4];
      f32x4 b1 = *(const f32x4*)&Bst[kk][64 + tx * 4];
      float as[8] = {a0[0], a0[1], a0[2], a0[3], a1[0], a1[1], a1[2], a1[3]};
      #pragma unroll
      for (int i = 0; i < 8; ++i) {
        accv[i][0] += b0 * as[i];
        accv[i][1] += b1 * as[i];
      }
    }
    __syncthreads();
  }
  #pragma unroll
  for (int ih = 0; ih < 2; ++ih)
    #pragma unroll
    for (int i = 0; i < 4; ++i) {
      long m = m0 + ih * 64 + ty * 4 + i;
      #pragma unroll
      for (int jh = 0; jh < 2; ++jh) {
        long n = n0 + jh * 64 + tx * 4;
        f32x4 val = accv[ih * 4 + i][jh];
        if (POST == P_F32_RELU) {
          f32x4 z = {0.f, 0.f, 0.f, 0.f};
          #pragma unroll
          for (int j = 0; j < 4; ++j) val[j] = fmaxf(val[j], 0.f);
          (void)z;
        }
        if (POST == P_F32_RESID) val += *(const f32x4*)&resid[m * N + n];
        *(f32x4*)&C[m * N + n] = val;
      }
    }
}

// ---------------- f32 causal flash attention (HD=64, 64-row Q tile) ----------------

__global__ __launch_bounds__(256) void attn_f32_k(const float* __restrict__ q,
    const float* __restrict__ k, const float* __restrict__ v, float* __restrict__ o) {
  int qt = blockIdx.x;                 // q tile of 64
  int bh = blockIdx.y;                 // b*16+h
  int b = bh >> 4, h = bh & 15;
  long hb = (long)b * kT * kD + h * kHD;
  int t = threadIdx.x, qr = t >> 2, sub = t & 3;

  __shared__ float Qs[64][68], Ks[64][68], Vs[64][68], Ps[64][68];

  #pragma unroll
  for (int it = 0; it < 4; ++it) {
    int c = it * 256 + t, row = c >> 4, c4 = (c & 15) * 4;
    f32x4 qv = *(const f32x4*)(q + hb + (long)(qt * 64 + row) * kD + c4);
    #pragma unroll
    for (int j = 0; j < 4; ++j) Qs[row][c4 + j] = qv[j];
  }
  __syncthreads();
  f32x4 qreg[16];
  #pragma unroll
  for (int d4 = 0; d4 < 16; ++d4) qreg[d4] = *(const f32x4*)&Qs[qr][d4 * 4];
  int qg = qt * 64 + qr;

  float mrow = -1e30f, lsum = 0.f;
  f32x4 accO[4];
  #pragma unroll
  for (int i = 0; i < 4; ++i) accO[i] = 0.f;

  for (int itl = 0; itl <= qt; ++itl) {
    #pragma unroll
    for (int it = 0; it < 4; ++it) {
      int c = it * 256 + t, row = c >> 4, c4 = (c & 15) * 4;
      f32x4 kv = *(const f32x4*)(k + hb + (long)(itl * 64 + row) * kD + c4);
      f32x4 vv = *(const f32x4*)(v + hb + (long)(itl * 64 + row) * kD + c4);
      #pragma unroll
      for (int j = 0; j < 4; ++j) { Ks[row][c4 + j] = kv[j]; Vs[row][c4 + j] = vv[j]; }
    }
    __syncthreads();

    float s[16];
    #pragma unroll
    for (int kk = 0; kk < 16; ++kk) {
      int key = kk * 4 + sub;
      f32x4 a = {0.f, 0.f, 0.f, 0.f};
      #pragma unroll
      for (int d4 = 0; d4 < 16; ++d4) a += qreg[d4] * *(const f32x4*)&Ks[key][d4 * 4];
      float sv = (a[0] + a[1] + a[2] + a[3]) * 0.125f;
      if (itl * 64 + key > qg) sv = -1e30f;
      s[kk] = sv;
    }
    float mx = s[0];
    #pragma unroll
    for (int kk = 1; kk < 16; ++kk) mx = fmaxf(mx, s[kk]);
    mx = fmaxf(mx, __shfl_xor(mx, 1));
    mx = fmaxf(mx, __shfl_xor(mx, 2));
    float mi = fmaxf(mrow, mx);
    float alpha = __expf(mrow - mi);
    mrow = mi;
    float rs = 0.f;
    #pragma unroll
    for (int kk = 0; kk < 16; ++kk) {
      float p = __expf(s[kk] - mi);
      rs += p;
      Ps[qr][kk * 4 + sub] = p;
    }
    rs += __shfl_xor(rs, 1);
    rs += __shfl_xor(rs, 2);
    lsum = lsum * alpha + rs;
    #pragma unroll
    for (int i = 0; i < 4; ++i) accO[i] *= alpha;
    #pragma unroll
    for (int key2 = 0; key2 < 64; ++key2) {
      float p = Ps[qr][key2];
      #pragma unroll
      for (int i4 = 0; i4 < 4; ++i4)
        accO[i4] += p * *(const f32x4*)&Vs[key2][sub * 16 + i4 * 4];
    }
    __syncthreads();
  }
  float inv = 1.f / lsum;
  #pragma unroll
  for (int i4 = 0; i4 < 4; ++i4) {
    f32x4 ov = accO[i4] * inv;
    *(f32x4*)(o + hb + (long)qg * kD + sub * 16 + i4 * 4) = ov;
  }
}

// ---------------- bf16 MFMA GEMM (post-routing only): C = A(bf16) * B(NxK f32->bf16)^T ----

template <int POST, bool EXPERT, bool GATHER>
__global__ __launch_bounds__(256) void gemm_bt_k(
    const u16* __restrict__ A, const float* __restrict__ Bf, void* __restrict__ C,
    const int* __restrict__ rows, const int* __restrict__ offsets,
    int N, int K, int lda, long eBstride) {
  constexpr int BM = 128, BK = 64;
  int m0 = blockIdx.x * BM;
  int n0 = blockIdx.y * BM;
  if (EXPERT) {
    int total = offsets[kE];
    if (m0 >= total) return;
    int e = 0;
    while (offsets[e + 1] <= m0) ++e;
    Bf += (long)e * eBstride;
  }
  __shared__ __align__(16) u16 As[BM][BK];
  __shared__ __align__(16) u16 Bs[BM][BK + 8];
  int t = threadIdx.x;
  int l = t & 63, lr = l & 15, lg = l >> 4;
  int wid = t >> 6;
  int wm = (wid >> 1) * 64, wn = (wid & 1) * 64;

  long asrc[4];
  #pragma unroll
  for (int it = 0; it < 4; ++it) {
    int c = it * 256 + t;
    int row = c >> 3, col = (c & 7) * 8;
    int grow = GATHER ? rows[m0 + row] : (m0 + row);
    asrc[it] = (long)grow * lda + col;
  }
  f32x4 acc[4][4];
  #pragma unroll
  for (int i = 0; i < 4; ++i)
    #pragma unroll
    for (int j = 0; j < 4; ++j) acc[i][j] = 0.f;

  for (int k0 = 0; k0 < K; k0 += BK) {
    #pragma unroll
    for (int it = 0; it < 4; ++it)
      ld_lds16(A + asrc[it] + k0, &As[0][0] + (it * 256 + (t & ~63)) * 8);
    #pragma unroll
    for (int it = 0; it < 8; ++it) {
      int c = it * 256 + t;
      int row = c >> 4, col = (c & 15) * 4;
      f32x4 v = *(const f32x4*)(Bf + (long)(n0 + row) * K + k0 + col);
      u16x4 o; o[0] = f2bf(v[0]); o[1] = f2bf(v[1]); o[2] = f2bf(v[2]); o[3] = f2bf(v[3]);
      *(u16x4*)&Bs[row][col] = o;
    }
    __syncthreads();
    #pragma unroll
    for (int kk = 0; kk < 2; ++kk) {
      int kc = kk * 32 + lg * 8;
      bf16x8 af[4], bq[4];
      #pragma unroll
      for (int i = 0; i < 4; ++i) af[i] = *(const bf16x8*)&As[wm + i*16 + lr][kc];
      #pragma unroll
      for (int j = 0; j < 4; ++j) bq[j] = *(const bf16x8*)&Bs[wn + j*16 + lr][kc];
      #pragma unroll
      for (int i = 0; i < 4; ++i)
        #pragma unroll
        for (int j = 0; j < 4; ++j)
          acc[i][j] = MFMA16(af[i], bq[j], acc[i][j]);
    }
    __syncthreads();
  }
  #pragma unroll
  for (int i = 0; i < 4; ++i) {
    #pragma unroll
    for (int r = 0; r < 4; ++r) {
      long m = m0 + wm + i*16 + lg*4 + r;
      #pragma unroll
      for (int j = 0; j < 4; ++j) {
        int n = n0 + wn + j*16 + lr;
        float val = acc[i][j][r];
        if (POST == P_BF16_RELU)       ((u16*)C)[m * N + n] = f2bf(fmaxf(val, 0.f));
        else if (POST == P_F32)        ((float*)C)[m * N + n] = val;
      }
    }
  }
}

// ---------------- host ----------------

extern "C" void kernel_launch(void* const* d_in, const int* in_sizes, int n_in,
                              void* d_out, int out_size, void* d_ws, size_t ws_size,
                              hipStream_t stream) {
  const int*   idx  = (const int*)  d_in[0];
  const float* wte  = (const float*)d_in[1];
  const float* wpe  = (const float*)d_in[2];
  const float* wq   = (const float*)d_in[3];
  const float* wk   = (const float*)d_in[4];
  const float* wv   = (const float*)d_in[5];
  const float* wo   = (const float*)d_in[6];
  const float* gate = (const float*)d_in[7];
  const float* f1   = (const float*)d_in[8];
  const float* f2   = (const float*)d_in[9];
  const float* lmh  = (const float*)d_in[10];
  float* out = (float*)d_out;

  char* ws = (char*)d_ws;
  size_t off = 0;
  auto alloc = [&](size_t b) -> char* {
    char* p = ws + off;
    off += (b + 255) & ~(size_t)255;
    return p;
  };
  float* x     = (float*)alloc((size_t)kBT * kD * 4);
  float* xnf   = (float*)alloc((size_t)kBT * kD * 4);
  u16*   xnb   = (u16*)  alloc((size_t)kBT * kD * 2);
  float* qf    = (float*)alloc((size_t)kBT * kD * 4);
  float* kf    = (float*)alloc((size_t)kBT * kD * 4);
  float* vf    = (float*)alloc((size_t)kBT * kD * 4);
  float* of    = (float*)alloc((size_t)kBT * kD * 4);
  float* hbuf  = (float*)alloc((size_t)kSLOTS * kFF * 4);   // f32 for L0/L1; u16 alias for L2
  float* outs  = (float*)alloc((size_t)kSLOTS * kD * 4);
  float* probs = (float*)alloc((size_t)kBT * kE * 4);
  int*   top2e = (int*)  alloc((size_t)kBT * 2 * 4);
  float* top2w = (float*)alloc((size_t)kBT * 2 * 4);
  int*   meta  = (int*)  alloc(64 * 4);
  int* counts = meta; int* cursors = meta + 8; int* offs = meta + 16;
  int*   rows  = (int*)  alloc((size_t)kSLOTS * 4);
  int*   slotOf= (int*)  alloc((size_t)kBT * 2 * 4);
  float* aux   = (float*)alloc(256);
  u16* hbuf16 = (u16*)hbuf;

  hipMemsetAsync(aux, 0, 4, stream);
  embed_rms_k<<<kBT, 256, 0, stream>>>(idx, wte, wpe, x);

  dim3 gProj(kBT / 128, kD / 128);     // (16,8)
  dim3 gAttn(kT / 64, 2 * kH);         // (16,32)
  dim3 gF1(kSLOTS / 128, kFF / 128);   // (40,32)
  dim3 gF2(kSLOTS / 128, kD / 128);    // (40,8)
  dim3 gLM(kBT / 128, kV / 128);       // (16,250)

  for (int li = 0; li < kL; ++li) {
    size_t dd = (size_t)li * kD * kD;
    rmsnorm2_k<<<kBT, 256, 0, stream>>>(x, xnf, xnb);
    sgemm_bt_k<P_F32, false, false><<<gProj, 256, 0, stream>>>(
        xnf, wq + dd, qf, nullptr, nullptr, nullptr, kD, kD, kD, 0);
    sgemm_bt_k<P_F32, false, false><<<gProj, 256, 0, stream>>>(
        xnf, wk + dd, kf, nullptr, nullptr, nullptr, kD, kD, kD, 0);
    sgemm_bt_k<P_F32, false, false><<<gProj, 256, 0, stream>>>(
        xnf, wv + dd, vf, nullptr, nullptr, nullptr, kD, kD, kD, 0);
    attn_f32_k<<<gAttn, 256, 0, stream>>>(qf, kf, vf, of);
    sgemm_bt_k<P_F32_RESID, false, false><<<gProj, 256, 0, stream>>>(
        of, wo + dd, x, x, nullptr, nullptr, kD, kD, kD, 0);
    rmsnorm2_k<<<kBT, 256, 0, stream>>>(x, xnf, xnb);
    hipMemsetAsync(meta, 0, 64, stream);                 // counts + cursors
    gate_topk_k<<<kBT, 256, 0, stream>>>(x, gate + (size_t)li * kE * kD,
                                         probs, top2e, top2w, counts);
    calc_offsets_k<<<1, 64, 0, stream>>>(counts, offs);
    hipMemsetAsync(rows, 0, (size_t)kSLOTS * 4, stream); // pad slots -> token 0
    fill_slots_k<<<kBT / 256, 256, 0, stream>>>(top2e, offs, cursors, rows, slotOf);
    size_t fd = (size_t)li * kE * kFF * kD;
    if (li < 2) {
      // f32 MoE (feeds the next layer's routing decision)
      sgemm_bt_k<P_F32_RELU, true, true><<<gF1, 256, 0, stream>>>(
          xnf, f1 + fd, hbuf, nullptr, rows, offs, kFF, kD, kD, (long)kFF * kD);
      sgemm_bt_k<P_F32, false, true><<<gF2, 256, 0, stream>>>(
          hbuf, f2 + fd, outs, nullptr, nullptr, offs, kD, kFF, kFF, (long)kD * kFF);
    } else {
      // last layer: nothing downstream is routing-sensitive -> bf16 MFMA
      gemm_bt_k<P_BF16_RELU, true, true><<<gF1, 256, 0, stream>>>(
          xnb, f1 + fd, hbuf16, rows, offs, kFF, kD, kD, (long)kFF * kD);
      gemm_bt_k<P_F32, true, false><<<gF2, 256, 0, stream>>>(
          hbuf16, f2 + fd, outs, nullptr, offs, kD, kFF, kFF, (long)kD * kFF);
    }
    moe_combine_k<<<kBT, 256, 0, stream>>>(x, outs, slotOf, top2w);
    aux_reduce_k<<<1, 256, 0, stream>>>(probs, aux);
  }
  cast_bf16_k<<<2048, 256, 0, stream>>>(x, xnb, (long)kBT * kD / 4);
  gemm_bt_k<P_F32, false, false><<<gLM, 256, 0, stream>>>(
      xnb, lmh, out, nullptr, nullptr, kV, kD, kD, 0);
  write_aux_k<<<1, 64, 0, stream>>>(aux, out + (size_t)kBT * kV);
}

// Round 4
// 4404.346 us; speedup vs baseline: 1.2843x; 1.2843x over previous
//
#include <hip/hip_runtime.h>

typedef unsigned short u16;
typedef __attribute__((ext_vector_type(4))) float f32x4;
typedef __attribute__((ext_vector_type(8))) __bf16 bf16x8;
typedef __attribute__((ext_vector_type(4))) unsigned short u16x4;
typedef __attribute__((ext_vector_type(8))) unsigned short u16x8;

constexpr int kT = 1024, kD = 1024, kH = 16, kHD = 64, kL = 3, kE = 8;
constexpr int kFF = 4096, kV = 32000, kBT = 2048, kSLOTS = 5120;

__device__ __forceinline__ u16 f2bf(float f) {
  union { float f; unsigned u; } v; v.f = f;
  unsigned r = v.u + 0x7FFFu + ((v.u >> 16) & 1u);   // RNE
  return (u16)(r >> 16);
}
__device__ __forceinline__ float bf2f(u16 h) {
  union { unsigned u; float f; } v; v.u = ((unsigned)h) << 16; return v.f;
}
// 3-way bf16 split: x = hi + mid + lo + r, |r| <= ~2^-24 |x|
__device__ __forceinline__ void split3(float x, u16& h, u16& m, u16& l) {
  h = f2bf(x); float r1 = x - bf2f(h);
  m = f2bf(r1); float r2 = r1 - bf2f(m);
  l = f2bf(r2);
}

__device__ __forceinline__ void ld_lds16(const void* g, void* l) {
  __builtin_amdgcn_global_load_lds((const __attribute__((address_space(1))) void*)g,
                                   (__attribute__((address_space(3))) void*)l, 16, 0, 0);
}

#define MFMA16(a, b, c) __builtin_amdgcn_mfma_f32_16x16x32_bf16(a, b, c, 0, 0, 0)

__device__ __forceinline__ float blockReduceSum256(float v) {
  #pragma unroll
  for (int m = 32; m >= 1; m >>= 1) v += __shfl_xor(v, m);
  __shared__ float sh_[4];
  int w = threadIdx.x >> 6;
  if ((threadIdx.x & 63) == 0) sh_[w] = v;
  __syncthreads();
  v = (sh_[0] + sh_[1]) + (sh_[2] + sh_[3]);
  __syncthreads();
  return v;
}

// ---------------- elementwise / small kernels ----------------

__global__ __launch_bounds__(256) void cast_bf16_k(const float* __restrict__ in,
                                                   u16* __restrict__ out, long n4) {
  long i = (long)blockIdx.x * 256 + threadIdx.x;
  long stride = (long)gridDim.x * 256;
  for (; i < n4; i += stride) {
    f32x4 v = ((const f32x4*)in)[i];
    u16x4 o; o[0] = f2bf(v[0]); o[1] = f2bf(v[1]); o[2] = f2bf(v[2]); o[3] = f2bf(v[3]);
    ((u16x4*)out)[i] = o;
  }
}

// f32 -> 3 bf16 planes (planeStride elements apart)
__global__ __launch_bounds__(256) void split3_k(const float* __restrict__ in,
    u16* __restrict__ out, long planeStride, long n4) {
  long i = (long)blockIdx.x * 256 + threadIdx.x;
  long stride = (long)gridDim.x * 256;
  u16* o1 = out + planeStride; u16* o2 = out + 2 * planeStride;
  for (; i < n4; i += stride) {
    f32x4 v = ((const f32x4*)in)[i];
    u16x4 a, b, c;
    #pragma unroll
    for (int j = 0; j < 4; ++j) {
      u16 h, m, l; split3(v[j], h, m, l);
      a[j] = h; b[j] = m; c[j] = l;
    }
    ((u16x4*)out)[i] = a; ((u16x4*)o1)[i] = b; ((u16x4*)o2)[i] = c;
  }
}

__global__ __launch_bounds__(256) void embed_rms_k(const int* __restrict__ idx,
    const float* __restrict__ wte, const float* __restrict__ wpe, float* __restrict__ x) {
  int tok = blockIdx.x, t = threadIdx.x;
  int id = idx[tok];
  int tt = tok & (kT - 1);
  f32x4 a = ((const f32x4*)(wte + (long)id * kD))[t];
  f32x4 p = ((const f32x4*)(wpe + (long)tt * kD))[t];
  f32x4 vv = a + p;
  float ss = vv[0]*vv[0] + vv[1]*vv[1] + vv[2]*vv[2] + vv[3]*vv[3];
  ss = blockReduceSum256(ss);
  float sc = rsqrtf(ss * (1.0f / kD) + 1e-5f);
  vv *= sc;
  ((f32x4*)(x + (long)tok * kD))[t] = vv;
}

// rmsnorm -> f32 + bf16 (fallback path)
__global__ __launch_bounds__(256) void rmsnorm2_k(const float* __restrict__ x,
    float* __restrict__ xnf, u16* __restrict__ xnb) {
  int tok = blockIdx.x, t = threadIdx.x;
  f32x4 vv = ((const f32x4*)(x + (long)tok * kD))[t];
  float ss = blockReduceSum256(vv[0]*vv[0] + vv[1]*vv[1] + vv[2]*vv[2] + vv[3]*vv[3]);
  float sc = rsqrtf(ss * (1.0f / kD) + 1e-5f);
  vv *= sc;
  ((f32x4*)(xnf + (long)tok * kD))[t] = vv;
  u16x4 o;
  o[0] = f2bf(vv[0]); o[1] = f2bf(vv[1]); o[2] = f2bf(vv[2]); o[3] = f2bf(vv[3]);
  ((u16x4*)(xnb + (long)tok * kD))[t] = o;
}

// rmsnorm -> 3 bf16 planes (fast path)
__global__ __launch_bounds__(256) void rmsnorm3_k(const float* __restrict__ x,
    u16* __restrict__ xnP, long plane) {
  int tok = blockIdx.x, t = threadIdx.x;
  f32x4 vv = ((const f32x4*)(x + (long)tok * kD))[t];
  float ss = blockReduceSum256(vv[0]*vv[0] + vv[1]*vv[1] + vv[2]*vv[2] + vv[3]*vv[3]);
  float sc = rsqrtf(ss * (1.0f / kD) + 1e-5f);
  vv *= sc;
  u16x4 a, b, c;
  #pragma unroll
  for (int j = 0; j < 4; ++j) {
    u16 h, m, l; split3(vv[j], h, m, l);
    a[j] = h; b[j] = m; c[j] = l;
  }
  long o = (long)tok * kD / 4 + t;
  ((u16x4*)xnP)[o] = a;
  ((u16x4*)(xnP + plane))[o] = b;
  ((u16x4*)(xnP + 2 * plane))[o] = c;
}

// gating in f32 (bf16 would flip top-2 selections on near-ties)
__global__ __launch_bounds__(256) void gate_topk_k(const float* __restrict__ x,
    const float* __restrict__ gate_l, float* __restrict__ probs, int* __restrict__ top2e,
    float* __restrict__ top2w, int* __restrict__ counts) {
  int tok = blockIdx.x, t = threadIdx.x;
  f32x4 xv = ((const f32x4*)(x + (long)tok * kD))[t];
  float ss = blockReduceSum256(xv[0]*xv[0] + xv[1]*xv[1] + xv[2]*xv[2] + xv[3]*xv[3]);
  float sc = rsqrtf(ss * (1.0f / kD) + 1e-5f);
  float a[kE];
  #pragma unroll
  for (int e = 0; e < kE; ++e) {
    f32x4 gv = ((const f32x4*)(gate_l + (long)e * kD))[t];
    a[e] = xv[0]*gv[0] + xv[1]*gv[1] + xv[2]*gv[2] + xv[3]*gv[3];
  }
  __shared__ float sh8[kE][4];
  int w = t >> 6, l = t & 63;
  #pragma unroll
  for (int e = 0; e < kE; ++e) {
    float v = a[e];
    #pragma unroll
    for (int m = 32; m >= 1; m >>= 1) v += __shfl_xor(v, m);
    if (l == 0) sh8[e][w] = v;
  }
  __syncthreads();
  if (t == 0) {
    float lg[kE], mx = -1e30f;
    #pragma unroll
    for (int e = 0; e < kE; ++e) {
      lg[e] = (sh8[e][0] + sh8[e][1] + sh8[e][2] + sh8[e][3]) * sc;
      mx = fmaxf(mx, lg[e]);
    }
    float pe[kE], s = 0.f;
    #pragma unroll
    for (int e = 0; e < kE; ++e) { pe[e] = __expf(lg[e] - mx); s += pe[e]; }
    float inv = 1.f / s;
    int i1 = 0;
    #pragma unroll
    for (int e = 1; e < kE; ++e) if (lg[e] > lg[i1]) i1 = e;
    int i2 = (i1 == 0) ? 1 : 0;
    #pragma unroll
    for (int e = 0; e < kE; ++e) if (e != i1 && lg[e] > lg[i2]) i2 = e;
    #pragma unroll
    for (int e = 0; e < kE; ++e) probs[(long)tok * kE + e] = pe[e] * inv;
    float p1 = pe[i1] * inv, p2 = pe[i2] * inv;
    float wn = p1 + p2;
    top2e[tok*2] = i1; top2e[tok*2+1] = i2;
    top2w[tok*2] = p1 / wn; top2w[tok*2+1] = p2 / wn;
    atomicAdd(&counts[i1], 1); atomicAdd(&counts[i2], 1);
  }
}

__global__ void calc_offsets_k(const int* __restrict__ counts, int* __restrict__ offsets) {
  if (threadIdx.x == 0) {
    int o = 0;
    #pragma unroll
    for (int e = 0; e < kE; ++e) { offsets[e] = o; o += (counts[e] + 127) & ~127; }
    offsets[kE] = o;
  }
}

__global__ __launch_bounds__(256) void fill_slots_k(const int* __restrict__ top2e,
    const int* __restrict__ offsets, int* __restrict__ cursors,
    int* __restrict__ rows, int* __restrict__ slotOf) {
  int tok = blockIdx.x * 256 + threadIdx.x;
  if (tok >= kBT) return;
  #pragma unroll
  for (int j = 0; j < 2; ++j) {
    int e = top2e[tok*2 + j];
    int pos = atomicAdd(&cursors[e], 1);
    int slot = offsets[e] + pos;
    rows[slot] = tok;
    slotOf[tok*2 + j] = slot;
  }
}

__global__ __launch_bounds__(256) void moe_combine_k(float* __restrict__ x,
    const float* __restrict__ outs, const int* __restrict__ slotOf,
    const float* __restrict__ top2w) {
  int tok = blockIdx.x, t = threadIdx.x;
  int s0 = slotOf[tok*2], s1 = slotOf[tok*2+1];
  float w0 = top2w[tok*2], w1 = top2w[tok*2+1];
  f32x4 a = ((const f32x4*)(outs + (long)s0 * kD))[t];
  f32x4 b = ((const f32x4*)(outs + (long)s1 * kD))[t];
  f32x4 xv = ((f32x4*)(x + (long)tok * kD))[t];
  xv += a * w0 + b * w1;
  ((f32x4*)(x + (long)tok * kD))[t] = xv;
}

__global__ __launch_bounds__(256) void aux_reduce_k(const float* __restrict__ probs,
                                                    float* __restrict__ aux) {
  int t = threadIdx.x;
  float part[kE] = {};
  for (int i = t; i < kBT; i += 256) {
    #pragma unroll
    for (int e = 0; e < kE; ++e) part[e] += probs[(long)i * kE + e];
  }
  __shared__ float sh8[kE][4];
  int w = t >> 6, l = t & 63;
  #pragma unroll
  for (int e = 0; e < kE; ++e) {
    float v = part[e];
    #pragma unroll
    for (int m = 32; m >= 1; m >>= 1) v += __shfl_xor(v, m);
    if (l == 0) sh8[e][w] = v;
  }
  __syncthreads();
  if (t == 0) {
    float acc = 0.f;
    #pragma unroll
    for (int e = 0; e < kE; ++e) {
      float frac = (sh8[e][0] + sh8[e][1] + sh8[e][2] + sh8[e][3]) * (1.0f / kBT);
      acc += frac * frac;
    }
    aux[0] += (float)kE * acc;
  }
}

__global__ void write_aux_k(const float* __restrict__ aux, float* __restrict__ out) {
  if (threadIdx.x == 0) out[0] = 0.01f * aux[0] / (float)kL;
}

enum { P_BF16 = 0, P_BF16_RELU = 1, P_F32 = 2, P_F32_RESID = 3, P_F32_RELU = 4,
       P_SPLIT3_RELU = 5 };

// ---------------- split-3 MFMA GEMM: C = sum_s A_pa[s] * B_pb[s]^T ----------------
// f32-equivalent accuracy via 6 bf16 plane products. 128x128 tile, BK=64, 4 waves.

template <int POST, bool GATHER, bool EXPERT>
__global__ __launch_bounds__(256) void gemm3_bt_k(
    const u16* __restrict__ A0, long planeA,
    const u16* __restrict__ B0, long planeB,
    void* __restrict__ C, long planeC,
    const float* __restrict__ resid,
    const int* __restrict__ rows, const int* __restrict__ offsets,
    int N, int K, int lda, long eBstride) {
  constexpr int BM = 128, BK = 64;
  int m0 = blockIdx.x * BM;
  int n0 = blockIdx.y * BM;
  if (EXPERT) {
    int total = offsets[kE];
    if (m0 >= total) return;
    int e = 0;
    while (offsets[e + 1] <= m0) ++e;
    B0 += (long)e * eBstride;
  }
  __shared__ __align__(16) u16 As[BM][BK];
  __shared__ __align__(16) u16 Bs[BM][BK];
  int t = threadIdx.x;
  int l = t & 63, lr = l & 15, lg = l >> 4;
  int wid = t >> 6;
  int wm = (wid >> 1) * 64, wn = (wid & 1) * 64;

  long asrc[4], bsrc[4];
  #pragma unroll
  for (int it = 0; it < 4; ++it) {
    int c = it * 256 + t;
    int row = c >> 3, col = (c & 7) * 8;
    int grow = GATHER ? rows[m0 + row] : (m0 + row);
    asrc[it] = (long)grow * lda + col;
    bsrc[it] = (long)(n0 + row) * K + col;
  }
  f32x4 acc[4][4];
  #pragma unroll
  for (int i = 0; i < 4; ++i)
    #pragma unroll
    for (int j = 0; j < 4; ++j) acc[i][j] = 0.f;

  const int pa[6] = {0, 0, 1, 0, 2, 1};
  const int pb[6] = {0, 1, 0, 2, 0, 1};
  #pragma unroll 1
  for (int s = 0; s < 6; ++s) {
    const u16* Ab = A0 + (long)pa[s] * planeA;
    const u16* Bb = B0 + (long)pb[s] * planeB;
    for (int k0 = 0; k0 < K; k0 += BK) {
      #pragma unroll
      for (int it = 0; it < 4; ++it) {
        ld_lds16(Ab + asrc[it] + k0, &As[0][0] + (it * 256 + (t & ~63)) * 8);
        ld_lds16(Bb + bsrc[it] + k0, &Bs[0][0] + (it * 256 + (t & ~63)) * 8);
      }
      __syncthreads();
      #pragma unroll
      for (int kk = 0; kk < 2; ++kk) {
        int kc = kk * 32 + lg * 8;
        bf16x8 af[4], bq[4];
        #pragma unroll
        for (int i = 0; i < 4; ++i) af[i] = *(const bf16x8*)&As[wm + i*16 + lr][kc];
        #pragma unroll
        for (int j = 0; j < 4; ++j) bq[j] = *(const bf16x8*)&Bs[wn + j*16 + lr][kc];
        #pragma unroll
        for (int i = 0; i < 4; ++i)
          #pragma unroll
          for (int j = 0; j < 4; ++j)
            acc[i][j] = MFMA16(af[i], bq[j], acc[i][j]);
      }
      __syncthreads();
    }
  }
  #pragma unroll
  for (int i = 0; i < 4; ++i) {
    #pragma unroll
    for (int r = 0; r < 4; ++r) {
      long m = m0 + wm + i*16 + lg*4 + r;
      #pragma unroll
      for (int j = 0; j < 4; ++j) {
        int n = n0 + wn + j*16 + lr;
        float val = acc[i][j][r];
        if (POST == P_F32) {
          ((float*)C)[m * N + n] = val;
        } else if (POST == P_F32_RESID) {
          ((float*)C)[m * N + n] = val + resid[m * N + n];
        } else if (POST == P_SPLIT3_RELU) {
          val = fmaxf(val, 0.f);
          u16 h, mm, lo; split3(val, h, mm, lo);
          u16* Cp = (u16*)C;
          Cp[m * N + n] = h;
          Cp[planeC + m * N + n] = mm;
          Cp[2 * planeC + m * N + n] = lo;
        }
      }
    }
  }
}

// ---------------- single-bf16 MFMA GEMM (post-routing): B is f32, converted in staging ----

template <int POST, bool EXPERT, bool GATHER>
__global__ __launch_bounds__(256) void gemm_bt_k(
    const u16* __restrict__ A, const float* __restrict__ Bf, void* __restrict__ C,
    const int* __restrict__ rows, const int* __restrict__ offsets,
    int N, int K, int lda, long eBstride) {
  constexpr int BM = 128, BK = 64;
  int m0 = blockIdx.x * BM;
  int n0 = blockIdx.y * BM;
  if (EXPERT) {
    int total = offsets[kE];
    if (m0 >= total) return;
    int e = 0;
    while (offsets[e + 1] <= m0) ++e;
    Bf += (long)e * eBstride;
  }
  __shared__ __align__(16) u16 As[BM][BK];
  __shared__ __align__(16) u16 Bs[BM][BK + 8];
  int t = threadIdx.x;
  int l = t & 63, lr = l & 15, lg = l >> 4;
  int wid = t >> 6;
  int wm = (wid >> 1) * 64, wn = (wid & 1) * 64;

  long asrc[4];
  #pragma unroll
  for (int it = 0; it < 4; ++it) {
    int c = it * 256 + t;
    int row = c >> 3, col = (c & 7) * 8;
    int grow = GATHER ? rows[m0 + row] : (m0 + row);
    asrc[it] = (long)grow * lda + col;
  }
  f32x4 acc[4][4];
  #pragma unroll
  for (int i = 0; i < 4; ++i)
    #pragma unroll
    for (int j = 0; j < 4; ++j) acc[i][j] = 0.f;

  for (int k0 = 0; k0 < K; k0 += BK) {
    #pragma unroll
    for (int it = 0; it < 4; ++it)
      ld_lds16(A + asrc[it] + k0, &As[0][0] + (it * 256 + (t & ~63)) * 8);
    #pragma unroll
    for (int it = 0; it < 8; ++it) {
      int c = it * 256 + t;
      int row = c >> 4, col = (c & 15) * 4;
      f32x4 v = *(const f32x4*)(Bf + (long)(n0 + row) * K + k0 + col);
      u16x4 o; o[0] = f2bf(v[0]); o[1] = f2bf(v[1]); o[2] = f2bf(v[2]); o[3] = f2bf(v[3]);
      *(u16x4*)&Bs[row][col] = o;
    }
    __syncthreads();
    #pragma unroll
    for (int kk = 0; kk < 2; ++kk) {
      int kc = kk * 32 + lg * 8;
      bf16x8 af[4], bq[4];
      #pragma unroll
      for (int i = 0; i < 4; ++i) af[i] = *(const bf16x8*)&As[wm + i*16 + lr][kc];
      #pragma unroll
      for (int j = 0; j < 4; ++j) bq[j] = *(const bf16x8*)&Bs[wn + j*16 + lr][kc];
      #pragma unroll
      for (int i = 0; i < 4; ++i)
        #pragma unroll
        for (int j = 0; j < 4; ++j)
          acc[i][j] = MFMA16(af[i], bq[j], acc[i][j]);
    }
    __syncthreads();
  }
  #pragma unroll
  for (int i = 0; i < 4; ++i) {
    #pragma unroll
    for (int r = 0; r < 4; ++r) {
      long m = m0 + wm + i*16 + lg*4 + r;
      #pragma unroll
      for (int j = 0; j < 4; ++j) {
        int n = n0 + wn + j*16 + lr;
        float val = acc[i][j][r];
        if (POST == P_BF16_RELU)       ((u16*)C)[m * N + n] = f2bf(fmaxf(val, 0.f));
        else if (POST == P_F32)        ((float*)C)[m * N + n] = val;
      }
    }
  }
}

// ---------------- f32 SGEMM (fallback path only) ----------------

template <int POST, bool GATHER, bool EXPERT>
__global__ __launch_bounds__(256) void sgemm_bt_k(
    const float* __restrict__ A, const float* __restrict__ B, float* __restrict__ C,
    const float* __restrict__ resid, const int* __restrict__ rows,
    const int* __restrict__ offsets, int N, int K, int lda, long eBstride) {
  constexpr int BM = 128, BN = 128, BK = 32;
  int m0 = blockIdx.x * BM, n0 = blockIdx.y * BN;
  if (EXPERT) {
    int total = offsets[kE];
    if (m0 >= total) return;
    int e = 0;
    while (offsets[e + 1] <= m0) ++e;
    B += (long)e * eBstride;
  }
  __shared__ float Ast[BK][BM];
  __shared__ float Bst[BK][BN];
  int t = threadIdx.x, tx = t & 15, ty = t >> 4;
  long asrc[4], bsrc[4];
  #pragma unroll
  for (int it = 0; it < 4; ++it) {
    int c = it * 256 + t;
    int row = c >> 3, kc = (c & 7) * 4;
    int gr = GATHER ? rows[m0 + row] : (m0 + row);
    asrc[it] = (long)gr * lda + kc;
    bsrc[it] = (long)(n0 + row) * K + kc;
  }
  f32x4 accv[8][2];
  #pragma unroll
  for (int i = 0; i < 8; ++i) { accv[i][0] = 0.f; accv[i][1] = 0.f; }

  for (int k0 = 0; k0 < K; k0 += BK) {
    #pragma unroll
    for (int it = 0; it < 4; ++it) {
      int c = it * 256 + t;
      int row = c >> 3, kc = (c & 7) * 4;
      f32x4 av = *(const f32x4*)(A + asrc[it] + k0);
      f32x4 bv = *(const f32x4*)(B + bsrc[it] + k0);
      #pragma unroll
      for (int j = 0; j < 4; ++j) { Ast[kc + j][row] = av[j]; Bst[kc + j][row] = bv[j]; }
    }
    __syncthreads();
    #pragma unroll
    for (int kk = 0; kk < BK; ++kk) {
      f32x4 a0 = *(const f32x4*)&Ast[kk][ty * 4];
      f32x4 a1 = *(const f32x4*)&Ast[kk][64 + ty * 4];
      f32x4 b0 = *(const f32x4*)&Bst[kk][tx * 4];
      f32x4 b1 = *(const f32x4*)&Bst[kk][64 + tx * 4];
      float as[8] = {a0[0], a0[1], a0[2], a0[3], a1[0], a1[1], a1[2], a1[3]};
      #pragma unroll
      for (int i = 0; i < 8; ++i) {
        accv[i][0] += b0 * as[i];
        accv[i][1] += b1 * as[i];
      }
    }
    __syncthreads();
  }
  #pragma unroll
  for (int ih = 0; ih < 2; ++ih)
    #pragma unroll
    for (int i = 0; i < 4; ++i) {
      long m = m0 + ih * 64 + ty * 4 + i;
      #pragma unroll
      for (int jh = 0; jh < 2; ++jh) {
        long n = n0 + jh * 64 + tx * 4;
        f32x4 val = accv[ih * 4 + i][jh];
        if (POST == P_F32_RELU) {
          #pragma unroll
          for (int j = 0; j < 4; ++j) val[j] = fmaxf(val[j], 0.f);
        }
        if (POST == P_F32_RESID) val += *(const f32x4*)&resid[m * N + n];
        *(f32x4*)&C[m * N + n] = val;
      }
    }
}

// ---------------- f32 causal flash attention (HD=64, 64-row Q tile) ----------------

__global__ __launch_bounds__(256) void attn_f32_k(const float* __restrict__ q,
    const float* __restrict__ k, const float* __restrict__ v, float* __restrict__ o,
    int ldq) {
  int qt = blockIdx.x;                 // q tile of 64
  int bh = blockIdx.y;                 // b*16+h
  int b = bh >> 4, h = bh & 15;
  long hbq = (long)b * kT * ldq + h * kHD;
  long hbo = (long)b * kT * kD + h * kHD;
  int t = threadIdx.x, qr = t >> 2, sub = t & 3;

  __shared__ float Qs[64][68], Ks[64][68], Vs[64][68], Ps[64][68];

  #pragma unroll
  for (int it = 0; it < 4; ++it) {
    int c = it * 256 + t, row = c >> 4, c4 = (c & 15) * 4;
    f32x4 qv = *(const f32x4*)(q + hbq + (long)(qt * 64 + row) * ldq + c4);
    #pragma unroll
    for (int j = 0; j < 4; ++j) Qs[row][c4 + j] = qv[j];
  }
  __syncthreads();
  f32x4 qreg[16];
  #pragma unroll
  for (int d4 = 0; d4 < 16; ++d4) qreg[d4] = *(const f32x4*)&Qs[qr][d4 * 4];
  int qg = qt * 64 + qr;

  float mrow = -1e30f, lsum = 0.f;
  f32x4 accO[4];
  #pragma unroll
  for (int i = 0; i < 4; ++i) accO[i] = 0.f;

  for (int itl = 0; itl <= qt; ++itl) {
    #pragma unroll
    for (int it = 0; it < 4; ++it) {
      int c = it * 256 + t, row = c >> 4, c4 = (c & 15) * 4;
      f32x4 kv = *(const f32x4*)(k + hbq + (long)(itl * 64 + row) * ldq + c4);
      f32x4 vv = *(const f32x4*)(v + hbq + (long)(itl * 64 + row) * ldq + c4);
      #pragma unroll
      for (int j = 0; j < 4; ++j) { Ks[row][c4 + j] = kv[j]; Vs[row][c4 + j] = vv[j]; }
    }
    __syncthreads();

    float s[16];
    #pragma unroll
    for (int kk = 0; kk < 16; ++kk) {
      int key = kk * 4 + sub;
      f32x4 a = {0.f, 0.f, 0.f, 0.f};
      #pragma unroll
      for (int d4 = 0; d4 < 16; ++d4) a += qreg[d4] * *(const f32x4*)&Ks[key][d4 * 4];
      float sv = (a[0] + a[1] + a[2] + a[3]) * 0.125f;
      if (itl * 64 + key > qg) sv = -1e30f;
      s[kk] = sv;
    }
    float mx = s[0];
    #pragma unroll
    for (int kk = 1; kk < 16; ++kk) mx = fmaxf(mx, s[kk]);
    mx = fmaxf(mx, __shfl_xor(mx, 1));
    mx = fmaxf(mx, __shfl_xor(mx, 2));
    float mi = fmaxf(mrow, mx);
    float alpha = __expf(mrow - mi);
    mrow = mi;
    float rs = 0.f;
    #pragma unroll
    for (int kk = 0; kk < 16; ++kk) {
      float p = __expf(s[kk] - mi);
      rs += p;
      Ps[qr][kk * 4 + sub] = p;
    }
    rs += __shfl_xor(rs, 1);
    rs += __shfl_xor(rs, 2);
    lsum = lsum * alpha + rs;
    #pragma unroll
    for (int i = 0; i < 4; ++i) accO[i] *= alpha;
    #pragma unroll
    for (int key2 = 0; key2 < 64; ++key2) {
      float p = Ps[qr][key2];
      #pragma unroll
      for (int i4 = 0; i4 < 4; ++i4)
        accO[i4] += p * *(const f32x4*)&Vs[key2][sub * 16 + i4 * 4];
    }
    __syncthreads();
  }
  float inv = 1.f / lsum;
  #pragma unroll
  for (int i4 = 0; i4 < 4; ++i4) {
    f32x4 ov = accO[i4] * inv;
    *(f32x4*)(o + hbo + (long)qg * kD + sub * 16 + i4 * 4) = ov;
  }
}

// ---------------- host ----------------

extern "C" void kernel_launch(void* const* d_in, const int* in_sizes, int n_in,
                              void* d_out, int out_size, void* d_ws, size_t ws_size,
                              hipStream_t stream) {
  const int*   idx  = (const int*)  d_in[0];
  const float* wte  = (const float*)d_in[1];
  const float* wpe  = (const float*)d_in[2];
  const float* wq   = (const float*)d_in[3];
  const float* wk   = (const float*)d_in[4];
  const float* wv   = (const float*)d_in[5];
  const float* wo   = (const float*)d_in[6];
  const float* gate = (const float*)d_in[7];
  const float* f1   = (const float*)d_in[8];
  const float* f2   = (const float*)d_in[9];
  const float* lmh  = (const float*)d_in[10];
  float* out = (float*)d_out;

  char* ws = (char*)d_ws;
  size_t off = 0;
  auto alloc = [&](size_t b) -> char* {
    char* p = ws + off;
    off += (b + 255) & ~(size_t)255;
    return p;
  };

  constexpr long PLN_XN = (long)kBT * kD;            // activation plane
  constexpr long PLN_QKV = (long)3 * kD * kD;        // fused qkv weight plane (per layer)
  constexpr long PLN_WO = (long)kD * kD;
  constexpr long PLN_FF = (long)kE * kFF * kD;       // f1/f2 plane (per layer)
  constexpr long PLN_H = (long)kSLOTS * kFF;

  // shared small buffers
  float* x     = (float*)alloc((size_t)kBT * kD * 4);
  float* outs  = (float*)alloc((size_t)kSLOTS * kD * 4);
  float* probs = (float*)alloc((size_t)kBT * kE * 4);
  int*   top2e = (int*)  alloc((size_t)kBT * 2 * 4);
  float* top2w = (float*)alloc((size_t)kBT * 2 * 4);
  int*   meta  = (int*)  alloc(64 * 4);
  int* counts = meta; int* cursors = meta + 8; int* offs = meta + 16;
  int*   rows  = (int*)  alloc((size_t)kSLOTS * 4);
  int*   slotOf= (int*)  alloc((size_t)kBT * 2 * 4);
  float* aux   = (float*)alloc(256);
  size_t off_shared = off;

  // fast-path buffers
  u16*   xnP   = (u16*)  alloc((size_t)3 * PLN_XN * 2);
  float* qkvf  = (float*)alloc((size_t)kBT * 3 * kD * 4);
  float* of    = (float*)alloc((size_t)kBT * kD * 4);
  u16*   ofP   = (u16*)  alloc((size_t)3 * PLN_XN * 2);
  u16*   hP    = (u16*)  alloc((size_t)3 * PLN_H * 2);
  u16*   wqkvP = (u16*)  alloc((size_t)kL * 3 * PLN_QKV * 2);
  u16*   woP   = (u16*)  alloc((size_t)kL * 3 * PLN_WO * 2);
  u16*   f1P   = (u16*)  alloc((size_t)3 * PLN_FF * 2);   // reused per layer
  u16*   f2P   = (u16*)  alloc((size_t)3 * PLN_FF * 2);
  bool fast = (off <= ws_size);

  dim3 gProj(kBT / 128, kD / 128);     // (16,8)
  dim3 gQKV(kBT / 128, 3 * kD / 128);  // (16,24)
  dim3 gAttn(kT / 64, 2 * kH);         // (16,32)
  dim3 gF1(kSLOTS / 128, kFF / 128);   // (40,32)
  dim3 gF2(kSLOTS / 128, kD / 128);    // (40,8)
  dim3 gLM(kBT / 128, kV / 128);       // (16,250)

  if (fast) {
    // weight planes (small ones upfront)
    for (int li = 0; li < kL; ++li) {
      u16* dst = wqkvP + (size_t)li * 3 * PLN_QKV;
      split3_k<<<1024, 256, 0, stream>>>(wq + (size_t)li * kD * kD, dst, PLN_QKV, (long)kD * kD / 4);
      split3_k<<<1024, 256, 0, stream>>>(wk + (size_t)li * kD * kD, dst + (long)kD * kD, PLN_QKV, (long)kD * kD / 4);
      split3_k<<<1024, 256, 0, stream>>>(wv + (size_t)li * kD * kD, dst + (long)2 * kD * kD, PLN_QKV, (long)kD * kD / 4);
      split3_k<<<1024, 256, 0, stream>>>(wo + (size_t)li * kD * kD, woP + (size_t)li * 3 * PLN_WO, PLN_WO, (long)kD * kD / 4);
    }
    hipMemsetAsync(aux, 0, 4, stream);
    embed_rms_k<<<kBT, 256, 0, stream>>>(idx, wte, wpe, x);

    for (int li = 0; li < kL; ++li) {
      rmsnorm3_k<<<kBT, 256, 0, stream>>>(x, xnP, PLN_XN);
      gemm3_bt_k<P_F32, false, false><<<gQKV, 256, 0, stream>>>(
          xnP, PLN_XN, wqkvP + (size_t)li * 3 * PLN_QKV, PLN_QKV,
          qkvf, 0, nullptr, nullptr, nullptr, 3 * kD, kD, kD, 0);
      attn_f32_k<<<gAttn, 256, 0, stream>>>(qkvf, qkvf + kD, qkvf + 2 * kD, of, 3 * kD);
      split3_k<<<2048, 256, 0, stream>>>(of, ofP, PLN_XN, PLN_XN / 4);
      gemm3_bt_k<P_F32_RESID, false, false><<<gProj, 256, 0, stream>>>(
          ofP, PLN_XN, woP + (size_t)li * 3 * PLN_WO, PLN_WO,
          x, 0, x, nullptr, nullptr, kD, kD, kD, 0);
      rmsnorm3_k<<<kBT, 256, 0, stream>>>(x, xnP, PLN_XN);
      hipMemsetAsync(meta, 0, 64, stream);
      gate_topk_k<<<kBT, 256, 0, stream>>>(x, gate + (size_t)li * kE * kD,
                                           probs, top2e, top2w, counts);
      calc_offsets_k<<<1, 64, 0, stream>>>(counts, offs);
      hipMemsetAsync(rows, 0, (size_t)kSLOTS * 4, stream);
      fill_slots_k<<<kBT / 256, 256, 0, stream>>>(top2e, offs, cursors, rows, slotOf);
      size_t fd = (size_t)li * PLN_FF;
      if (li < 2) {
        split3_k<<<4096, 256, 0, stream>>>(f1 + fd, f1P, PLN_FF, PLN_FF / 4);
        split3_k<<<4096, 256, 0, stream>>>(f2 + fd, f2P, PLN_FF, PLN_FF / 4);
        gemm3_bt_k<P_SPLIT3_RELU, true, true><<<gF1, 256, 0, stream>>>(
            xnP, PLN_XN, f1P, PLN_FF, hP, PLN_H, nullptr, rows, offs,
            kFF, kD, kD, (long)kFF * kD);
        gemm3_bt_k<P_F32, false, true><<<gF2, 256, 0, stream>>>(
            hP, PLN_H, f2P, PLN_FF, outs, 0, nullptr, nullptr, offs,
            kD, kFF, kFF, (long)kD * kFF);
      } else {
        // last layer: nothing downstream is routing-sensitive -> single bf16
        gemm_bt_k<P_BF16_RELU, true, true><<<gF1, 256, 0, stream>>>(
            xnP, f1 + fd, hP, rows, offs, kFF, kD, kD, (long)kFF * kD);
        gemm_bt_k<P_F32, true, false><<<gF2, 256, 0, stream>>>(
            hP, f2 + fd, outs, nullptr, offs, kD, kFF, kFF, (long)kD * kFF);
      }
      moe_combine_k<<<kBT, 256, 0, stream>>>(x, outs, slotOf, top2w);
      aux_reduce_k<<<1, 256, 0, stream>>>(probs, aux);
    }
    cast_bf16_k<<<2048, 256, 0, stream>>>(x, xnP, PLN_XN / 4);
    gemm_bt_k<P_F32, false, false><<<gLM, 256, 0, stream>>>(
        xnP, lmh, out, nullptr, nullptr, kV, kD, kD, 0);
    write_aux_k<<<1, 64, 0, stream>>>(aux, out + (size_t)kBT * kV);
    return;
  }

  // ---------- fallback: round-2 f32 path ----------
  off = off_shared;
  float* xnf   = (float*)alloc((size_t)kBT * kD * 4);
  u16*   xnb   = (u16*)  alloc((size_t)kBT * kD * 2);
  float* qf    = (float*)alloc((size_t)kBT * kD * 4);
  float* kf    = (float*)alloc((size_t)kBT * kD * 4);
  float* vf    = (float*)alloc((size_t)kBT * kD * 4);
  float* off32 = (float*)alloc((size_t)kBT * kD * 4);
  float* hbuf  = (float*)alloc((size_t)kSLOTS * kFF * 4);
  u16* hbuf16 = (u16*)hbuf;

  hipMemsetAsync(aux, 0, 4, stream);
  embed_rms_k<<<kBT, 256, 0, stream>>>(idx, wte, wpe, x);
  for (int li = 0; li < kL; ++li) {
    size_t dd = (size_t)li * kD * kD;
    rmsnorm2_k<<<kBT, 256, 0, stream>>>(x, xnf, xnb);
    sgemm_bt_k<P_F32, false, false><<<gProj, 256, 0, stream>>>(
        xnf, wq + dd, qf, nullptr, nullptr, nullptr, kD, kD, kD, 0);
    sgemm_bt_k<P_F32, false, false><<<gProj, 256, 0, stream>>>(
        xnf, wk + dd, kf, nullptr, nullptr, nullptr, kD, kD, kD, 0);
    sgemm_bt_k<P_F32, false, false><<<gProj, 256, 0, stream>>>(
        xnf, wv + dd, vf, nullptr, nullptr, nullptr, kD, kD, kD, 0);
    attn_f32_k<<<gAttn, 256, 0, stream>>>(qf, kf, vf, off32, kD);
    sgemm_bt_k<P_F32_RESID, false, false><<<gProj, 256, 0, stream>>>(
        off32, wo + dd, x, x, nullptr, nullptr, kD, kD, kD, 0);
    rmsnorm2_k<<<kBT, 256, 0, stream>>>(x, xnf, xnb);
    hipMemsetAsync(meta, 0, 64, stream);
    gate_topk_k<<<kBT, 256, 0, stream>>>(x, gate + (size_t)li * kE * kD,
                                         probs, top2e, top2w, counts);
    calc_offsets_k<<<1, 64, 0, stream>>>(counts, offs);
    hipMemsetAsync(rows, 0, (size_t)kSLOTS * 4, stream);
    fill_slots_k<<<kBT / 256, 256, 0, stream>>>(top2e, offs, cursors, rows, slotOf);
    size_t fd = (size_t)li * kE * kFF * kD;
    if (li < 2) {
      sgemm_bt_k<P_F32_RELU, true, true><<<gF1, 256, 0, stream>>>(
          xnf, f1 + fd, hbuf, nullptr, rows, offs, kFF, kD, kD, (long)kFF * kD);
      sgemm_bt_k<P_F32, false, true><<<gF2, 256, 0, stream>>>(
          hbuf, f2 + fd, outs, nullptr, nullptr, offs, kD, kFF, kFF, (long)kD * kFF);
    } else {
      gemm_bt_k<P_BF16_RELU, true, true><<<gF1, 256, 0, stream>>>(
          xnb, f1 + fd, hbuf16, rows, offs, kFF, kD, kD, (long)kFF * kD);
      gemm_bt_k<P_F32, true, false><<<gF2, 256, 0, stream>>>(
          hbuf16, f2 + fd, outs, nullptr, offs, kD, kFF, kFF, (long)kD * kFF);
    }
    moe_combine_k<<<kBT, 256, 0, stream>>>(x, outs, slotOf, top2w);
    aux_reduce_k<<<1, 256, 0, stream>>>(probs, aux);
  }
  cast_bf16_k<<<2048, 256, 0, stream>>>(x, xnb, (long)kBT * kD / 4);
  gemm_bt_k<P_F32, false, false><<<gLM, 256, 0, stream>>>(
      xnb, lmh, out, nullptr, nullptr, kV, kD, kD, 0);
  write_aux_k<<<1, 64, 0, stream>>>(aux, out + (size_t)kBT * kV);
}

// Round 5
// 3447.991 us; speedup vs baseline: 1.6405x; 1.2774x over previous
//
#include <hip/hip_runtime.h>

typedef unsigned short u16;
typedef __attribute__((ext_vector_type(4))) float f32x4;
typedef __attribute__((ext_vector_type(8))) __bf16 bf16x8;
typedef __attribute__((ext_vector_type(4))) unsigned short u16x4;
typedef __attribute__((ext_vector_type(8))) unsigned short u16x8;

constexpr int kT = 1024, kD = 1024, kH = 16, kHD = 64, kL = 3, kE = 8;
constexpr int kFF = 4096, kV = 32000, kBT = 2048, kSLOTS = 5120;

__device__ __forceinline__ u16 f2bf(float f) {
  union { float f; unsigned u; } v; v.f = f;
  unsigned r = v.u + 0x7FFFu + ((v.u >> 16) & 1u);   // RNE
  return (u16)(r >> 16);
}
__device__ __forceinline__ float bf2f(u16 h) {
  union { unsigned u; float f; } v; v.u = ((unsigned)h) << 16; return v.f;
}
// 3-way bf16 split: x = hi + mid + lo + r, |r| <= ~2^-24 |x|
__device__ __forceinline__ void split3(float x, u16& h, u16& m, u16& l) {
  h = f2bf(x); float r1 = x - bf2f(h);
  m = f2bf(r1); float r2 = r1 - bf2f(m);
  l = f2bf(r2);
}

__device__ __forceinline__ void ld_lds16(const void* g, void* l) {
  __builtin_amdgcn_global_load_lds((const __attribute__((address_space(1))) void*)g,
                                   (__attribute__((address_space(3))) void*)l, 16, 0, 0);
}

#define MFMA16(a, b, c) __builtin_amdgcn_mfma_f32_16x16x32_bf16(a, b, c, 0, 0, 0)

__device__ __forceinline__ float blockReduceSum256(float v) {
  #pragma unroll
  for (int m = 32; m >= 1; m >>= 1) v += __shfl_xor(v, m);
  __shared__ float sh_[4];
  int w = threadIdx.x >> 6;
  if ((threadIdx.x & 63) == 0) sh_[w] = v;
  __syncthreads();
  v = (sh_[0] + sh_[1]) + (sh_[2] + sh_[3]);
  __syncthreads();
  return v;
}

// ---------------- elementwise / small kernels ----------------

__global__ __launch_bounds__(256) void cast_bf16_k(const float* __restrict__ in,
                                                   u16* __restrict__ out, long n4) {
  long i = (long)blockIdx.x * 256 + threadIdx.x;
  long stride = (long)gridDim.x * 256;
  for (; i < n4; i += stride) {
    f32x4 v = ((const f32x4*)in)[i];
    u16x4 o; o[0] = f2bf(v[0]); o[1] = f2bf(v[1]); o[2] = f2bf(v[2]); o[3] = f2bf(v[3]);
    ((u16x4*)out)[i] = o;
  }
}

// f32 -> 3 bf16 planes (planeStride elements apart)
__global__ __launch_bounds__(256) void split3_k(const float* __restrict__ in,
    u16* __restrict__ out, long planeStride, long n4) {
  long i = (long)blockIdx.x * 256 + threadIdx.x;
  long stride = (long)gridDim.x * 256;
  u16* o1 = out + planeStride; u16* o2 = out + 2 * planeStride;
  for (; i < n4; i += stride) {
    f32x4 v = ((const f32x4*)in)[i];
    u16x4 a, b, c;
    #pragma unroll
    for (int j = 0; j < 4; ++j) {
      u16 h, m, l; split3(v[j], h, m, l);
      a[j] = h; b[j] = m; c[j] = l;
    }
    ((u16x4*)out)[i] = a; ((u16x4*)o1)[i] = b; ((u16x4*)o2)[i] = c;
  }
}

__global__ __launch_bounds__(256) void embed_rms_k(const int* __restrict__ idx,
    const float* __restrict__ wte, const float* __restrict__ wpe, float* __restrict__ x) {
  int tok = blockIdx.x, t = threadIdx.x;
  int id = idx[tok];
  int tt = tok & (kT - 1);
  f32x4 a = ((const f32x4*)(wte + (long)id * kD))[t];
  f32x4 p = ((const f32x4*)(wpe + (long)tt * kD))[t];
  f32x4 vv = a + p;
  float ss = vv[0]*vv[0] + vv[1]*vv[1] + vv[2]*vv[2] + vv[3]*vv[3];
  ss = blockReduceSum256(ss);
  float sc = rsqrtf(ss * (1.0f / kD) + 1e-5f);
  vv *= sc;
  ((f32x4*)(x + (long)tok * kD))[t] = vv;
}

// rmsnorm -> f32 + bf16 (fallback path)
__global__ __launch_bounds__(256) void rmsnorm2_k(const float* __restrict__ x,
    float* __restrict__ xnf, u16* __restrict__ xnb) {
  int tok = blockIdx.x, t = threadIdx.x;
  f32x4 vv = ((const f32x4*)(x + (long)tok * kD))[t];
  float ss = blockReduceSum256(vv[0]*vv[0] + vv[1]*vv[1] + vv[2]*vv[2] + vv[3]*vv[3]);
  float sc = rsqrtf(ss * (1.0f / kD) + 1e-5f);
  vv *= sc;
  ((f32x4*)(xnf + (long)tok * kD))[t] = vv;
  u16x4 o;
  o[0] = f2bf(vv[0]); o[1] = f2bf(vv[1]); o[2] = f2bf(vv[2]); o[3] = f2bf(vv[3]);
  ((u16x4*)(xnb + (long)tok * kD))[t] = o;
}

// rmsnorm -> 3 bf16 planes (fast path)
__global__ __launch_bounds__(256) void rmsnorm3_k(const float* __restrict__ x,
    u16* __restrict__ xnP, long plane) {
  int tok = blockIdx.x, t = threadIdx.x;
  f32x4 vv = ((const f32x4*)(x + (long)tok * kD))[t];
  float ss = blockReduceSum256(vv[0]*vv[0] + vv[1]*vv[1] + vv[2]*vv[2] + vv[3]*vv[3]);
  float sc = rsqrtf(ss * (1.0f / kD) + 1e-5f);
  vv *= sc;
  u16x4 a, b, c;
  #pragma unroll
  for (int j = 0; j < 4; ++j) {
    u16 h, m, l; split3(vv[j], h, m, l);
    a[j] = h; b[j] = m; c[j] = l;
  }
  long o = (long)tok * kD / 4 + t;
  ((u16x4*)xnP)[o] = a;
  ((u16x4*)(xnP + plane))[o] = b;
  ((u16x4*)(xnP + 2 * plane))[o] = c;
}

// gating in f32 (bf16 would flip top-2 selections on near-ties)
__global__ __launch_bounds__(256) void gate_topk_k(const float* __restrict__ x,
    const float* __restrict__ gate_l, float* __restrict__ probs, int* __restrict__ top2e,
    float* __restrict__ top2w, int* __restrict__ counts) {
  int tok = blockIdx.x, t = threadIdx.x;
  f32x4 xv = ((const f32x4*)(x + (long)tok * kD))[t];
  float ss = blockReduceSum256(xv[0]*xv[0] + xv[1]*xv[1] + xv[2]*xv[2] + xv[3]*xv[3]);
  float sc = rsqrtf(ss * (1.0f / kD) + 1e-5f);
  float a[kE];
  #pragma unroll
  for (int e = 0; e < kE; ++e) {
    f32x4 gv = ((const f32x4*)(gate_l + (long)e * kD))[t];
    a[e] = xv[0]*gv[0] + xv[1]*gv[1] + xv[2]*gv[2] + xv[3]*gv[3];
  }
  __shared__ float sh8[kE][4];
  int w = t >> 6, l = t & 63;
  #pragma unroll
  for (int e = 0; e < kE; ++e) {
    float v = a[e];
    #pragma unroll
    for (int m = 32; m >= 1; m >>= 1) v += __shfl_xor(v, m);
    if (l == 0) sh8[e][w] = v;
  }
  __syncthreads();
  if (t == 0) {
    float lg[kE], mx = -1e30f;
    #pragma unroll
    for (int e = 0; e < kE; ++e) {
      lg[e] = (sh8[e][0] + sh8[e][1] + sh8[e][2] + sh8[e][3]) * sc;
      mx = fmaxf(mx, lg[e]);
    }
    float pe[kE], s = 0.f;
    #pragma unroll
    for (int e = 0; e < kE; ++e) { pe[e] = __expf(lg[e] - mx); s += pe[e]; }
    float inv = 1.f / s;
    int i1 = 0;
    #pragma unroll
    for (int e = 1; e < kE; ++e) if (lg[e] > lg[i1]) i1 = e;
    int i2 = (i1 == 0) ? 1 : 0;
    #pragma unroll
    for (int e = 0; e < kE; ++e) if (e != i1 && lg[e] > lg[i2]) i2 = e;
    #pragma unroll
    for (int e = 0; e < kE; ++e) probs[(long)tok * kE + e] = pe[e] * inv;
    float p1 = pe[i1] * inv, p2 = pe[i2] * inv;
    float wn = p1 + p2;
    top2e[tok*2] = i1; top2e[tok*2+1] = i2;
    top2w[tok*2] = p1 / wn; top2w[tok*2+1] = p2 / wn;
    atomicAdd(&counts[i1], 1); atomicAdd(&counts[i2], 1);
  }
}

__global__ void calc_offsets_k(const int* __restrict__ counts, int* __restrict__ offsets) {
  if (threadIdx.x == 0) {
    int o = 0;
    #pragma unroll
    for (int e = 0; e < kE; ++e) { offsets[e] = o; o += (counts[e] + 127) & ~127; }
    offsets[kE] = o;
  }
}

__global__ __launch_bounds__(256) void fill_slots_k(const int* __restrict__ top2e,
    const int* __restrict__ offsets, int* __restrict__ cursors,
    int* __restrict__ rows, int* __restrict__ slotOf) {
  int tok = blockIdx.x * 256 + threadIdx.x;
  if (tok >= kBT) return;
  #pragma unroll
  for (int j = 0; j < 2; ++j) {
    int e = top2e[tok*2 + j];
    int pos = atomicAdd(&cursors[e], 1);
    int slot = offsets[e] + pos;
    rows[slot] = tok;
    slotOf[tok*2 + j] = slot;
  }
}

__global__ __launch_bounds__(256) void moe_combine_k(float* __restrict__ x,
    const float* __restrict__ outs, const int* __restrict__ slotOf,
    const float* __restrict__ top2w) {
  int tok = blockIdx.x, t = threadIdx.x;
  int s0 = slotOf[tok*2], s1 = slotOf[tok*2+1];
  float w0 = top2w[tok*2], w1 = top2w[tok*2+1];
  f32x4 a = ((const f32x4*)(outs + (long)s0 * kD))[t];
  f32x4 b = ((const f32x4*)(outs + (long)s1 * kD))[t];
  f32x4 xv = ((f32x4*)(x + (long)tok * kD))[t];
  xv += a * w0 + b * w1;
  ((f32x4*)(x + (long)tok * kD))[t] = xv;
}

__global__ __launch_bounds__(256) void aux_reduce_k(const float* __restrict__ probs,
                                                    float* __restrict__ aux) {
  int t = threadIdx.x;
  float part[kE] = {};
  for (int i = t; i < kBT; i += 256) {
    #pragma unroll
    for (int e = 0; e < kE; ++e) part[e] += probs[(long)i * kE + e];
  }
  __shared__ float sh8[kE][4];
  int w = t >> 6, l = t & 63;
  #pragma unroll
  for (int e = 0; e < kE; ++e) {
    float v = part[e];
    #pragma unroll
    for (int m = 32; m >= 1; m >>= 1) v += __shfl_xor(v, m);
    if (l == 0) sh8[e][w] = v;
  }
  __syncthreads();
  if (t == 0) {
    float acc = 0.f;
    #pragma unroll
    for (int e = 0; e < kE; ++e) {
      float frac = (sh8[e][0] + sh8[e][1] + sh8[e][2] + sh8[e][3]) * (1.0f / kBT);
      acc += frac * frac;
    }
    aux[0] += (float)kE * acc;
  }
}

__global__ void write_aux_k(const float* __restrict__ aux, float* __restrict__ out) {
  if (threadIdx.x == 0) out[0] = 0.01f * aux[0] / (float)kL;
}

enum { P_BF16 = 0, P_BF16_RELU = 1, P_F32 = 2, P_F32_RESID = 3, P_F32_RELU = 4,
       P_SPLIT3_RELU = 5 };

// ------- fused split-3 MFMA GEMM: C = sum over 6 plane-pairs A_pa*B_pb^T -------
// BK=32, six 128x32 LDS tiles (48KB), 96 MFMA per barrier-pair.
// XOR-swizzled LDS via pre-swizzled global source (linear global_load_lds dest).

template <int POST, bool GATHER, bool EXPERT>
__global__ __launch_bounds__(256) void gemm3f_bt_k(
    const u16* __restrict__ A0, long planeA,
    const u16* __restrict__ B0, long planeB,
    void* __restrict__ C, long planeC,
    const float* __restrict__ resid,
    const int* __restrict__ rows, const int* __restrict__ offsets,
    int N, int K, int lda, long eBstride) {
  constexpr int BM = 128, BK = 32;
  int m0 = blockIdx.x * BM;
  int n0 = blockIdx.y * BM;
  if (EXPERT) {
    int total = offsets[kE];
    if (m0 >= total) return;
    int e = 0;
    while (offsets[e + 1] <= m0) ++e;
    B0 += (long)e * eBstride;
  }
  __shared__ __align__(16) u16 As[3][BM][BK];
  __shared__ __align__(16) u16 Bs[3][BM][BK];
  int t = threadIdx.x;
  int l = t & 63, lr = l & 15, lg = l >> 4;
  int wid = t >> 6;
  int wm = (wid >> 1) * 64, wn = (wid & 1) * 64;

  long asrc[2], bsrc[2];
  int ldst[2];
  #pragma unroll
  for (int it = 0; it < 2; ++it) {
    int c = it * 256 + t;
    int row = c >> 2;
    int col = ((c ^ row) & 3) * 8;          // inverse-swizzled global column
    int grow = GATHER ? rows[m0 + row] : (m0 + row);
    asrc[it] = (long)grow * lda + col;
    bsrc[it] = (long)(n0 + row) * K + col;
    ldst[it] = (it * 256 + (t & ~63)) * 8;  // u16 units; linear dest
  }
  int swz = (lg ^ (lr & 3)) * 8;            // swizzled read column (u16 units)

  f32x4 acc[4][4];
  #pragma unroll
  for (int i = 0; i < 4; ++i)
    #pragma unroll
    for (int j = 0; j < 4; ++j) acc[i][j] = 0.f;

  for (int k0 = 0; k0 < K; k0 += BK) {
    #pragma unroll
    for (int p = 0; p < 3; ++p) {
      #pragma unroll
      for (int it = 0; it < 2; ++it) {
        ld_lds16(A0 + p * planeA + asrc[it] + k0, &As[p][0][0] + ldst[it]);
        ld_lds16(B0 + p * planeB + bsrc[it] + k0, &Bs[p][0][0] + ldst[it]);
      }
    }
    __syncthreads();
    bf16x8 af[3][4];
    #pragma unroll
    for (int p = 0; p < 3; ++p)
      #pragma unroll
      for (int i = 0; i < 4; ++i)
        af[p][i] = *(const bf16x8*)&As[p][wm + i*16 + lr][swz];
    // B-plane groups: B0 x {A0,A1,A2}, B1 x {A0,A1}, B2 x {A0}
    #pragma unroll
    for (int g = 0; g < 3; ++g) {
      bf16x8 bq[4];
      #pragma unroll
      for (int j = 0; j < 4; ++j)
        bq[j] = *(const bf16x8*)&Bs[g][wn + j*16 + lr][swz];
      #pragma unroll
      for (int a = 0; a < 3 - g; ++a)
        #pragma unroll
        for (int i = 0; i < 4; ++i)
          #pragma unroll
          for (int j = 0; j < 4; ++j)
            acc[i][j] = MFMA16(af[a][i], bq[j], acc[i][j]);
    }
    __syncthreads();
  }
  #pragma unroll
  for (int i = 0; i < 4; ++i) {
    #pragma unroll
    for (int r = 0; r < 4; ++r) {
      long m = m0 + wm + i*16 + lg*4 + r;
      #pragma unroll
      for (int j = 0; j < 4; ++j) {
        int n = n0 + wn + j*16 + lr;
        float val = acc[i][j][r];
        if (POST == P_F32) {
          ((float*)C)[m * N + n] = val;
        } else if (POST == P_F32_RESID) {
          ((float*)C)[m * N + n] = val + resid[m * N + n];
        } else if (POST == P_SPLIT3_RELU) {
          val = fmaxf(val, 0.f);
          u16 h, mm, lo; split3(val, h, mm, lo);
          u16* Cp = (u16*)C;
          Cp[m * N + n] = h;
          Cp[planeC + m * N + n] = mm;
          Cp[2 * planeC + m * N + n] = lo;
        }
      }
    }
  }
}

// ---------------- single-bf16 MFMA GEMM (post-routing): B is f32, converted in staging ----

template <int POST, bool EXPERT, bool GATHER>
__global__ __launch_bounds__(256) void gemm_bt_k(
    const u16* __restrict__ A, const float* __restrict__ Bf, void* __restrict__ C,
    const int* __restrict__ rows, const int* __restrict__ offsets,
    int N, int K, int lda, long eBstride) {
  constexpr int BM = 128, BK = 64;
  int m0 = blockIdx.x * BM;
  int n0 = blockIdx.y * BM;
  if (EXPERT) {
    int total = offsets[kE];
    if (m0 >= total) return;
    int e = 0;
    while (offsets[e + 1] <= m0) ++e;
    Bf += (long)e * eBstride;
  }
  __shared__ __align__(16) u16 As[BM][BK];
  __shared__ __align__(16) u16 Bs[BM][BK + 8];
  int t = threadIdx.x;
  int l = t & 63, lr = l & 15, lg = l >> 4;
  int wid = t >> 6;
  int wm = (wid >> 1) * 64, wn = (wid & 1) * 64;

  long asrc[4];
  #pragma unroll
  for (int it = 0; it < 4; ++it) {
    int c = it * 256 + t;
    int row = c >> 3, col = (c & 7) * 8;
    int grow = GATHER ? rows[m0 + row] : (m0 + row);
    asrc[it] = (long)grow * lda + col;
  }
  f32x4 acc[4][4];
  #pragma unroll
  for (int i = 0; i < 4; ++i)
    #pragma unroll
    for (int j = 0; j < 4; ++j) acc[i][j] = 0.f;

  for (int k0 = 0; k0 < K; k0 += BK) {
    #pragma unroll
    for (int it = 0; it < 4; ++it)
      ld_lds16(A + asrc[it] + k0, &As[0][0] + (it * 256 + (t & ~63)) * 8);
    #pragma unroll
    for (int it = 0; it < 8; ++it) {
      int c = it * 256 + t;
      int row = c >> 4, col = (c & 15) * 4;
      f32x4 v = *(const f32x4*)(Bf + (long)(n0 + row) * K + k0 + col);
      u16x4 o; o[0] = f2bf(v[0]); o[1] = f2bf(v[1]); o[2] = f2bf(v[2]); o[3] = f2bf(v[3]);
      *(u16x4*)&Bs[row][col] = o;
    }
    __syncthreads();
    #pragma unroll
    for (int kk = 0; kk < 2; ++kk) {
      int kc = kk * 32 + lg * 8;
      bf16x8 af[4], bq[4];
      #pragma unroll
      for (int i = 0; i < 4; ++i) af[i] = *(const bf16x8*)&As[wm + i*16 + lr][kc];
      #pragma unroll
      for (int j = 0; j < 4; ++j) bq[j] = *(const bf16x8*)&Bs[wn + j*16 + lr][kc];
      #pragma unroll
      for (int i = 0; i < 4; ++i)
        #pragma unroll
        for (int j = 0; j < 4; ++j)
          acc[i][j] = MFMA16(af[i], bq[j], acc[i][j]);
    }
    __syncthreads();
  }
  #pragma unroll
  for (int i = 0; i < 4; ++i) {
    #pragma unroll
    for (int r = 0; r < 4; ++r) {
      long m = m0 + wm + i*16 + lg*4 + r;
      #pragma unroll
      for (int j = 0; j < 4; ++j) {
        int n = n0 + wn + j*16 + lr;
        float val = acc[i][j][r];
        if (POST == P_BF16_RELU)       ((u16*)C)[m * N + n] = f2bf(fmaxf(val, 0.f));
        else if (POST == P_F32)        ((float*)C)[m * N + n] = val;
      }
    }
  }
}

// ---------------- f32 SGEMM (fallback path only) ----------------

template <int POST, bool GATHER, bool EXPERT>
__global__ __launch_bounds__(256) void sgemm_bt_k(
    const float* __restrict__ A, const float* __restrict__ B, float* __restrict__ C,
    const float* __restrict__ resid, const int* __restrict__ rows,
    const int* __restrict__ offsets, int N, int K, int lda, long eBstride) {
  constexpr int BM = 128, BN = 128, BK = 32;
  int m0 = blockIdx.x * BM, n0 = blockIdx.y * BN;
  if (EXPERT) {
    int total = offsets[kE];
    if (m0 >= total) return;
    int e = 0;
    while (offsets[e + 1] <= m0) ++e;
    B += (long)e * eBstride;
  }
  __shared__ float Ast[BK][BM];
  __shared__ float Bst[BK][BN];
  int t = threadIdx.x, tx = t & 15, ty = t >> 4;
  long asrc[4], bsrc[4];
  #pragma unroll
  for (int it = 0; it < 4; ++it) {
    int c = it * 256 + t;
    int row = c >> 3, kc = (c & 7) * 4;
    int gr = GATHER ? rows[m0 + row] : (m0 + row);
    asrc[it] = (long)gr * lda + kc;
    bsrc[it] = (long)(n0 + row) * K + kc;
  }
  f32x4 accv[8][2];
  #pragma unroll
  for (int i = 0; i < 8; ++i) { accv[i][0] = 0.f; accv[i][1] = 0.f; }

  for (int k0 = 0; k0 < K; k0 += BK) {
    #pragma unroll
    for (int it = 0; it < 4; ++it) {
      int c = it * 256 + t;
      int row = c >> 3, kc = (c & 7) * 4;
      f32x4 av = *(const f32x4*)(A + asrc[it] + k0);
      f32x4 bv = *(const f32x4*)(B + bsrc[it] + k0);
      #pragma unroll
      for (int j = 0; j < 4; ++j) { Ast[kc + j][row] = av[j]; Bst[kc + j][row] = bv[j]; }
    }
    __syncthreads();
    #pragma unroll
    for (int kk = 0; kk < BK; ++kk) {
      f32x4 a0 = *(const f32x4*)&Ast[kk][ty * 4];
      f32x4 a1 = *(const f32x4*)&Ast[kk][64 + ty * 4];
      f32x4 b0 = *(const f32x4*)&Bst[kk][tx * 4];
      f32x4 b1 = *(const f32x4*)&Bst[kk][64 + tx * 4];
      float as[8] = {a0[0], a0[1], a0[2], a0[3], a1[0], a1[1], a1[2], a1[3]};
      #pragma unroll
      for (int i = 0; i < 8; ++i) {
        accv[i][0] += b0 * as[i];
        accv[i][1] += b1 * as[i];
      }
    }
    __syncthreads();
  }
  #pragma unroll
  for (int ih = 0; ih < 2; ++ih)
    #pragma unroll
    for (int i = 0; i < 4; ++i) {
      long m = m0 + ih * 64 + ty * 4 + i;
      #pragma unroll
      for (int jh = 0; jh < 2; ++jh) {
        long n = n0 + jh * 64 + tx * 4;
        f32x4 val = accv[ih * 4 + i][jh];
        if (POST == P_F32_RELU) {
          #pragma unroll
          for (int j = 0; j < 4; ++j) val[j] = fmaxf(val[j], 0.f);
        }
        if (POST == P_F32_RESID) val += *(const f32x4*)&resid[m * N + n];
        *(f32x4*)&C[m * N + n] = val;
      }
    }
}

// ---------------- f32 causal flash attention (HD=64, 64-row Q tile) ----------------

__global__ __launch_bounds__(256) void attn_f32_k(const float* __restrict__ q,
    const float* __restrict__ k, const float* __restrict__ v, float* __restrict__ o,
    int ldq) {
  int qt = blockIdx.x;                 // q tile of 64
  int bh = blockIdx.y;                 // b*16+h
  int b = bh >> 4, h = bh & 15;
  long hbq = (long)b * kT * ldq + h * kHD;
  long hbo = (long)b * kT * kD + h * kHD;
  int t = threadIdx.x, qr = t >> 2, sub = t & 3;

  __shared__ float Qs[64][68], Ks[64][68], Vs[64][68], Ps[64][68];

  #pragma unroll
  for (int it = 0; it < 4; ++it) {
    int c = it * 256 + t, row = c >> 4, c4 = (c & 15) * 4;
    f32x4 qv = *(const f32x4*)(q + hbq + (long)(qt * 64 + row) * ldq + c4);
    #pragma unroll
    for (int j = 0; j < 4; ++j) Qs[row][c4 + j] = qv[j];
  }
  __syncthreads();
  f32x4 qreg[16];
  #pragma unroll
  for (int d4 = 0; d4 < 16; ++d4) qreg[d4] = *(const f32x4*)&Qs[qr][d4 * 4];
  int qg = qt * 64 + qr;

  float mrow = -1e30f, lsum = 0.f;
  f32x4 accO[4];
  #pragma unroll
  for (int i = 0; i < 4; ++i) accO[i] = 0.f;

  for (int itl = 0; itl <= qt; ++itl) {
    #pragma unroll
    for (int it = 0; it < 4; ++it) {
      int c = it * 256 + t, row = c >> 4, c4 = (c & 15) * 4;
      f32x4 kv = *(const f32x4*)(k + hbq + (long)(itl * 64 + row) * ldq + c4);
      f32x4 vv = *(const f32x4*)(v + hbq + (long)(itl * 64 + row) * ldq + c4);
      #pragma unroll
      for (int j = 0; j < 4; ++j) { Ks[row][c4 + j] = kv[j]; Vs[row][c4 + j] = vv[j]; }
    }
    __syncthreads();

    float s[16];
    #pragma unroll
    for (int kk = 0; kk < 16; ++kk) {
      int key = kk * 4 + sub;
      f32x4 a = {0.f, 0.f, 0.f, 0.f};
      #pragma unroll
      for (int d4 = 0; d4 < 16; ++d4) a += qreg[d4] * *(const f32x4*)&Ks[key][d4 * 4];
      float sv = (a[0] + a[1] + a[2] + a[3]) * 0.125f;
      if (itl * 64 + key > qg) sv = -1e30f;
      s[kk] = sv;
    }
    float mx = s[0];
    #pragma unroll
    for (int kk = 1; kk < 16; ++kk) mx = fmaxf(mx, s[kk]);
    mx = fmaxf(mx, __shfl_xor(mx, 1));
    mx = fmaxf(mx, __shfl_xor(mx, 2));
    float mi = fmaxf(mrow, mx);
    float alpha = __expf(mrow - mi);
    mrow = mi;
    float rs = 0.f;
    #pragma unroll
    for (int kk = 0; kk < 16; ++kk) {
      float p = __expf(s[kk] - mi);
      rs += p;
      Ps[qr][kk * 4 + sub] = p;
    }
    rs += __shfl_xor(rs, 1);
    rs += __shfl_xor(rs, 2);
    lsum = lsum * alpha + rs;
    #pragma unroll
    for (int i = 0; i < 4; ++i) accO[i] *= alpha;
    #pragma unroll
    for (int key2 = 0; key2 < 64; ++key2) {
      float p = Ps[qr][key2];
      #pragma unroll
      for (int i4 = 0; i4 < 4; ++i4)
        accO[i4] += p * *(const f32x4*)&Vs[key2][sub * 16 + i4 * 4];
    }
    __syncthreads();
  }
  float inv = 1.f / lsum;
  #pragma unroll
  for (int i4 = 0; i4 < 4; ++i4) {
    f32x4 ov = accO[i4] * inv;
    *(f32x4*)(o + hbo + (long)qg * kD + sub * 16 + i4 * 4) = ov;
  }
}

// ---------------- host ----------------

extern "C" void kernel_launch(void* const* d_in, const int* in_sizes, int n_in,
                              void* d_out, int out_size, void* d_ws, size_t ws_size,
                              hipStream_t stream) {
  const int*   idx  = (const int*)  d_in[0];
  const float* wte  = (const float*)d_in[1];
  const float* wpe  = (const float*)d_in[2];
  const float* wq   = (const float*)d_in[3];
  const float* wk   = (const float*)d_in[4];
  const float* wv   = (const float*)d_in[5];
  const float* wo   = (const float*)d_in[6];
  const float* gate = (const float*)d_in[7];
  const float* f1   = (const float*)d_in[8];
  const float* f2   = (const float*)d_in[9];
  const float* lmh  = (const float*)d_in[10];
  float* out = (float*)d_out;

  char* ws = (char*)d_ws;
  size_t off = 0;
  auto alloc = [&](size_t b) -> char* {
    char* p = ws + off;
    off += (b + 255) & ~(size_t)255;
    return p;
  };

  constexpr long PLN_XN = (long)kBT * kD;            // activation plane
  constexpr long PLN_QKV = (long)3 * kD * kD;        // fused qkv weight plane (per layer)
  constexpr long PLN_WO = (long)kD * kD;
  constexpr long PLN_FF = (long)kE * kFF * kD;       // f1/f2 plane (per layer)
  constexpr long PLN_H = (long)kSLOTS * kFF;

  // shared small buffers
  float* x     = (float*)alloc((size_t)kBT * kD * 4);
  float* outs  = (float*)alloc((size_t)kSLOTS * kD * 4);
  float* probs = (float*)alloc((size_t)kBT * kE * 4);
  int*   top2e = (int*)  alloc((size_t)kBT * 2 * 4);
  float* top2w = (float*)alloc((size_t)kBT * 2 * 4);
  int*   meta  = (int*)  alloc(64 * 4);
  int* counts = meta; int* cursors = meta + 8; int* offs = meta + 16;
  int*   rows  = (int*)  alloc((size_t)kSLOTS * 4);
  int*   slotOf= (int*)  alloc((size_t)kBT * 2 * 4);
  float* aux   = (float*)alloc(256);
  size_t off_shared = off;

  // fast-path buffers
  u16*   xnP   = (u16*)  alloc((size_t)3 * PLN_XN * 2);
  float* qkvf  = (float*)alloc((size_t)kBT * 3 * kD * 4);
  float* of    = (float*)alloc((size_t)kBT * kD * 4);
  u16*   ofP   = (u16*)  alloc((size_t)3 * PLN_XN * 2);
  u16*   hP    = (u16*)  alloc((size_t)3 * PLN_H * 2);
  u16*   wqkvP = (u16*)  alloc((size_t)kL * 3 * PLN_QKV * 2);
  u16*   woP   = (u16*)  alloc((size_t)kL * 3 * PLN_WO * 2);
  u16*   f1P   = (u16*)  alloc((size_t)3 * PLN_FF * 2);   // reused per layer
  u16*   f2P   = (u16*)  alloc((size_t)3 * PLN_FF * 2);
  bool fast = (off <= ws_size);

  dim3 gProj(kBT / 128, kD / 128);     // (16,8)
  dim3 gQKV(kBT / 128, 3 * kD / 128);  // (16,24)
  dim3 gAttn(kT / 64, 2 * kH);         // (16,32)
  dim3 gF1(kSLOTS / 128, kFF / 128);   // (40,32)
  dim3 gF2(kSLOTS / 128, kD / 128);    // (40,8)
  dim3 gLM(kBT / 128, kV / 128);       // (16,250)

  if (fast) {
    // weight planes (small ones upfront)
    for (int li = 0; li < kL; ++li) {
      u16* dst = wqkvP + (size_t)li * 3 * PLN_QKV;
      split3_k<<<1024, 256, 0, stream>>>(wq + (size_t)li * kD * kD, dst, PLN_QKV, (long)kD * kD / 4);
      split3_k<<<1024, 256, 0, stream>>>(wk + (size_t)li * kD * kD, dst + (long)kD * kD, PLN_QKV, (long)kD * kD / 4);
      split3_k<<<1024, 256, 0, stream>>>(wv + (size_t)li * kD * kD, dst + (long)2 * kD * kD, PLN_QKV, (long)kD * kD / 4);
      split3_k<<<1024, 256, 0, stream>>>(wo + (size_t)li * kD * kD, woP + (size_t)li * 3 * PLN_WO, PLN_WO, (long)kD * kD / 4);
    }
    hipMemsetAsync(aux, 0, 4, stream);
    embed_rms_k<<<kBT, 256, 0, stream>>>(idx, wte, wpe, x);

    for (int li = 0; li < kL; ++li) {
      rmsnorm3_k<<<kBT, 256, 0, stream>>>(x, xnP, PLN_XN);
      gemm3f_bt_k<P_F32, false, false><<<gQKV, 256, 0, stream>>>(
          xnP, PLN_XN, wqkvP + (size_t)li * 3 * PLN_QKV, PLN_QKV,
          qkvf, 0, nullptr, nullptr, nullptr, 3 * kD, kD, kD, 0);
      attn_f32_k<<<gAttn, 256, 0, stream>>>(qkvf, qkvf + kD, qkvf + 2 * kD, of, 3 * kD);
      split3_k<<<2048, 256, 0, stream>>>(of, ofP, PLN_XN, PLN_XN / 4);
      gemm3f_bt_k<P_F32_RESID, false, false><<<gProj, 256, 0, stream>>>(
          ofP, PLN_XN, woP + (size_t)li * 3 * PLN_WO, PLN_WO,
          x, 0, x, nullptr, nullptr, kD, kD, kD, 0);
      rmsnorm3_k<<<kBT, 256, 0, stream>>>(x, xnP, PLN_XN);
      hipMemsetAsync(meta, 0, 64, stream);
      gate_topk_k<<<kBT, 256, 0, stream>>>(x, gate + (size_t)li * kE * kD,
                                           probs, top2e, top2w, counts);
      calc_offsets_k<<<1, 64, 0, stream>>>(counts, offs);
      hipMemsetAsync(rows, 0, (size_t)kSLOTS * 4, stream);
      fill_slots_k<<<kBT / 256, 256, 0, stream>>>(top2e, offs, cursors, rows, slotOf);
      size_t fd = (size_t)li * PLN_FF;
      if (li < 2) {
        split3_k<<<4096, 256, 0, stream>>>(f1 + fd, f1P, PLN_FF, PLN_FF / 4);
        split3_k<<<4096, 256, 0, stream>>>(f2 + fd, f2P, PLN_FF, PLN_FF / 4);
        gemm3f_bt_k<P_SPLIT3_RELU, true, true><<<gF1, 256, 0, stream>>>(
            xnP, PLN_XN, f1P, PLN_FF, hP, PLN_H, nullptr, rows, offs,
            kFF, kD, kD, (long)kFF * kD);
        gemm3f_bt_k<P_F32, false, true><<<gF2, 256, 0, stream>>>(
            hP, PLN_H, f2P, PLN_FF, outs, 0, nullptr, nullptr, offs,
            kD, kFF, kFF, (long)kD * kFF);
      } else {
        // last layer: nothing downstream is routing-sensitive -> single bf16
        gemm_bt_k<P_BF16_RELU, true, true><<<gF1, 256, 0, stream>>>(
            xnP, f1 + fd, hP, rows, offs, kFF, kD, kD, (long)kFF * kD);
        gemm_bt_k<P_F32, true, false><<<gF2, 256, 0, stream>>>(
            hP, f2 + fd, outs, nullptr, offs, kD, kFF, kFF, (long)kD * kFF);
      }
      moe_combine_k<<<kBT, 256, 0, stream>>>(x, outs, slotOf, top2w);
      aux_reduce_k<<<1, 256, 0, stream>>>(probs, aux);
    }
    cast_bf16_k<<<2048, 256, 0, stream>>>(x, xnP, PLN_XN / 4);
    gemm_bt_k<P_F32, false, false><<<gLM, 256, 0, stream>>>(
        xnP, lmh, out, nullptr, nullptr, kV, kD, kD, 0);
    write_aux_k<<<1, 64, 0, stream>>>(aux, out + (size_t)kBT * kV);
    return;
  }

  // ---------- fallback: round-2 f32 path ----------
  off = off_shared;
  float* xnf   = (float*)alloc((size_t)kBT * kD * 4);
  u16*   xnb   = (u16*)  alloc((size_t)kBT * kD * 2);
  float* qf    = (float*)alloc((size_t)kBT * kD * 4);
  float* kf    = (float*)alloc((size_t)kBT * kD * 4);
  float* vf    = (float*)alloc((size_t)kBT * kD * 4);
  float* off32 = (float*)alloc((size_t)kBT * kD * 4);
  float* hbuf  = (float*)alloc((size_t)kSLOTS * kFF * 4);
  u16* hbuf16 = (u16*)hbuf;

  hipMemsetAsync(aux, 0, 4, stream);
  embed_rms_k<<<kBT, 256, 0, stream>>>(idx, wte, wpe, x);
  for (int li = 0; li < kL; ++li) {
    size_t dd = (size_t)li * kD * kD;
    rmsnorm2_k<<<kBT, 256, 0, stream>>>(x, xnf, xnb);
    sgemm_bt_k<P_F32, false, false><<<gProj, 256, 0, stream>>>(
        xnf, wq + dd, qf, nullptr, nullptr, nullptr, kD, kD, kD, 0);
    sgemm_bt_k<P_F32, false, false><<<gProj, 256, 0, stream>>>(
        xnf, wk + dd, kf, nullptr, nullptr, nullptr, kD, kD, kD, 0);
    sgemm_bt_k<P_F32, false, false><<<gProj, 256, 0, stream>>>(
        xnf, wv + dd, vf, nullptr, nullptr, nullptr, kD, kD, kD, 0);
    attn_f32_k<<<gAttn, 256, 0, stream>>>(qf, kf, vf, off32, kD);
    sgemm_bt_k<P_F32_RESID, false, false><<<gProj, 256, 0, stream>>>(
        off32, wo + dd, x, x, nullptr, nullptr, kD, kD, kD, 0);
    rmsnorm2_k<<<kBT, 256, 0, stream>>>(x, xnf, xnb);
    hipMemsetAsync(meta, 0, 64, stream);
    gate_topk_k<<<kBT, 256, 0, stream>>>(x, gate + (size_t)li * kE * kD,
                                         probs, top2e, top2w, counts);
    calc_offsets_k<<<1, 64, 0, stream>>>(counts, offs);
    hipMemsetAsync(rows, 0, (size_t)kSLOTS * 4, stream);
    fill_slots_k<<<kBT / 256, 256, 0, stream>>>(top2e, offs, cursors, rows, slotOf);
    size_t fd = (size_t)li * kE * kFF * kD;
    if (li < 2) {
      sgemm_bt_k<P_F32_RELU, true, true><<<gF1, 256, 0, stream>>>(
          xnf, f1 + fd, hbuf, nullptr, rows, offs, kFF, kD, kD, (long)kFF * kD);
      sgemm_bt_k<P_F32, false, true><<<gF2, 256, 0, stream>>>(
          hbuf, f2 + fd, outs, nullptr, nullptr, offs, kD, kFF, kFF, (long)kD * kFF);
    } else {
      gemm_bt_k<P_BF16_RELU, true, true><<<gF1, 256, 0, stream>>>(
          xnb, f1 + fd, hbuf16, rows, offs, kFF, kD, kD, (long)kFF * kD);
      gemm_bt_k<P_F32, true, false><<<gF2, 256, 0, stream>>>(
          hbuf16, f2 + fd, outs, nullptr, offs, kD, kFF, kFF, (long)kD * kFF);
    }
    moe_combine_k<<<kBT, 256, 0, stream>>>(x, outs, slotOf, top2w);
    aux_reduce_k<<<1, 256, 0, stream>>>(probs, aux);
  }
  cast_bf16_k<<<2048, 256, 0, stream>>>(x, xnb, (long)kBT * kD / 4);
  gemm_bt_k<P_F32, false, false><<<gLM, 256, 0, stream>>>(
      xnb, lmh, out, nullptr, nullptr, kV, kD, kD, 0);
  write_aux_k<<<1, 64, 0, stream>>>(aux, out + (size_t)kBT * kV);
}

// Round 6
// 3064.859 us; speedup vs baseline: 1.8456x; 1.1250x over previous
//
#include <hip/hip_runtime.h>

typedef unsigned short u16;
typedef __attribute__((ext_vector_type(4))) float f32x4;
typedef __attribute__((ext_vector_type(8))) __bf16 bf16x8;
typedef __attribute__((ext_vector_type(8))) _Float16 f16x8;
typedef __attribute__((ext_vector_type(4))) unsigned short u16x4;
typedef __attribute__((ext_vector_type(8))) unsigned short u16x8;

constexpr int kT = 1024, kD = 1024, kH = 16, kHD = 64, kL = 3, kE = 8;
constexpr int kFF = 4096, kV = 32000, kBT = 2048, kSLOTS = 5120;

__device__ __forceinline__ u16 f2bf(float f) {
  union { float f; unsigned u; } v; v.f = f;
  unsigned r = v.u + 0x7FFFu + ((v.u >> 16) & 1u);   // RNE
  return (u16)(r >> 16);
}
__device__ __forceinline__ u16 f2h(float x) {
  _Float16 h = (_Float16)x;
  union { _Float16 h; u16 u; } v; v.h = h; return v.u;
}
__device__ __forceinline__ float h2f(u16 b) {
  union { u16 u; _Float16 h; } v; v.u = b; return (float)v.h;
}
// fp16 split-2: x = hi + 2^-11 * mid + O(2^-22 x)
__device__ __forceinline__ void split2h(float x, u16& h, u16& m) {
  _Float16 hh = (_Float16)x;
  union { _Float16 h; u16 u; } v; v.h = hh; h = v.u;
  float r = (x - (float)hh) * 2048.0f;
  union { _Float16 h; u16 u; } w; w.h = (_Float16)r; m = w.u;
}

__device__ __forceinline__ void ld_lds16(const void* g, void* l) {
  __builtin_amdgcn_global_load_lds((const __attribute__((address_space(1))) void*)g,
                                   (__attribute__((address_space(3))) void*)l, 16, 0, 0);
}

#define MFMA16(a, b, c) __builtin_amdgcn_mfma_f32_16x16x32_bf16(a, b, c, 0, 0, 0)
#define MFMAH(a, b, c)  __builtin_amdgcn_mfma_f32_16x16x32_f16(a, b, c, 0, 0, 0)

__device__ __forceinline__ float blockReduceSum256(float v) {
  #pragma unroll
  for (int m = 32; m >= 1; m >>= 1) v += __shfl_xor(v, m);
  __shared__ float sh_[4];
  int w = threadIdx.x >> 6;
  if ((threadIdx.x & 63) == 0) sh_[w] = v;
  __syncthreads();
  v = (sh_[0] + sh_[1]) + (sh_[2] + sh_[3]);
  __syncthreads();
  return v;
}

// ---------------- elementwise / small kernels ----------------

__global__ __launch_bounds__(256) void cast_bf16_k(const float* __restrict__ in,
                                                   u16* __restrict__ out, long n4) {
  long i = (long)blockIdx.x * 256 + threadIdx.x;
  long stride = (long)gridDim.x * 256;
  for (; i < n4; i += stride) {
    f32x4 v = ((const f32x4*)in)[i];
    u16x4 o; o[0] = f2bf(v[0]); o[1] = f2bf(v[1]); o[2] = f2bf(v[2]); o[3] = f2bf(v[3]);
    ((u16x4*)out)[i] = o;
  }
}

__global__ __launch_bounds__(256) void cast_h_k(const float* __restrict__ in,
                                                u16* __restrict__ out, long n4) {
  long i = (long)blockIdx.x * 256 + threadIdx.x;
  long stride = (long)gridDim.x * 256;
  for (; i < n4; i += stride) {
    f32x4 v = ((const f32x4*)in)[i];
    u16x4 o; o[0] = f2h(v[0]); o[1] = f2h(v[1]); o[2] = f2h(v[2]); o[3] = f2h(v[3]);
    ((u16x4*)out)[i] = o;
  }
}

// f32 -> 2 fp16 planes
__global__ __launch_bounds__(256) void split2h_k(const float* __restrict__ in,
    u16* __restrict__ out, long planeStride, long n4) {
  long i = (long)blockIdx.x * 256 + threadIdx.x;
  long stride = (long)gridDim.x * 256;
  u16* o1 = out + planeStride;
  for (; i < n4; i += stride) {
    f32x4 v = ((const f32x4*)in)[i];
    u16x4 a, b;
    #pragma unroll
    for (int j = 0; j < 4; ++j) {
      u16 h, m; split2h(v[j], h, m);
      a[j] = h; b[j] = m;
    }
    ((u16x4*)out)[i] = a; ((u16x4*)o1)[i] = b;
  }
}

__global__ __launch_bounds__(256) void embed_rms_k(const int* __restrict__ idx,
    const float* __restrict__ wte, const float* __restrict__ wpe, float* __restrict__ x) {
  int tok = blockIdx.x, t = threadIdx.x;
  int id = idx[tok];
  int tt = tok & (kT - 1);
  f32x4 a = ((const f32x4*)(wte + (long)id * kD))[t];
  f32x4 p = ((const f32x4*)(wpe + (long)tt * kD))[t];
  f32x4 vv = a + p;
  float ss = vv[0]*vv[0] + vv[1]*vv[1] + vv[2]*vv[2] + vv[3]*vv[3];
  ss = blockReduceSum256(ss);
  float sc = rsqrtf(ss * (1.0f / kD) + 1e-5f);
  vv *= sc;
  ((f32x4*)(x + (long)tok * kD))[t] = vv;
}

// rmsnorm -> f32 + bf16 (fallback path)
__global__ __launch_bounds__(256) void rmsnorm2_k(const float* __restrict__ x,
    float* __restrict__ xnf, u16* __restrict__ xnb) {
  int tok = blockIdx.x, t = threadIdx.x;
  f32x4 vv = ((const f32x4*)(x + (long)tok * kD))[t];
  float ss = blockReduceSum256(vv[0]*vv[0] + vv[1]*vv[1] + vv[2]*vv[2] + vv[3]*vv[3]);
  float sc = rsqrtf(ss * (1.0f / kD) + 1e-5f);
  vv *= sc;
  ((f32x4*)(xnf + (long)tok * kD))[t] = vv;
  u16x4 o;
  o[0] = f2bf(vv[0]); o[1] = f2bf(vv[1]); o[2] = f2bf(vv[2]); o[3] = f2bf(vv[3]);
  ((u16x4*)(xnb + (long)tok * kD))[t] = o;
}

// rmsnorm -> 2 fp16 planes (fast path)
__global__ __launch_bounds__(256) void rmsnorm2h_k(const float* __restrict__ x,
    u16* __restrict__ xnP, long plane) {
  int tok = blockIdx.x, t = threadIdx.x;
  f32x4 vv = ((const f32x4*)(x + (long)tok * kD))[t];
  float ss = blockReduceSum256(vv[0]*vv[0] + vv[1]*vv[1] + vv[2]*vv[2] + vv[3]*vv[3]);
  float sc = rsqrtf(ss * (1.0f / kD) + 1e-5f);
  vv *= sc;
  u16x4 a, b;
  #pragma unroll
  for (int j = 0; j < 4; ++j) {
    u16 h, m; split2h(vv[j], h, m);
    a[j] = h; b[j] = m;
  }
  long o = (long)tok * kD / 4 + t;
  ((u16x4*)xnP)[o] = a;
  ((u16x4*)(xnP + plane))[o] = b;
}

// gating in f32 (bf16 would flip top-2 selections on near-ties)
__global__ __launch_bounds__(256) void gate_topk_k(const float* __restrict__ x,
    const float* __restrict__ gate_l, float* __restrict__ probs, int* __restrict__ top2e,
    float* __restrict__ top2w, int* __restrict__ counts) {
  int tok = blockIdx.x, t = threadIdx.x;
  f32x4 xv = ((const f32x4*)(x + (long)tok * kD))[t];
  float ss = blockReduceSum256(xv[0]*xv[0] + xv[1]*xv[1] + xv[2]*xv[2] + xv[3]*xv[3]);
  float sc = rsqrtf(ss * (1.0f / kD) + 1e-5f);
  float a[kE];
  #pragma unroll
  for (int e = 0; e < kE; ++e) {
    f32x4 gv = ((const f32x4*)(gate_l + (long)e * kD))[t];
    a[e] = xv[0]*gv[0] + xv[1]*gv[1] + xv[2]*gv[2] + xv[3]*gv[3];
  }
  __shared__ float sh8[kE][4];
  int w = t >> 6, l = t & 63;
  #pragma unroll
  for (int e = 0; e < kE; ++e) {
    float v = a[e];
    #pragma unroll
    for (int m = 32; m >= 1; m >>= 1) v += __shfl_xor(v, m);
    if (l == 0) sh8[e][w] = v;
  }
  __syncthreads();
  if (t == 0) {
    float lg[kE], mx = -1e30f;
    #pragma unroll
    for (int e = 0; e < kE; ++e) {
      lg[e] = (sh8[e][0] + sh8[e][1] + sh8[e][2] + sh8[e][3]) * sc;
      mx = fmaxf(mx, lg[e]);
    }
    float pe[kE], s = 0.f;
    #pragma unroll
    for (int e = 0; e < kE; ++e) { pe[e] = __expf(lg[e] - mx); s += pe[e]; }
    float inv = 1.f / s;
    int i1 = 0;
    #pragma unroll
    for (int e = 1; e < kE; ++e) if (lg[e] > lg[i1]) i1 = e;
    int i2 = (i1 == 0) ? 1 : 0;
    #pragma unroll
    for (int e = 0; e < kE; ++e) if (e != i1 && lg[e] > lg[i2]) i2 = e;
    #pragma unroll
    for (int e = 0; e < kE; ++e) probs[(long)tok * kE + e] = pe[e] * inv;
    float p1 = pe[i1] * inv, p2 = pe[i2] * inv;
    float wn = p1 + p2;
    top2e[tok*2] = i1; top2e[tok*2+1] = i2;
    top2w[tok*2] = p1 / wn; top2w[tok*2+1] = p2 / wn;
    atomicAdd(&counts[i1], 1); atomicAdd(&counts[i2], 1);
  }
}

__global__ void calc_offsets_k(const int* __restrict__ counts, int* __restrict__ offsets) {
  if (threadIdx.x == 0) {
    int o = 0;
    #pragma unroll
    for (int e = 0; e < kE; ++e) { offsets[e] = o; o += (counts[e] + 127) & ~127; }
    offsets[kE] = o;
  }
}

__global__ __launch_bounds__(256) void fill_slots_k(const int* __restrict__ top2e,
    const int* __restrict__ offsets, int* __restrict__ cursors,
    int* __restrict__ rows, int* __restrict__ slotOf) {
  int tok = blockIdx.x * 256 + threadIdx.x;
  if (tok >= kBT) return;
  #pragma unroll
  for (int j = 0; j < 2; ++j) {
    int e = top2e[tok*2 + j];
    int pos = atomicAdd(&cursors[e], 1);
    int slot = offsets[e] + pos;
    rows[slot] = tok;
    slotOf[tok*2 + j] = slot;
  }
}

__global__ __launch_bounds__(256) void moe_combine_k(float* __restrict__ x,
    const float* __restrict__ outs, const int* __restrict__ slotOf,
    const float* __restrict__ top2w) {
  int tok = blockIdx.x, t = threadIdx.x;
  int s0 = slotOf[tok*2], s1 = slotOf[tok*2+1];
  float w0 = top2w[tok*2], w1 = top2w[tok*2+1];
  f32x4 a = ((const f32x4*)(outs + (long)s0 * kD))[t];
  f32x4 b = ((const f32x4*)(outs + (long)s1 * kD))[t];
  f32x4 xv = ((f32x4*)(x + (long)tok * kD))[t];
  xv += a * w0 + b * w1;
  ((f32x4*)(x + (long)tok * kD))[t] = xv;
}

__global__ __launch_bounds__(256) void aux_reduce_k(const float* __restrict__ probs,
                                                    float* __restrict__ aux) {
  int t = threadIdx.x;
  float part[kE] = {};
  for (int i = t; i < kBT; i += 256) {
    #pragma unroll
    for (int e = 0; e < kE; ++e) part[e] += probs[(long)i * kE + e];
  }
  __shared__ float sh8[kE][4];
  int w = t >> 6, l = t & 63;
  #pragma unroll
  for (int e = 0; e < kE; ++e) {
    float v = part[e];
    #pragma unroll
    for (int m = 32; m >= 1; m >>= 1) v += __shfl_xor(v, m);
    if (l == 0) sh8[e][w] = v;
  }
  __syncthreads();
  if (t == 0) {
    float acc = 0.f;
    #pragma unroll
    for (int e = 0; e < kE; ++e) {
      float frac = (sh8[e][0] + sh8[e][1] + sh8[e][2] + sh8[e][3]) * (1.0f / kBT);
      acc += frac * frac;
    }
    aux[0] += (float)kE * acc;
  }
}

__global__ void write_aux_k(const float* __restrict__ aux, float* __restrict__ out) {
  if (threadIdx.x == 0) out[0] = 0.01f * aux[0] / (float)kL;
}

enum { P_BF16 = 0, P_BF16_RELU = 1, P_F32 = 2, P_F32_RESID = 3, P_F32_RELU = 4,
       P_SPLIT2_RELU = 5, P_F16_RELU = 6 };

// ------- fused fp16 split-2 MFMA GEMM: C = Ah*Bh^T + (Ah*Bm^T + Am*Bh^T)/2048 -------
// BK=64, four 128x64 LDS tiles (64KB), 96 MFMA per barrier-pair.
// grid: x = n-block (fastest -> B panel reuse in L2), y = m-block.
// 8-chunk XOR swizzle via pre-swizzled global source (linear global_load_lds dest).

template <int POST, bool GATHER, bool EXPERT>
__global__ __launch_bounds__(256) void gemm2h_bt_k(
    const u16* __restrict__ A0, long planeA,
    const u16* __restrict__ B0, long planeB,
    void* __restrict__ C, long planeC,
    const float* __restrict__ resid,
    const int* __restrict__ rows, const int* __restrict__ offsets,
    int N, int K, int lda, long eBstride) {
  constexpr int BM = 128, BK = 64;
  int m0 = blockIdx.y * BM;
  int n0 = blockIdx.x * BM;
  if (EXPERT) {
    int total = offsets[kE];
    if (m0 >= total) return;
    int e = 0;
    while (offsets[e + 1] <= m0) ++e;
    B0 += (long)e * eBstride;
  }
  __shared__ __align__(16) u16 Ah[BM][BK];
  __shared__ __align__(16) u16 Am[BM][BK];
  __shared__ __align__(16) u16 Bh[BM][BK];
  __shared__ __align__(16) u16 Bm[BM][BK];
  int t = threadIdx.x;
  int l = t & 63, lr = l & 15, lg = l >> 4;
  int wid = t >> 6;
  int wm = (wid >> 1) * 64, wn = (wid & 1) * 64;

  long asrc[4], bsrc[4];
  int ldst[4];
  #pragma unroll
  for (int it = 0; it < 4; ++it) {
    int c = it * 256 + t;
    int row = c >> 3;
    int col = ((c ^ row) & 7) * 8;          // inverse-swizzled source column chunk
    int grow = GATHER ? rows[m0 + row] : (m0 + row);
    asrc[it] = (long)grow * lda + col;
    bsrc[it] = (long)(n0 + row) * K + col;
    ldst[it] = (it * 256 + (t & ~63)) * 8;  // linear dest, u16 units
  }

  f32x4 acc[4][4], acc1[4][4];
  #pragma unroll
  for (int i = 0; i < 4; ++i)
    #pragma unroll
    for (int j = 0; j < 4; ++j) { acc[i][j] = 0.f; acc1[i][j] = 0.f; }

  for (int k0 = 0; k0 < K; k0 += BK) {
    #pragma unroll
    for (int it = 0; it < 4; ++it) {
      ld_lds16(A0 + asrc[it] + k0,          &Ah[0][0] + ldst[it]);
      ld_lds16(A0 + planeA + asrc[it] + k0, &Am[0][0] + ldst[it]);
      ld_lds16(B0 + bsrc[it] + k0,          &Bh[0][0] + ldst[it]);
      ld_lds16(B0 + planeB + bsrc[it] + k0, &Bm[0][0] + ldst[it]);
    }
    __syncthreads();
    #pragma unroll
    for (int kk = 0; kk < 2; ++kk) {
      int swz = ((kk * 4 + lg) ^ (lr & 7)) * 8;   // swizzled read column
      f16x8 ah[4], am[4], bh[4], bm[4];
      #pragma unroll
      for (int i = 0; i < 4; ++i) {
        ah[i] = *(const f16x8*)&Ah[wm + i*16 + lr][swz];
        am[i] = *(const f16x8*)&Am[wm + i*16 + lr][swz];
      }
      #pragma unroll
      for (int j = 0; j < 4; ++j) {
        bh[j] = *(const f16x8*)&Bh[wn + j*16 + lr][swz];
        bm[j] = *(const f16x8*)&Bm[wn + j*16 + lr][swz];
      }
      #pragma unroll
      for (int i = 0; i < 4; ++i)
        #pragma unroll
        for (int j = 0; j < 4; ++j) {
          acc[i][j]  = MFMAH(ah[i], bh[j], acc[i][j]);
          acc1[i][j] = MFMAH(ah[i], bm[j], acc1[i][j]);
          acc1[i][j] = MFMAH(am[i], bh[j], acc1[i][j]);
        }
    }
    __syncthreads();
  }
  #pragma unroll
  for (int i = 0; i < 4; ++i) {
    #pragma unroll
    for (int r = 0; r < 4; ++r) {
      long m = m0 + wm + i*16 + lg*4 + r;
      #pragma unroll
      for (int j = 0; j < 4; ++j) {
        int n = n0 + wn + j*16 + lr;
        float val = acc[i][j][r] + acc1[i][j][r] * (1.0f / 2048.0f);
        if (POST == P_F32) {
          ((float*)C)[m * N + n] = val;
        } else if (POST == P_F32_RESID) {
          ((float*)C)[m * N + n] = val + resid[m * N + n];
        } else if (POST == P_SPLIT2_RELU) {
          val = fmaxf(val, 0.f);
          u16 h, mm; split2h(val, h, mm);
          u16* Cp = (u16*)C;
          Cp[m * N + n] = h;
          Cp[planeC + m * N + n] = mm;
        }
      }
    }
  }
}

// ---------------- single-plane MFMA GEMM (post-routing): B is f32, converted in staging ----
// HALF=true: A is fp16 bits, B converted to fp16; else bf16.

template <int POST, bool EXPERT, bool GATHER, bool HALF>
__global__ __launch_bounds__(256) void gemm_bt_k(
    const u16* __restrict__ A, const float* __restrict__ Bf, void* __restrict__ C,
    const int* __restrict__ rows, const int* __restrict__ offsets,
    int N, int K, int lda, long eBstride) {
  constexpr int BM = 128, BK = 64;
  int m0 = blockIdx.x * BM;
  int n0 = blockIdx.y * BM;
  if (EXPERT) {
    int total = offsets[kE];
    if (m0 >= total) return;
    int e = 0;
    while (offsets[e + 1] <= m0) ++e;
    Bf += (long)e * eBstride;
  }
  __shared__ __align__(16) u16 As[BM][BK];
  __shared__ __align__(16) u16 Bs[BM][BK + 8];
  int t = threadIdx.x;
  int l = t & 63, lr = l & 15, lg = l >> 4;
  int wid = t >> 6;
  int wm = (wid >> 1) * 64, wn = (wid & 1) * 64;

  long asrc[4];
  #pragma unroll
  for (int it = 0; it < 4; ++it) {
    int c = it * 256 + t;
    int row = c >> 3, col = (c & 7) * 8;
    int grow = GATHER ? rows[m0 + row] : (m0 + row);
    asrc[it] = (long)grow * lda + col;
  }
  f32x4 acc[4][4];
  #pragma unroll
  for (int i = 0; i < 4; ++i)
    #pragma unroll
    for (int j = 0; j < 4; ++j) acc[i][j] = 0.f;

  for (int k0 = 0; k0 < K; k0 += BK) {
    #pragma unroll
    for (int it = 0; it < 4; ++it)
      ld_lds16(A + asrc[it] + k0, &As[0][0] + (it * 256 + (t & ~63)) * 8);
    #pragma unroll
    for (int it = 0; it < 8; ++it) {
      int c = it * 256 + t;
      int row = c >> 4, col = (c & 15) * 4;
      f32x4 v = *(const f32x4*)(Bf + (long)(n0 + row) * K + k0 + col);
      u16x4 o;
      #pragma unroll
      for (int j = 0; j < 4; ++j) o[j] = HALF ? f2h(v[j]) : f2bf(v[j]);
      *(u16x4*)&Bs[row][col] = o;
    }
    __syncthreads();
    #pragma unroll
    for (int kk = 0; kk < 2; ++kk) {
      int kc = kk * 32 + lg * 8;
      #pragma unroll
      for (int i = 0; i < 4; ++i)
        #pragma unroll
        for (int j = 0; j < 4; ++j) {
          if (HALF) {
            f16x8 af = *(const f16x8*)&As[wm + i*16 + lr][kc];
            f16x8 bq = *(const f16x8*)&Bs[wn + j*16 + lr][kc];
            acc[i][j] = MFMAH(af, bq, acc[i][j]);
          } else {
            bf16x8 af = *(const bf16x8*)&As[wm + i*16 + lr][kc];
            bf16x8 bq = *(const bf16x8*)&Bs[wn + j*16 + lr][kc];
            acc[i][j] = MFMA16(af, bq, acc[i][j]);
          }
        }
    }
    __syncthreads();
  }
  #pragma unroll
  for (int i = 0; i < 4; ++i) {
    #pragma unroll
    for (int r = 0; r < 4; ++r) {
      long m = m0 + wm + i*16 + lg*4 + r;
      #pragma unroll
      for (int j = 0; j < 4; ++j) {
        int n = n0 + wn + j*16 + lr;
        float val = acc[i][j][r];
        if (POST == P_BF16_RELU)       ((u16*)C)[m * N + n] = f2bf(fmaxf(val, 0.f));
        else if (POST == P_F16_RELU)   ((u16*)C)[m * N + n] = f2h(fmaxf(val, 0.f));
        else if (POST == P_F32)        ((float*)C)[m * N + n] = val;
      }
    }
  }
}

// ---------------- f32 SGEMM (fallback path only) ----------------

template <int POST, bool GATHER, bool EXPERT>
__global__ __launch_bounds__(256) void sgemm_bt_k(
    const float* __restrict__ A, const float* __restrict__ B, float* __restrict__ C,
    const float* __restrict__ resid, const int* __restrict__ rows,
    const int* __restrict__ offsets, int N, int K, int lda, long eBstride) {
  constexpr int BM = 128, BN = 128, BK = 32;
  int m0 = blockIdx.x * BM, n0 = blockIdx.y * BN;
  if (EXPERT) {
    int total = offsets[kE];
    if (m0 >= total) return;
    int e = 0;
    while (offsets[e + 1] <= m0) ++e;
    B += (long)e * eBstride;
  }
  __shared__ float Ast[BK][BM];
  __shared__ float Bst[BK][BN];
  int t = threadIdx.x, tx = t & 15, ty = t >> 4;
  long asrc[4], bsrc[4];
  #pragma unroll
  for (int it = 0; it < 4; ++it) {
    int c = it * 256 + t;
    int row = c >> 3, kc = (c & 7) * 4;
    int gr = GATHER ? rows[m0 + row] : (m0 + row);
    asrc[it] = (long)gr * lda + kc;
    bsrc[it] = (long)(n0 + row) * K + kc;
  }
  f32x4 accv[8][2];
  #pragma unroll
  for (int i = 0; i < 8; ++i) { accv[i][0] = 0.f; accv[i][1] = 0.f; }

  for (int k0 = 0; k0 < K; k0 += BK) {
    #pragma unroll
    for (int it = 0; it < 4; ++it) {
      int c = it * 256 + t;
      int row = c >> 3, kc = (c & 7) * 4;
      f32x4 av = *(const f32x4*)(A + asrc[it] + k0);
      f32x4 bv = *(const f32x4*)(B + bsrc[it] + k0);
      #pragma unroll
      for (int j = 0; j < 4; ++j) { Ast[kc + j][row] = av[j]; Bst[kc + j][row] = bv[j]; }
    }
    __syncthreads();
    #pragma unroll
    for (int kk = 0; kk < BK; ++kk) {
      f32x4 a0 = *(const f32x4*)&Ast[kk][ty * 4];
      f32x4 a1 = *(const f32x4*)&Ast[kk][64 + ty * 4];
      f32x4 b0 = *(const f32x4*)&Bst[kk][tx * 4];
      f32x4 b1 = *(const f32x4*)&Bst[kk][64 + tx * 4];
      float as[8] = {a0[0], a0[1], a0[2], a0[3], a1[0], a1[1], a1[2], a1[3]};
      #pragma unroll
      for (int i = 0; i < 8; ++i) {
        accv[i][0] += b0 * as[i];
        accv[i][1] += b1 * as[i];
      }
    }
    __syncthreads();
  }
  #pragma unroll
  for (int ih = 0; ih < 2; ++ih)
    #pragma unroll
    for (int i = 0; i < 4; ++i) {
      long m = m0 + ih * 64 + ty * 4 + i;
      #pragma unroll
      for (int jh = 0; jh < 2; ++jh) {
        long n = n0 + jh * 64 + tx * 4;
        f32x4 val = accv[ih * 4 + i][jh];
        if (POST == P_F32_RELU) {
          #pragma unroll
          for (int j = 0; j < 4; ++j) val[j] = fmaxf(val[j], 0.f);
        }
        if (POST == P_F32_RESID) val += *(const f32x4*)&resid[m * N + n];
        *(f32x4*)&C[m * N + n] = val;
      }
    }
}

// ---------------- f32 causal flash attention (HD=64, 64-row Q tile) ----------------

__global__ __launch_bounds__(256) void attn_f32_k(const float* __restrict__ q,
    const float* __restrict__ k, const float* __restrict__ v, float* __restrict__ o,
    int ldq) {
  int qt = blockIdx.x;                 // q tile of 64
  int bh = blockIdx.y;                 // b*16+h
  int b = bh >> 4, h = bh & 15;
  long hbq = (long)b * kT * ldq + h * kHD;
  long hbo = (long)b * kT * kD + h * kHD;
  int t = threadIdx.x, qr = t >> 2, sub = t & 3;

  __shared__ float Qs[64][68], Ks[64][68], Vs[64][68], Ps[64][68];

  #pragma unroll
  for (int it = 0; it < 4; ++it) {
    int c = it * 256 + t, row = c >> 4, c4 = (c & 15) * 4;
    f32x4 qv = *(const f32x4*)(q + hbq + (long)(qt * 64 + row) * ldq + c4);
    #pragma unroll
    for (int j = 0; j < 4; ++j) Qs[row][c4 + j] = qv[j];
  }
  __syncthreads();
  f32x4 qreg[16];
  #pragma unroll
  for (int d4 = 0; d4 < 16; ++d4) qreg[d4] = *(const f32x4*)&Qs[qr][d4 * 4];
  int qg = qt * 64 + qr;

  float mrow = -1e30f, lsum = 0.f;
  f32x4 accO[4];
  #pragma unroll
  for (int i = 0; i < 4; ++i) accO[i] = 0.f;

  for (int itl = 0; itl <= qt; ++itl) {
    #pragma unroll
    for (int it = 0; it < 4; ++it) {
      int c = it * 256 + t, row = c >> 4, c4 = (c & 15) * 4;
      f32x4 kv = *(const f32x4*)(k + hbq + (long)(itl * 64 + row) * ldq + c4);
      f32x4 vv = *(const f32x4*)(v + hbq + (long)(itl * 64 + row) * ldq + c4);
      #pragma unroll
      for (int j = 0; j < 4; ++j) { Ks[row][c4 + j] = kv[j]; Vs[row][c4 + j] = vv[j]; }
    }
    __syncthreads();

    float s[16];
    #pragma unroll
    for (int kk = 0; kk < 16; ++kk) {
      int key = kk * 4 + sub;
      f32x4 a = {0.f, 0.f, 0.f, 0.f};
      #pragma unroll
      for (int d4 = 0; d4 < 16; ++d4) a += qreg[d4] * *(const f32x4*)&Ks[key][d4 * 4];
      float sv = (a[0] + a[1] + a[2] + a[3]) * 0.125f;
      if (itl * 64 + key > qg) sv = -1e30f;
      s[kk] = sv;
    }
    float mx = s[0];
    #pragma unroll
    for (int kk = 1; kk < 16; ++kk) mx = fmaxf(mx, s[kk]);
    mx = fmaxf(mx, __shfl_xor(mx, 1));
    mx = fmaxf(mx, __shfl_xor(mx, 2));
    float mi = fmaxf(mrow, mx);
    float alpha = __expf(mrow - mi);
    mrow = mi;
    float rs = 0.f;
    #pragma unroll
    for (int kk = 0; kk < 16; ++kk) {
      float p = __expf(s[kk] - mi);
      rs += p;
      Ps[qr][kk * 4 + sub] = p;
    }
    rs += __shfl_xor(rs, 1);
    rs += __shfl_xor(rs, 2);
    lsum = lsum * alpha + rs;
    #pragma unroll
    for (int i = 0; i < 4; ++i) accO[i] *= alpha;
    #pragma unroll
    for (int key2 = 0; key2 < 64; ++key2) {
      float p = Ps[qr][key2];
      #pragma unroll
      for (int i4 = 0; i4 < 4; ++i4)
        accO[i4] += p * *(const f32x4*)&Vs[key2][sub * 16 + i4 * 4];
    }
    __syncthreads();
  }
  float inv = 1.f / lsum;
  #pragma unroll
  for (int i4 = 0; i4 < 4; ++i4) {
    f32x4 ov = accO[i4] * inv;
    *(f32x4*)(o + hbo + (long)qg * kD + sub * 16 + i4 * 4) = ov;
  }
}

// ---------------- host ----------------

extern "C" void kernel_launch(void* const* d_in, const int* in_sizes, int n_in,
                              void* d_out, int out_size, void* d_ws, size_t ws_size,
                              hipStream_t stream) {
  const int*   idx  = (const int*)  d_in[0];
  const float* wte  = (const float*)d_in[1];
  const float* wpe  = (const float*)d_in[2];
  const float* wq   = (const float*)d_in[3];
  const float* wk   = (const float*)d_in[4];
  const float* wv   = (const float*)d_in[5];
  const float* wo   = (const float*)d_in[6];
  const float* gate = (const float*)d_in[7];
  const float* f1   = (const float*)d_in[8];
  const float* f2   = (const float*)d_in[9];
  const float* lmh  = (const float*)d_in[10];
  float* out = (float*)d_out;

  char* ws = (char*)d_ws;
  size_t off = 0;
  auto alloc = [&](size_t b) -> char* {
    char* p = ws + off;
    off += (b + 255) & ~(size_t)255;
    return p;
  };

  constexpr long PLN_XN = (long)kBT * kD;            // activation plane
  constexpr long PLN_QKV = (long)3 * kD * kD;        // fused qkv weight plane (per layer)
  constexpr long PLN_WO = (long)kD * kD;
  constexpr long PLN_FF = (long)kE * kFF * kD;       // f1/f2 plane (per layer)
  constexpr long PLN_H = (long)kSLOTS * kFF;

  // shared small buffers
  float* x     = (float*)alloc((size_t)kBT * kD * 4);
  float* outs  = (float*)alloc((size_t)kSLOTS * kD * 4);
  float* probs = (float*)alloc((size_t)kBT * kE * 4);
  int*   top2e = (int*)  alloc((size_t)kBT * 2 * 4);
  float* top2w = (float*)alloc((size_t)kBT * 2 * 4);
  int*   meta  = (int*)  alloc(64 * 4);
  int* counts = meta; int* cursors = meta + 8; int* offs = meta + 16;
  int*   rows  = (int*)  alloc((size_t)kSLOTS * 4);
  int*   slotOf= (int*)  alloc((size_t)kBT * 2 * 4);
  float* aux   = (float*)alloc(256);
  size_t off_shared = off;

  // fast-path buffers (2 fp16 planes each)
  u16*   xnP   = (u16*)  alloc((size_t)2 * PLN_XN * 2);
  float* qkvf  = (float*)alloc((size_t)kBT * 3 * kD * 4);
  float* of    = (float*)alloc((size_t)kBT * kD * 4);
  u16*   ofP   = (u16*)  alloc((size_t)2 * PLN_XN * 2);
  u16*   hP    = (u16*)  alloc((size_t)2 * PLN_H * 2);
  u16*   wqkvP = (u16*)  alloc((size_t)kL * 2 * PLN_QKV * 2);
  u16*   woP   = (u16*)  alloc((size_t)kL * 2 * PLN_WO * 2);
  u16*   f1P   = (u16*)  alloc((size_t)2 * PLN_FF * 2);   // reused per layer
  u16*   f2P   = (u16*)  alloc((size_t)2 * PLN_FF * 2);
  bool fast = (off <= ws_size);

  // fused GEMM grids: x = n (fastest, B-panel L2 reuse), y = m
  dim3 gProj(kD / 128, kBT / 128);     // (8,16)
  dim3 gQKV(3 * kD / 128, kBT / 128);  // (24,16)
  dim3 gAttn(kT / 64, 2 * kH);         // (16,32)
  dim3 gF1(kFF / 128, kSLOTS / 128);   // (32,40)
  dim3 gF2(kD / 128, kSLOTS / 128);    // (8,40)
  // single-plane GEMM grids keep x = m
  dim3 gF1s(kSLOTS / 128, kFF / 128);  // (40,32)
  dim3 gF2s(kSLOTS / 128, kD / 128);   // (40,8)
  dim3 gLM(kBT / 128, kV / 128);       // (16,250)

  if (fast) {
    for (int li = 0; li < kL; ++li) {
      u16* dst = wqkvP + (size_t)li * 2 * PLN_QKV;
      split2h_k<<<1024, 256, 0, stream>>>(wq + (size_t)li * kD * kD, dst, PLN_QKV, (long)kD * kD / 4);
      split2h_k<<<1024, 256, 0, stream>>>(wk + (size_t)li * kD * kD, dst + (long)kD * kD, PLN_QKV, (long)kD * kD / 4);
      split2h_k<<<1024, 256, 0, stream>>>(wv + (size_t)li * kD * kD, dst + (long)2 * kD * kD, PLN_QKV, (long)kD * kD / 4);
      split2h_k<<<1024, 256, 0, stream>>>(wo + (size_t)li * kD * kD, woP + (size_t)li * 2 * PLN_WO, PLN_WO, (long)kD * kD / 4);
    }
    hipMemsetAsync(aux, 0, 4, stream);
    embed_rms_k<<<kBT, 256, 0, stream>>>(idx, wte, wpe, x);

    for (int li = 0; li < kL; ++li) {
      rmsnorm2h_k<<<kBT, 256, 0, stream>>>(x, xnP, PLN_XN);
      gemm2h_bt_k<P_F32, false, false><<<gQKV, 256, 0, stream>>>(
          xnP, PLN_XN, wqkvP + (size_t)li * 2 * PLN_QKV, PLN_QKV,
          qkvf, 0, nullptr, nullptr, nullptr, 3 * kD, kD, kD, 0);
      attn_f32_k<<<gAttn, 256, 0, stream>>>(qkvf, qkvf + kD, qkvf + 2 * kD, of, 3 * kD);
      split2h_k<<<2048, 256, 0, stream>>>(of, ofP, PLN_XN, PLN_XN / 4);
      gemm2h_bt_k<P_F32_RESID, false, false><<<gProj, 256, 0, stream>>>(
          ofP, PLN_XN, woP + (size_t)li * 2 * PLN_WO, PLN_WO,
          x, 0, x, nullptr, nullptr, kD, kD, kD, 0);
      rmsnorm2h_k<<<kBT, 256, 0, stream>>>(x, xnP, PLN_XN);
      hipMemsetAsync(meta, 0, 64, stream);
      gate_topk_k<<<kBT, 256, 0, stream>>>(x, gate + (size_t)li * kE * kD,
                                           probs, top2e, top2w, counts);
      calc_offsets_k<<<1, 64, 0, stream>>>(counts, offs);
      hipMemsetAsync(rows, 0, (size_t)kSLOTS * 4, stream);
      fill_slots_k<<<kBT / 256, 256, 0, stream>>>(top2e, offs, cursors, rows, slotOf);
      size_t fd = (size_t)li * PLN_FF;
      if (li < 2) {
        split2h_k<<<4096, 256, 0, stream>>>(f1 + fd, f1P, PLN_FF, PLN_FF / 4);
        split2h_k<<<4096, 256, 0, stream>>>(f2 + fd, f2P, PLN_FF, PLN_FF / 4);
        gemm2h_bt_k<P_SPLIT2_RELU, true, true><<<gF1, 256, 0, stream>>>(
            xnP, PLN_XN, f1P, PLN_FF, hP, PLN_H, nullptr, rows, offs,
            kFF, kD, kD, (long)kFF * kD);
        gemm2h_bt_k<P_F32, false, true><<<gF2, 256, 0, stream>>>(
            hP, PLN_H, f2P, PLN_FF, outs, 0, nullptr, nullptr, offs,
            kD, kFF, kFF, (long)kD * kFF);
      } else {
        // last layer: nothing downstream is routing-sensitive -> single fp16 plane
        gemm_bt_k<P_F16_RELU, true, true, true><<<gF1s, 256, 0, stream>>>(
            xnP, f1 + fd, hP, rows, offs, kFF, kD, kD, (long)kFF * kD);
        gemm_bt_k<P_F32, true, false, true><<<gF2s, 256, 0, stream>>>(
            hP, f2 + fd, outs, nullptr, offs, kD, kFF, kFF, (long)kD * kFF);
      }
      moe_combine_k<<<kBT, 256, 0, stream>>>(x, outs, slotOf, top2w);
      aux_reduce_k<<<1, 256, 0, stream>>>(probs, aux);
    }
    cast_h_k<<<2048, 256, 0, stream>>>(x, xnP, PLN_XN / 4);
    gemm_bt_k<P_F32, false, false, true><<<gLM, 256, 0, stream>>>(
        xnP, lmh, out, nullptr, nullptr, kV, kD, kD, 0);
    write_aux_k<<<1, 64, 0, stream>>>(aux, out + (size_t)kBT * kV);
    return;
  }

  // ---------- fallback: round-2 f32 path ----------
  off = off_shared;
  float* xnf   = (float*)alloc((size_t)kBT * kD * 4);
  u16*   xnb   = (u16*)  alloc((size_t)kBT * kD * 2);
  float* qf    = (float*)alloc((size_t)kBT * kD * 4);
  float* kf    = (float*)alloc((size_t)kBT * kD * 4);
  float* vf    = (float*)alloc((size_t)kBT * kD * 4);
  float* off32 = (float*)alloc((size_t)kBT * kD * 4);
  float* hbuf  = (float*)alloc((size_t)kSLOTS * kFF * 4);
  u16* hbuf16 = (u16*)hbuf;

  hipMemsetAsync(aux, 0, 4, stream);
  embed_rms_k<<<kBT, 256, 0, stream>>>(idx, wte, wpe, x);
  for (int li = 0; li < kL; ++li) {
    size_t dd = (size_t)li * kD * kD;
    rmsnorm2_k<<<kBT, 256, 0, stream>>>(x, xnf, xnb);
    dim3 gP(kBT / 128, kD / 128);
    sgemm_bt_k<P_F32, false, false><<<gP, 256, 0, stream>>>(
        xnf, wq + dd, qf, nullptr, nullptr, nullptr, kD, kD, kD, 0);
    sgemm_bt_k<P_F32, false, false><<<gP, 256, 0, stream>>>(
        xnf, wk + dd, kf, nullptr, nullptr, nullptr, kD, kD, kD, 0);
    sgemm_bt_k<P_F32, false, false><<<gP, 256, 0, stream>>>(
        xnf, wv + dd, vf, nullptr, nullptr, nullptr, kD, kD, kD, 0);
    attn_f32_k<<<gAttn, 256, 0, stream>>>(qf, kf, vf, off32, kD);
    sgemm_bt_k<P_F32_RESID, false, false><<<gP, 256, 0, stream>>>(
        off32, wo + dd, x, x, nullptr, nullptr, kD, kD, kD, 0);
    rmsnorm2_k<<<kBT, 256, 0, stream>>>(x, xnf, xnb);
    hipMemsetAsync(meta, 0, 64, stream);
    gate_topk_k<<<kBT, 256, 0, stream>>>(x, gate + (size_t)li * kE * kD,
                                         probs, top2e, top2w, counts);
    calc_offsets_k<<<1, 64, 0, stream>>>(counts, offs);
    hipMemsetAsync(rows, 0, (size_t)kSLOTS * 4, stream);
    fill_slots_k<<<kBT / 256, 256, 0, stream>>>(top2e, offs, cursors, rows, slotOf);
    size_t fd = (size_t)li * kE * kFF * kD;
    if (li < 2) {
      sgemm_bt_k<P_F32_RELU, true, true><<<gF1s, 256, 0, stream>>>(
          xnf, f1 + fd, hbuf, nullptr, rows, offs, kFF, kD, kD, (long)kFF * kD);
      sgemm_bt_k<P_F32, false, true><<<gF2s, 256, 0, stream>>>(
          hbuf, f2 + fd, outs, nullptr, nullptr, offs, kD, kFF, kFF, (long)kD * kFF);
    } else {
      gemm_bt_k<P_BF16_RELU, true, true, false><<<gF1s, 256, 0, stream>>>(
          xnb, f1 + fd, hbuf16, rows, offs, kFF, kD, kD, (long)kFF * kD);
      gemm_bt_k<P_F32, true, false, false><<<gF2s, 256, 0, stream>>>(
          hbuf16, f2 + fd, outs, nullptr, offs, kD, kFF, kFF, (long)kD * kFF);
    }
    moe_combine_k<<<kBT, 256, 0, stream>>>(x, outs, slotOf, top2w);
    aux_reduce_k<<<1, 256, 0, stream>>>(probs, aux);
  }
  cast_bf16_k<<<2048, 256, 0, stream>>>(x, xnb, (long)kBT * kD / 4);
  gemm_bt_k<P_F32, false, false, false><<<gLM, 256, 0, stream>>>(
      xnb, lmh, out, nullptr, nullptr, kV, kD, kD, 0);
  write_aux_k<<<1, 64, 0, stream>>>(aux, out + (size_t)kBT * kV);
}

// Round 7
// 2731.771 us; speedup vs baseline: 2.0706x; 1.1219x over previous
//
#include <hip/hip_runtime.h>

typedef unsigned short u16;
typedef __attribute__((ext_vector_type(4))) float f32x4;
typedef __attribute__((ext_vector_type(8))) __bf16 bf16x8;
typedef __attribute__((ext_vector_type(8))) _Float16 f16x8;
typedef __attribute__((ext_vector_type(4))) unsigned short u16x4;
typedef __attribute__((ext_vector_type(8))) unsigned short u16x8;

constexpr int kT = 1024, kD = 1024, kH = 16, kHD = 64, kL = 3, kE = 8;
constexpr int kFF = 4096, kV = 32000, kBT = 2048, kSLOTS = 5120;

__device__ __forceinline__ u16 f2bf(float f) {
  union { float f; unsigned u; } v; v.f = f;
  unsigned r = v.u + 0x7FFFu + ((v.u >> 16) & 1u);   // RNE
  return (u16)(r >> 16);
}
__device__ __forceinline__ u16 f2h(float x) {
  _Float16 h = (_Float16)x;
  union { _Float16 h; u16 u; } v; v.h = h; return v.u;
}
// uniform-scale fp16 split-2: 64*x = hi + mid + O(2^-11 * |64x - hi|)
// both planes share scale 64; product of two planes carries scale 4096.
__device__ __forceinline__ void split2s(float x, u16& h, u16& m) {
  float xs = x * 64.0f;
  _Float16 hh = (_Float16)xs;
  union { _Float16 h; u16 u; } v; v.h = hh; h = v.u;
  float r = xs - (float)hh;
  union { _Float16 h; u16 u; } w; w.h = (_Float16)r; m = w.u;
}

__device__ __forceinline__ void ld_lds16(const void* g, void* l) {
  __builtin_amdgcn_global_load_lds((const __attribute__((address_space(1))) void*)g,
                                   (__attribute__((address_space(3))) void*)l, 16, 0, 0);
}

#define MFMA16(a, b, c) __builtin_amdgcn_mfma_f32_16x16x32_bf16(a, b, c, 0, 0, 0)
#define MFMAH(a, b, c)  __builtin_amdgcn_mfma_f32_16x16x32_f16(a, b, c, 0, 0, 0)

__device__ __forceinline__ float blockReduceSum256(float v) {
  #pragma unroll
  for (int m = 32; m >= 1; m >>= 1) v += __shfl_xor(v, m);
  __shared__ float sh_[4];
  int w = threadIdx.x >> 6;
  if ((threadIdx.x & 63) == 0) sh_[w] = v;
  __syncthreads();
  v = (sh_[0] + sh_[1]) + (sh_[2] + sh_[3]);
  __syncthreads();
  return v;
}

// ---------------- elementwise / small kernels ----------------

__global__ __launch_bounds__(256) void cast_bf16_k(const float* __restrict__ in,
                                                   u16* __restrict__ out, long n4) {
  long i = (long)blockIdx.x * 256 + threadIdx.x;
  long stride = (long)gridDim.x * 256;
  for (; i < n4; i += stride) {
    f32x4 v = ((const f32x4*)in)[i];
    u16x4 o; o[0] = f2bf(v[0]); o[1] = f2bf(v[1]); o[2] = f2bf(v[2]); o[3] = f2bf(v[3]);
    ((u16x4*)out)[i] = o;
  }
}

__global__ __launch_bounds__(256) void cast_h_k(const float* __restrict__ in,
                                                u16* __restrict__ out, long n4) {
  long i = (long)blockIdx.x * 256 + threadIdx.x;
  long stride = (long)gridDim.x * 256;
  for (; i < n4; i += stride) {
    f32x4 v = ((const f32x4*)in)[i];
    u16x4 o; o[0] = f2h(v[0]); o[1] = f2h(v[1]); o[2] = f2h(v[2]); o[3] = f2h(v[3]);
    ((u16x4*)out)[i] = o;
  }
}

// f32 -> 2 fp16 planes (uniform x64 scale)
__global__ __launch_bounds__(256) void split2h_k(const float* __restrict__ in,
    u16* __restrict__ out, long planeStride, long n4) {
  long i = (long)blockIdx.x * 256 + threadIdx.x;
  long stride = (long)gridDim.x * 256;
  u16* o1 = out + planeStride;
  for (; i < n4; i += stride) {
    f32x4 v = ((const f32x4*)in)[i];
    u16x4 a, b;
    #pragma unroll
    for (int j = 0; j < 4; ++j) {
      u16 h, m; split2s(v[j], h, m);
      a[j] = h; b[j] = m;
    }
    ((u16x4*)out)[i] = a; ((u16x4*)o1)[i] = b;
  }
}

__global__ __launch_bounds__(256) void embed_rms_k(const int* __restrict__ idx,
    const float* __restrict__ wte, const float* __restrict__ wpe, float* __restrict__ x) {
  int tok = blockIdx.x, t = threadIdx.x;
  int id = idx[tok];
  int tt = tok & (kT - 1);
  f32x4 a = ((const f32x4*)(wte + (long)id * kD))[t];
  f32x4 p = ((const f32x4*)(wpe + (long)tt * kD))[t];
  f32x4 vv = a + p;
  float ss = vv[0]*vv[0] + vv[1]*vv[1] + vv[2]*vv[2] + vv[3]*vv[3];
  ss = blockReduceSum256(ss);
  float sc = rsqrtf(ss * (1.0f / kD) + 1e-5f);
  vv *= sc;
  ((f32x4*)(x + (long)tok * kD))[t] = vv;
}

// rmsnorm -> f32 + bf16 (fallback path)
__global__ __launch_bounds__(256) void rmsnorm2_k(const float* __restrict__ x,
    float* __restrict__ xnf, u16* __restrict__ xnb) {
  int tok = blockIdx.x, t = threadIdx.x;
  f32x4 vv = ((const f32x4*)(x + (long)tok * kD))[t];
  float ss = blockReduceSum256(vv[0]*vv[0] + vv[1]*vv[1] + vv[2]*vv[2] + vv[3]*vv[3]);
  float sc = rsqrtf(ss * (1.0f / kD) + 1e-5f);
  vv *= sc;
  ((f32x4*)(xnf + (long)tok * kD))[t] = vv;
  u16x4 o;
  o[0] = f2bf(vv[0]); o[1] = f2bf(vv[1]); o[2] = f2bf(vv[2]); o[3] = f2bf(vv[3]);
  ((u16x4*)(xnb + (long)tok * kD))[t] = o;
}

// rmsnorm -> 2 fp16 planes (fast path, x64 scale)
__global__ __launch_bounds__(256) void rmsnorm2h_k(const float* __restrict__ x,
    u16* __restrict__ xnP, long plane) {
  int tok = blockIdx.x, t = threadIdx.x;
  f32x4 vv = ((const f32x4*)(x + (long)tok * kD))[t];
  float ss = blockReduceSum256(vv[0]*vv[0] + vv[1]*vv[1] + vv[2]*vv[2] + vv[3]*vv[3]);
  float sc = rsqrtf(ss * (1.0f / kD) + 1e-5f);
  vv *= sc;
  u16x4 a, b;
  #pragma unroll
  for (int j = 0; j < 4; ++j) {
    u16 h, m; split2s(vv[j], h, m);
    a[j] = h; b[j] = m;
  }
  long o = (long)tok * kD / 4 + t;
  ((u16x4*)xnP)[o] = a;
  ((u16x4*)(xnP + plane))[o] = b;
}

// gating in f32 (bf16 would flip top-2 selections on near-ties)
__global__ __launch_bounds__(256) void gate_topk_k(const float* __restrict__ x,
    const float* __restrict__ gate_l, float* __restrict__ probs, int* __restrict__ top2e,
    float* __restrict__ top2w, int* __restrict__ counts) {
  int tok = blockIdx.x, t = threadIdx.x;
  f32x4 xv = ((const f32x4*)(x + (long)tok * kD))[t];
  float ss = blockReduceSum256(xv[0]*xv[0] + xv[1]*xv[1] + xv[2]*xv[2] + xv[3]*xv[3]);
  float sc = rsqrtf(ss * (1.0f / kD) + 1e-5f);
  float a[kE];
  #pragma unroll
  for (int e = 0; e < kE; ++e) {
    f32x4 gv = ((const f32x4*)(gate_l + (long)e * kD))[t];
    a[e] = xv[0]*gv[0] + xv[1]*gv[1] + xv[2]*gv[2] + xv[3]*gv[3];
  }
  __shared__ float sh8[kE][4];
  int w = t >> 6, l = t & 63;
  #pragma unroll
  for (int e = 0; e < kE; ++e) {
    float v = a[e];
    #pragma unroll
    for (int m = 32; m >= 1; m >>= 1) v += __shfl_xor(v, m);
    if (l == 0) sh8[e][w] = v;
  }
  __syncthreads();
  if (t == 0) {
    float lg[kE], mx = -1e30f;
    #pragma unroll
    for (int e = 0; e < kE; ++e) {
      lg[e] = (sh8[e][0] + sh8[e][1] + sh8[e][2] + sh8[e][3]) * sc;
      mx = fmaxf(mx, lg[e]);
    }
    float pe[kE], s = 0.f;
    #pragma unroll
    for (int e = 0; e < kE; ++e) { pe[e] = __expf(lg[e] - mx); s += pe[e]; }
    float inv = 1.f / s;
    int i1 = 0;
    #pragma unroll
    for (int e = 1; e < kE; ++e) if (lg[e] > lg[i1]) i1 = e;
    int i2 = (i1 == 0) ? 1 : 0;
    #pragma unroll
    for (int e = 0; e < kE; ++e) if (e != i1 && lg[e] > lg[i2]) i2 = e;
    #pragma unroll
    for (int e = 0; e < kE; ++e) probs[(long)tok * kE + e] = pe[e] * inv;
    float p1 = pe[i1] * inv, p2 = pe[i2] * inv;
    float wn = p1 + p2;
    top2e[tok*2] = i1; top2e[tok*2+1] = i2;
    top2w[tok*2] = p1 / wn; top2w[tok*2+1] = p2 / wn;
    atomicAdd(&counts[i1], 1); atomicAdd(&counts[i2], 1);
  }
}

__global__ void calc_offsets_k(const int* __restrict__ counts, int* __restrict__ offsets) {
  if (threadIdx.x == 0) {
    int o = 0;
    #pragma unroll
    for (int e = 0; e < kE; ++e) { offsets[e] = o; o += (counts[e] + 127) & ~127; }
    offsets[kE] = o;
  }
}

__global__ __launch_bounds__(256) void fill_slots_k(const int* __restrict__ top2e,
    const int* __restrict__ offsets, int* __restrict__ cursors,
    int* __restrict__ rows, int* __restrict__ slotOf) {
  int tok = blockIdx.x * 256 + threadIdx.x;
  if (tok >= kBT) return;
  #pragma unroll
  for (int j = 0; j < 2; ++j) {
    int e = top2e[tok*2 + j];
    int pos = atomicAdd(&cursors[e], 1);
    int slot = offsets[e] + pos;
    rows[slot] = tok;
    slotOf[tok*2 + j] = slot;
  }
}

__global__ __launch_bounds__(256) void moe_combine_k(float* __restrict__ x,
    const float* __restrict__ outs, const int* __restrict__ slotOf,
    const float* __restrict__ top2w) {
  int tok = blockIdx.x, t = threadIdx.x;
  int s0 = slotOf[tok*2], s1 = slotOf[tok*2+1];
  float w0 = top2w[tok*2], w1 = top2w[tok*2+1];
  f32x4 a = ((const f32x4*)(outs + (long)s0 * kD))[t];
  f32x4 b = ((const f32x4*)(outs + (long)s1 * kD))[t];
  f32x4 xv = ((f32x4*)(x + (long)tok * kD))[t];
  xv += a * w0 + b * w1;
  ((f32x4*)(x + (long)tok * kD))[t] = xv;
}

__global__ __launch_bounds__(256) void aux_reduce_k(const float* __restrict__ probs,
                                                    float* __restrict__ aux) {
  int t = threadIdx.x;
  float part[kE] = {};
  for (int i = t; i < kBT; i += 256) {
    #pragma unroll
    for (int e = 0; e < kE; ++e) part[e] += probs[(long)i * kE + e];
  }
  __shared__ float sh8[kE][4];
  int w = t >> 6, l = t & 63;
  #pragma unroll
  for (int e = 0; e < kE; ++e) {
    float v = part[e];
    #pragma unroll
    for (int m = 32; m >= 1; m >>= 1) v += __shfl_xor(v, m);
    if (l == 0) sh8[e][w] = v;
  }
  __syncthreads();
  if (t == 0) {
    float acc = 0.f;
    #pragma unroll
    for (int e = 0; e < kE; ++e) {
      float frac = (sh8[e][0] + sh8[e][1] + sh8[e][2] + sh8[e][3]) * (1.0f / kBT);
      acc += frac * frac;
    }
    aux[0] += (float)kE * acc;
  }
}

__global__ void write_aux_k(const float* __restrict__ aux, float* __restrict__ out) {
  if (threadIdx.x == 0) out[0] = 0.01f * aux[0] / (float)kL;
}

enum { P_BF16 = 0, P_BF16_RELU = 1, P_F32 = 2, P_F32_RESID = 3, P_F32_RELU = 4,
       P_SPLIT2_RELU = 5, P_F16_RELU = 6 };

// ------- fused fp16 split-2 MFMA GEMM, single accumulator (uniform x64 planes) -------
// C = (Ah*Bh^T + Ah*Bm^T + Am*Bh^T) / 4096.
// BK=32; combined two-plane LDS tiles [128][64] (32KB total): row r holds
// hi chunks (logical 0-3) and mid chunks (logical 4-7), physically XOR-8
// swizzled: phys = logical ^ (r&7). Staged via per-lane pre-swizzled global
// source + linear global_load_lds dest (both-sides rule). 48 MFMA/barrier.
// grid: x = n-block (fastest -> B panel L2 reuse), y = m-block.

template <int POST, bool GATHER, bool EXPERT>
__global__ __launch_bounds__(256) void gemm2h_bt_k(
    const u16* __restrict__ A0, long planeA,
    const u16* __restrict__ B0, long planeB,
    void* __restrict__ C, long planeC,
    const float* __restrict__ resid,
    const int* __restrict__ rows, const int* __restrict__ offsets,
    int N, int K, int lda, long eBstride) {
  constexpr int BM = 128, BK = 32;
  int m0 = blockIdx.y * BM;
  int n0 = blockIdx.x * BM;
  if (EXPERT) {
    int total = offsets[kE];
    if (m0 >= total) return;
    int e = 0;
    while (offsets[e + 1] <= m0) ++e;
    B0 += (long)e * eBstride;
  }
  __shared__ __align__(16) u16 Ac[BM][64];
  __shared__ __align__(16) u16 Bc[BM][64];
  int t = threadIdx.x;
  int l = t & 63, lr = l & 15, lg = l >> 4;
  int wid = t >> 6;
  int wm = (wid >> 1) * 64, wn = (wid & 1) * 64;

  long asrc[4], bsrc[4];
  int ldst[4];
  #pragma unroll
  for (int it = 0; it < 4; ++it) {
    int d = it * 256 + t;                 // 16B-chunk index within tile
    int row = d >> 3, pc = d & 7;         // physical chunk
    int lc = pc ^ (row & 7);              // logical chunk (involution)
    int p = lc >> 2, c = lc & 3;          // plane, k-chunk
    int grow = GATHER ? rows[m0 + row] : (m0 + row);
    asrc[it] = (long)p * planeA + (long)grow * lda + c * 8;
    bsrc[it] = (long)p * planeB + (long)(n0 + row) * K + c * 8;
    ldst[it] = (it * 256 + (t & ~63)) * 8;   // linear dest, u16 units
  }
  int sa = lr & 7;
  int cH = (lg ^ sa) * 8;                 // hi-plane read col (u16 units)
  int cM = ((4 + lg) ^ sa) * 8;           // mid-plane read col

  f32x4 acc[4][4];
  #pragma unroll
  for (int i = 0; i < 4; ++i)
    #pragma unroll
    for (int j = 0; j < 4; ++j) acc[i][j] = 0.f;

  for (int k0 = 0; k0 < K; k0 += BK) {
    #pragma unroll
    for (int it = 0; it < 4; ++it) {
      ld_lds16(A0 + asrc[it] + k0, &Ac[0][0] + ldst[it]);
      ld_lds16(B0 + bsrc[it] + k0, &Bc[0][0] + ldst[it]);
    }
    __syncthreads();
    f16x8 ah[4], am[4];
    #pragma unroll
    for (int i = 0; i < 4; ++i) {
      ah[i] = *(const f16x8*)&Ac[wm + i*16 + lr][cH];
      am[i] = *(const f16x8*)&Ac[wm + i*16 + lr][cM];
    }
    #pragma unroll
    for (int j = 0; j < 4; ++j) {
      f16x8 bh = *(const f16x8*)&Bc[wn + j*16 + lr][cH];
      f16x8 bm = *(const f16x8*)&Bc[wn + j*16 + lr][cM];
      #pragma unroll
      for (int i = 0; i < 4; ++i) {
        acc[i][j] = MFMAH(ah[i], bh, acc[i][j]);
        acc[i][j] = MFMAH(am[i], bh, acc[i][j]);
        acc[i][j] = MFMAH(ah[i], bm, acc[i][j]);
      }
    }
    __syncthreads();
  }
  #pragma unroll
  for (int i = 0; i < 4; ++i) {
    #pragma unroll
    for (int r = 0; r < 4; ++r) {
      long m = m0 + wm + i*16 + lg*4 + r;
      #pragma unroll
      for (int j = 0; j < 4; ++j) {
        int n = n0 + wn + j*16 + lr;
        float val = acc[i][j][r] * (1.0f / 4096.0f);
        if (POST == P_F32) {
          ((float*)C)[m * N + n] = val;
        } else if (POST == P_F32_RESID) {
          ((float*)C)[m * N + n] = val + resid[m * N + n];
        } else if (POST == P_SPLIT2_RELU) {
          val = fmaxf(val, 0.f);
          u16 h, mm; split2s(val, h, mm);
          u16* Cp = (u16*)C;
          Cp[m * N + n] = h;
          Cp[planeC + m * N + n] = mm;
        }
      }
    }
  }
}

// ---------------- single-plane MFMA GEMM (post-routing): B is f32, converted in staging ----
// HALF=true: A is fp16 bits, B converted to fp16; else bf16. Output scaled by oscale.

template <int POST, bool EXPERT, bool GATHER, bool HALF>
__global__ __launch_bounds__(256) void gemm_bt_k(
    const u16* __restrict__ A, const float* __restrict__ Bf, void* __restrict__ C,
    const int* __restrict__ rows, const int* __restrict__ offsets,
    int N, int K, int lda, long eBstride, float oscale) {
  constexpr int BM = 128, BK = 64;
  int m0 = blockIdx.x * BM;
  int n0 = blockIdx.y * BM;
  if (EXPERT) {
    int total = offsets[kE];
    if (m0 >= total) return;
    int e = 0;
    while (offsets[e + 1] <= m0) ++e;
    Bf += (long)e * eBstride;
  }
  __shared__ __align__(16) u16 As[BM][BK];
  __shared__ __align__(16) u16 Bs[BM][BK + 8];
  int t = threadIdx.x;
  int l = t & 63, lr = l & 15, lg = l >> 4;
  int wid = t >> 6;
  int wm = (wid >> 1) * 64, wn = (wid & 1) * 64;

  long asrc[4];
  #pragma unroll
  for (int it = 0; it < 4; ++it) {
    int c = it * 256 + t;
    int row = c >> 3, col = (c & 7) * 8;
    int grow = GATHER ? rows[m0 + row] : (m0 + row);
    asrc[it] = (long)grow * lda + col;
  }
  f32x4 acc[4][4];
  #pragma unroll
  for (int i = 0; i < 4; ++i)
    #pragma unroll
    for (int j = 0; j < 4; ++j) acc[i][j] = 0.f;

  for (int k0 = 0; k0 < K; k0 += BK) {
    #pragma unroll
    for (int it = 0; it < 4; ++it)
      ld_lds16(A + asrc[it] + k0, &As[0][0] + (it * 256 + (t & ~63)) * 8);
    #pragma unroll
    for (int it = 0; it < 8; ++it) {
      int c = it * 256 + t;
      int row = c >> 4, col = (c & 15) * 4;
      f32x4 v = *(const f32x4*)(Bf + (long)(n0 + row) * K + k0 + col);
      u16x4 o;
      #pragma unroll
      for (int j = 0; j < 4; ++j) o[j] = HALF ? f2h(v[j]) : f2bf(v[j]);
      *(u16x4*)&Bs[row][col] = o;
    }
    __syncthreads();
    #pragma unroll
    for (int kk = 0; kk < 2; ++kk) {
      int kc = kk * 32 + lg * 8;
      #pragma unroll
      for (int i = 0; i < 4; ++i)
        #pragma unroll
        for (int j = 0; j < 4; ++j) {
          if (HALF) {
            f16x8 af = *(const f16x8*)&As[wm + i*16 + lr][kc];
            f16x8 bq = *(const f16x8*)&Bs[wn + j*16 + lr][kc];
            acc[i][j] = MFMAH(af, bq, acc[i][j]);
          } else {
            bf16x8 af = *(const bf16x8*)&As[wm + i*16 + lr][kc];
            bf16x8 bq = *(const bf16x8*)&Bs[wn + j*16 + lr][kc];
            acc[i][j] = MFMA16(af, bq, acc[i][j]);
          }
        }
    }
    __syncthreads();
  }
  #pragma unroll
  for (int i = 0; i < 4; ++i) {
    #pragma unroll
    for (int r = 0; r < 4; ++r) {
      long m = m0 + wm + i*16 + lg*4 + r;
      #pragma unroll
      for (int j = 0; j < 4; ++j) {
        int n = n0 + wn + j*16 + lr;
        float val = acc[i][j][r] * oscale;
        if (POST == P_BF16_RELU)       ((u16*)C)[m * N + n] = f2bf(fmaxf(val, 0.f));
        else if (POST == P_F16_RELU)   ((u16*)C)[m * N + n] = f2h(fmaxf(val, 0.f));
        else if (POST == P_F32)        ((float*)C)[m * N + n] = val;
      }
    }
  }
}

// ---------------- f32 SGEMM (fallback path only) ----------------

template <int POST, bool GATHER, bool EXPERT>
__global__ __launch_bounds__(256) void sgemm_bt_k(
    const float* __restrict__ A, const float* __restrict__ B, float* __restrict__ C,
    const float* __restrict__ resid, const int* __restrict__ rows,
    const int* __restrict__ offsets, int N, int K, int lda, long eBstride) {
  constexpr int BM = 128, BN = 128, BK = 32;
  int m0 = blockIdx.x * BM, n0 = blockIdx.y * BN;
  if (EXPERT) {
    int total = offsets[kE];
    if (m0 >= total) return;
    int e = 0;
    while (offsets[e + 1] <= m0) ++e;
    B += (long)e * eBstride;
  }
  __shared__ float Ast[BK][BM];
  __shared__ float Bst[BK][BN];
  int t = threadIdx.x, tx = t & 15, ty = t >> 4;
  long asrc[4], bsrc[4];
  #pragma unroll
  for (int it = 0; it < 4; ++it) {
    int c = it * 256 + t;
    int row = c >> 3, kc = (c & 7) * 4;
    int gr = GATHER ? rows[m0 + row] : (m0 + row);
    asrc[it] = (long)gr * lda + kc;
    bsrc[it] = (long)(n0 + row) * K + kc;
  }
  f32x4 accv[8][2];
  #pragma unroll
  for (int i = 0; i < 8; ++i) { accv[i][0] = 0.f; accv[i][1] = 0.f; }

  for (int k0 = 0; k0 < K; k0 += BK) {
    #pragma unroll
    for (int it = 0; it < 4; ++it) {
      int c = it * 256 + t;
      int row = c >> 3, kc = (c & 7) * 4;
      f32x4 av = *(const f32x4*)(A + asrc[it] + k0);
      f32x4 bv = *(const f32x4*)(B + bsrc[it] + k0);
      #pragma unroll
      for (int j = 0; j < 4; ++j) { Ast[kc + j][row] = av[j]; Bst[kc + j][row] = bv[j]; }
    }
    __syncthreads();
    #pragma unroll
    for (int kk = 0; kk < BK; ++kk) {
      f32x4 a0 = *(const f32x4*)&Ast[kk][ty * 4];
      f32x4 a1 = *(const f32x4*)&Ast[kk][64 + ty * 4];
      f32x4 b0 = *(const f32x4*)&Bst[kk][tx * 4];
      f32x4 b1 = *(const f32x4*)&Bst[kk][64 + tx * 4];
      float as[8] = {a0[0], a0[1], a0[2], a0[3], a1[0], a1[1], a1[2], a1[3]};
      #pragma unroll
      for (int i = 0; i < 8; ++i) {
        accv[i][0] += b0 * as[i];
        accv[i][1] += b1 * as[i];
      }
    }
    __syncthreads();
  }
  #pragma unroll
  for (int ih = 0; ih < 2; ++ih)
    #pragma unroll
    for (int i = 0; i < 4; ++i) {
      long m = m0 + ih * 64 + ty * 4 + i;
      #pragma unroll
      for (int jh = 0; jh < 2; ++jh) {
        long n = n0 + jh * 64 + tx * 4;
        f32x4 val = accv[ih * 4 + i][jh];
        if (POST == P_F32_RELU) {
          #pragma unroll
          for (int j = 0; j < 4; ++j) val[j] = fmaxf(val[j], 0.f);
        }
        if (POST == P_F32_RESID) val += *(const f32x4*)&resid[m * N + n];
        *(f32x4*)&C[m * N + n] = val;
      }
    }
}

// ---------------- f32 causal flash attention (HD=64, 64-row Q tile) ----------------

__global__ __launch_bounds__(256) void attn_f32_k(const float* __restrict__ q,
    const float* __restrict__ k, const float* __restrict__ v, float* __restrict__ o,
    int ldq) {
  int qt = blockIdx.x;                 // q tile of 64
  int bh = blockIdx.y;                 // b*16+h
  int b = bh >> 4, h = bh & 15;
  long hbq = (long)b * kT * ldq + h * kHD;
  long hbo = (long)b * kT * kD + h * kHD;
  int t = threadIdx.x, qr = t >> 2, sub = t & 3;

  __shared__ float Qs[64][68], Ks[64][68], Vs[64][68], Ps[64][68];

  #pragma unroll
  for (int it = 0; it < 4; ++it) {
    int c = it * 256 + t, row = c >> 4, c4 = (c & 15) * 4;
    f32x4 qv = *(const f32x4*)(q + hbq + (long)(qt * 64 + row) * ldq + c4);
    #pragma unroll
    for (int j = 0; j < 4; ++j) Qs[row][c4 + j] = qv[j];
  }
  __syncthreads();
  f32x4 qreg[16];
  #pragma unroll
  for (int d4 = 0; d4 < 16; ++d4) qreg[d4] = *(const f32x4*)&Qs[qr][d4 * 4];
  int qg = qt * 64 + qr;

  float mrow = -1e30f, lsum = 0.f;
  f32x4 accO[4];
  #pragma unroll
  for (int i = 0; i < 4; ++i) accO[i] = 0.f;

  for (int itl = 0; itl <= qt; ++itl) {
    #pragma unroll
    for (int it = 0; it < 4; ++it) {
      int c = it * 256 + t, row = c >> 4, c4 = (c & 15) * 4;
      f32x4 kv = *(const f32x4*)(k + hbq + (long)(itl * 64 + row) * ldq + c4);
      f32x4 vv = *(const f32x4*)(v + hbq + (long)(itl * 64 + row) * ldq + c4);
      #pragma unroll
      for (int j = 0; j < 4; ++j) { Ks[row][c4 + j] = kv[j]; Vs[row][c4 + j] = vv[j]; }
    }
    __syncthreads();

    float s[16];
    #pragma unroll
    for (int kk = 0; kk < 16; ++kk) {
      int key = kk * 4 + sub;
      f32x4 a = {0.f, 0.f, 0.f, 0.f};
      #pragma unroll
      for (int d4 = 0; d4 < 16; ++d4) a += qreg[d4] * *(const f32x4*)&Ks[key][d4 * 4];
      float sv = (a[0] + a[1] + a[2] + a[3]) * 0.125f;
      if (itl * 64 + key > qg) sv = -1e30f;
      s[kk] = sv;
    }
    float mx = s[0];
    #pragma unroll
    for (int kk = 1; kk < 16; ++kk) mx = fmaxf(mx, s[kk]);
    mx = fmaxf(mx, __shfl_xor(mx, 1));
    mx = fmaxf(mx, __shfl_xor(mx, 2));
    float mi = fmaxf(mrow, mx);
    float alpha = __expf(mrow - mi);
    mrow = mi;
    float rs = 0.f;
    #pragma unroll
    for (int kk = 0; kk < 16; ++kk) {
      float p = __expf(s[kk] - mi);
      rs += p;
      Ps[qr][kk * 4 + sub] = p;
    }
    rs += __shfl_xor(rs, 1);
    rs += __shfl_xor(rs, 2);
    lsum = lsum * alpha + rs;
    #pragma unroll
    for (int i = 0; i < 4; ++i) accO[i] *= alpha;
    #pragma unroll
    for (int key2 = 0; key2 < 64; ++key2) {
      float p = Ps[qr][key2];
      #pragma unroll
      for (int i4 = 0; i4 < 4; ++i4)
        accO[i4] += p * *(const f32x4*)&Vs[key2][sub * 16 + i4 * 4];
    }
    __syncthreads();
  }
  float inv = 1.f / lsum;
  #pragma unroll
  for (int i4 = 0; i4 < 4; ++i4) {
    f32x4 ov = accO[i4] * inv;
    *(f32x4*)(o + hbo + (long)qg * kD + sub * 16 + i4 * 4) = ov;
  }
}

// ---------------- host ----------------

extern "C" void kernel_launch(void* const* d_in, const int* in_sizes, int n_in,
                              void* d_out, int out_size, void* d_ws, size_t ws_size,
                              hipStream_t stream) {
  const int*   idx  = (const int*)  d_in[0];
  const float* wte  = (const float*)d_in[1];
  const float* wpe  = (const float*)d_in[2];
  const float* wq   = (const float*)d_in[3];
  const float* wk   = (const float*)d_in[4];
  const float* wv   = (const float*)d_in[5];
  const float* wo   = (const float*)d_in[6];
  const float* gate = (const float*)d_in[7];
  const float* f1   = (const float*)d_in[8];
  const float* f2   = (const float*)d_in[9];
  const float* lmh  = (const float*)d_in[10];
  float* out = (float*)d_out;

  char* ws = (char*)d_ws;
  size_t off = 0;
  auto alloc = [&](size_t b) -> char* {
    char* p = ws + off;
    off += (b + 255) & ~(size_t)255;
    return p;
  };

  constexpr long PLN_XN = (long)kBT * kD;            // activation plane
  constexpr long PLN_QKV = (long)3 * kD * kD;        // fused qkv weight plane (per layer)
  constexpr long PLN_WO = (long)kD * kD;
  constexpr long PLN_FF = (long)kE * kFF * kD;       // f1/f2 plane (per layer)
  constexpr long PLN_H = (long)kSLOTS * kFF;

  // shared small buffers
  float* x     = (float*)alloc((size_t)kBT * kD * 4);
  float* outs  = (float*)alloc((size_t)kSLOTS * kD * 4);
  float* probs = (float*)alloc((size_t)kBT * kE * 4);
  int*   top2e = (int*)  alloc((size_t)kBT * 2 * 4);
  float* top2w = (float*)alloc((size_t)kBT * 2 * 4);
  int*   meta  = (int*)  alloc(64 * 4);
  int* counts = meta; int* cursors = meta + 8; int* offs = meta + 16;
  int*   rows  = (int*)  alloc((size_t)kSLOTS * 4);
  int*   slotOf= (int*)  alloc((size_t)kBT * 2 * 4);
  float* aux   = (float*)alloc(256);
  size_t off_shared = off;

  // fast-path buffers (2 fp16 planes each)
  u16*   xnP   = (u16*)  alloc((size_t)2 * PLN_XN * 2);
  float* qkvf  = (float*)alloc((size_t)kBT * 3 * kD * 4);
  float* of    = (float*)alloc((size_t)kBT * kD * 4);
  u16*   ofP   = (u16*)  alloc((size_t)2 * PLN_XN * 2);
  u16*   hP    = (u16*)  alloc((size_t)2 * PLN_H * 2);
  u16*   wqkvP = (u16*)  alloc((size_t)kL * 2 * PLN_QKV * 2);
  u16*   woP   = (u16*)  alloc((size_t)kL * 2 * PLN_WO * 2);
  u16*   f1P   = (u16*)  alloc((size_t)2 * PLN_FF * 2);   // reused per layer
  u16*   f2P   = (u16*)  alloc((size_t)2 * PLN_FF * 2);
  bool fast = (off <= ws_size);

  // fused GEMM grids: x = n (fastest, B-panel L2 reuse), y = m
  dim3 gProj(kD / 128, kBT / 128);     // (8,16)
  dim3 gQKV(3 * kD / 128, kBT / 128);  // (24,16)
  dim3 gAttn(kT / 64, 2 * kH);         // (16,32)
  dim3 gF1(kFF / 128, kSLOTS / 128);   // (32,40)
  dim3 gF2(kD / 128, kSLOTS / 128);    // (8,40)
  // single-plane GEMM grids keep x = m
  dim3 gF1s(kSLOTS / 128, kFF / 128);  // (40,32)
  dim3 gF2s(kSLOTS / 128, kD / 128);   // (40,8)
  dim3 gLM(kBT / 128, kV / 128);       // (16,250)

  if (fast) {
    for (int li = 0; li < kL; ++li) {
      u16* dst = wqkvP + (size_t)li * 2 * PLN_QKV;
      split2h_k<<<1024, 256, 0, stream>>>(wq + (size_t)li * kD * kD, dst, PLN_QKV, (long)kD * kD / 4);
      split2h_k<<<1024, 256, 0, stream>>>(wk + (size_t)li * kD * kD, dst + (long)kD * kD, PLN_QKV, (long)kD * kD / 4);
      split2h_k<<<1024, 256, 0, stream>>>(wv + (size_t)li * kD * kD, dst + (long)2 * kD * kD, PLN_QKV, (long)kD * kD / 4);
      split2h_k<<<1024, 256, 0, stream>>>(wo + (size_t)li * kD * kD, woP + (size_t)li * 2 * PLN_WO, PLN_WO, (long)kD * kD / 4);
    }
    hipMemsetAsync(aux, 0, 4, stream);
    embed_rms_k<<<kBT, 256, 0, stream>>>(idx, wte, wpe, x);

    for (int li = 0; li < kL; ++li) {
      rmsnorm2h_k<<<kBT, 256, 0, stream>>>(x, xnP, PLN_XN);
      gemm2h_bt_k<P_F32, false, false><<<gQKV, 256, 0, stream>>>(
          xnP, PLN_XN, wqkvP + (size_t)li * 2 * PLN_QKV, PLN_QKV,
          qkvf, 0, nullptr, nullptr, nullptr, 3 * kD, kD, kD, 0);
      attn_f32_k<<<gAttn, 256, 0, stream>>>(qkvf, qkvf + kD, qkvf + 2 * kD, of, 3 * kD);
      split2h_k<<<2048, 256, 0, stream>>>(of, ofP, PLN_XN, PLN_XN / 4);
      gemm2h_bt_k<P_F32_RESID, false, false><<<gProj, 256, 0, stream>>>(
          ofP, PLN_XN, woP + (size_t)li * 2 * PLN_WO, PLN_WO,
          x, 0, x, nullptr, nullptr, kD, kD, kD, 0);
      rmsnorm2h_k<<<kBT, 256, 0, stream>>>(x, xnP, PLN_XN);
      hipMemsetAsync(meta, 0, 64, stream);
      gate_topk_k<<<kBT, 256, 0, stream>>>(x, gate + (size_t)li * kE * kD,
                                           probs, top2e, top2w, counts);
      calc_offsets_k<<<1, 64, 0, stream>>>(counts, offs);
      hipMemsetAsync(rows, 0, (size_t)kSLOTS * 4, stream);
      fill_slots_k<<<kBT / 256, 256, 0, stream>>>(top2e, offs, cursors, rows, slotOf);
      size_t fd = (size_t)li * PLN_FF;
      if (li < 2) {
        split2h_k<<<4096, 256, 0, stream>>>(f1 + fd, f1P, PLN_FF, PLN_FF / 4);
        split2h_k<<<4096, 256, 0, stream>>>(f2 + fd, f2P, PLN_FF, PLN_FF / 4);
        gemm2h_bt_k<P_SPLIT2_RELU, true, true><<<gF1, 256, 0, stream>>>(
            xnP, PLN_XN, f1P, PLN_FF, hP, PLN_H, nullptr, rows, offs,
            kFF, kD, kD, (long)kFF * kD);
        gemm2h_bt_k<P_F32, false, true><<<gF2, 256, 0, stream>>>(
            hP, PLN_H, f2P, PLN_FF, outs, 0, nullptr, nullptr, offs,
            kD, kFF, kFF, (long)kD * kFF);
      } else {
        // last layer: nothing downstream is routing-sensitive -> single fp16 plane
        // A = xnP hi-plane is f16(64*x) -> scale output by 1/64
        gemm_bt_k<P_F16_RELU, true, true, true><<<gF1s, 256, 0, stream>>>(
            xnP, f1 + fd, hP, rows, offs, kFF, kD, kD, (long)kFF * kD, 1.0f / 64.0f);
        gemm_bt_k<P_F32, true, false, true><<<gF2s, 256, 0, stream>>>(
            hP, f2 + fd, outs, nullptr, offs, kD, kFF, kFF, (long)kD * kFF, 1.0f);
      }
      moe_combine_k<<<kBT, 256, 0, stream>>>(x, outs, slotOf, top2w);
      aux_reduce_k<<<1, 256, 0, stream>>>(probs, aux);
    }
    cast_h_k<<<2048, 256, 0, stream>>>(x, xnP, PLN_XN / 4);
    gemm_bt_k<P_F32, false, false, true><<<gLM, 256, 0, stream>>>(
        xnP, lmh, out, nullptr, nullptr, kV, kD, kD, 0, 1.0f);
    write_aux_k<<<1, 64, 0, stream>>>(aux, out + (size_t)kBT * kV);
    return;
  }

  // ---------- fallback: round-2 f32 path ----------
  off = off_shared;
  float* xnf   = (float*)alloc((size_t)kBT * kD * 4);
  u16*   xnb   = (u16*)  alloc((size_t)kBT * kD * 2);
  float* qf    = (float*)alloc((size_t)kBT * kD * 4);
  float* kf    = (float*)alloc((size_t)kBT * kD * 4);
  float* vf    = (float*)alloc((size_t)kBT * kD * 4);
  float* off32 = (float*)alloc((size_t)kBT * kD * 4);
  float* hbuf  = (float*)alloc((size_t)kSLOTS * kFF * 4);
  u16* hbuf16 = (u16*)hbuf;

  hipMemsetAsync(aux, 0, 4, stream);
  embed_rms_k<<<kBT, 256, 0, stream>>>(idx, wte, wpe, x);
  for (int li = 0; li < kL; ++li) {
    size_t dd = (size_t)li * kD * kD;
    rmsnorm2_k<<<kBT, 256, 0, stream>>>(x, xnf, xnb);
    dim3 gP(kBT / 128, kD / 128);
    sgemm_bt_k<P_F32, false, false><<<gP, 256, 0, stream>>>(
        xnf, wq + dd, qf, nullptr, nullptr, nullptr, kD, kD, kD, 0);
    sgemm_bt_k<P_F32, false, false><<<gP, 256, 0, stream>>>(
        xnf, wk + dd, kf, nullptr, nullptr, nullptr, kD, kD, kD, 0);
    sgemm_bt_k<P_F32, false, false><<<gP, 256, 0, stream>>>(
        xnf, wv + dd, vf, nullptr, nullptr, nullptr, kD, kD, kD, 0);
    attn_f32_k<<<gAttn, 256, 0, stream>>>(qf, kf, vf, off32, kD);
    sgemm_bt_k<P_F32_RESID, false, false><<<gP, 256, 0, stream>>>(
        off32, wo + dd, x, x, nullptr, nullptr, kD, kD, kD, 0);
    rmsnorm2_k<<<kBT, 256, 0, stream>>>(x, xnf, xnb);
    hipMemsetAsync(meta, 0, 64, stream);
    gate_topk_k<<<kBT, 256, 0, stream>>>(x, gate + (size_t)li * kE * kD,
                                         probs, top2e, top2w, counts);
    calc_offsets_k<<<1, 64, 0, stream>>>(counts, offs);
    hipMemsetAsync(rows, 0, (size_t)kSLOTS * 4, stream);
    fill_slots_k<<<kBT / 256, 256, 0, stream>>>(top2e, offs, cursors, rows, slotOf);
    size_t fd = (size_t)li * kE * kFF * kD;
    if (li < 2) {
      sgemm_bt_k<P_F32_RELU, true, true><<<gF1s, 256, 0, stream>>>(
          xnf, f1 + fd, hbuf, nullptr, rows, offs, kFF, kD, kD, (long)kFF * kD);
      sgemm_bt_k<P_F32, false, true><<<gF2s, 256, 0, stream>>>(
          hbuf, f2 + fd, outs, nullptr, nullptr, offs, kD, kFF, kFF, (long)kD * kFF);
    } else {
      gemm_bt_k<P_BF16_RELU, true, true, false><<<gF1s, 256, 0, stream>>>(
          xnb, f1 + fd, hbuf16, rows, offs, kFF, kD, kD, (long)kFF * kD, 1.0f);
      gemm_bt_k<P_F32, true, false, false><<<gF2s, 256, 0, stream>>>(
          hbuf16, f2 + fd, outs, nullptr, offs, kD, kFF, kFF, (long)kD * kFF, 1.0f);
    }
    moe_combine_k<<<kBT, 256, 0, stream>>>(x, outs, slotOf, top2w);
    aux_reduce_k<<<1, 256, 0, stream>>>(probs, aux);
  }
  cast_bf16_k<<<2048, 256, 0, stream>>>(x, xnb, (long)kBT * kD / 4);
  gemm_bt_k<P_F32, false, false, false><<<gLM, 256, 0, stream>>>(
      xnb, lmh, out, nullptr, nullptr, kV, kD, kD, 0, 1.0f);
  write_aux_k<<<1, 64, 0, stream>>>(aux, out + (size_t)kBT * kV);
}

// Round 8
// 2728.983 us; speedup vs baseline: 2.0727x; 1.0010x over previous
//
#include <hip/hip_runtime.h>

typedef unsigned short u16;
typedef __attribute__((ext_vector_type(4))) float f32x4;
typedef __attribute__((ext_vector_type(8))) __bf16 bf16x8;
typedef __attribute__((ext_vector_type(8))) _Float16 f16x8;
typedef __attribute__((ext_vector_type(4))) unsigned short u16x4;
typedef __attribute__((ext_vector_type(8))) unsigned short u16x8;

constexpr int kT = 1024, kD = 1024, kH = 16, kHD = 64, kL = 3, kE = 8;
constexpr int kFF = 4096, kV = 32000, kBT = 2048, kSLOTS = 5120;

__device__ __forceinline__ u16 f2bf(float f) {
  union { float f; unsigned u; } v; v.f = f;
  unsigned r = v.u + 0x7FFFu + ((v.u >> 16) & 1u);   // RNE
  return (u16)(r >> 16);
}
__device__ __forceinline__ u16 f2h(float x) {
  _Float16 h = (_Float16)x;
  union { _Float16 h; u16 u; } v; v.h = h; return v.u;
}
// uniform-scale fp16 split-2: 64*x = hi + mid + O(2^-11 * |64x - hi|)
__device__ __forceinline__ void split2s(float x, u16& h, u16& m) {
  float xs = x * 64.0f;
  _Float16 hh = (_Float16)xs;
  union { _Float16 h; u16 u; } v; v.h = hh; h = v.u;
  float r = xs - (float)hh;
  union { _Float16 h; u16 u; } w; w.h = (_Float16)r; m = w.u;
}

__device__ __forceinline__ void ld_lds16(const void* g, void* l) {
  __builtin_amdgcn_global_load_lds((const __attribute__((address_space(1))) void*)g,
                                   (__attribute__((address_space(3))) void*)l, 16, 0, 0);
}

// XCD-aware bijective block swizzle (requires nwg % 8 == 0)
__device__ __forceinline__ int xcd_swz(int lin, int nwg) {
  return (lin & 7) * (nwg >> 3) + (lin >> 3);
}

#define MFMA16(a, b, c) __builtin_amdgcn_mfma_f32_16x16x32_bf16(a, b, c, 0, 0, 0)
#define MFMAH(a, b, c)  __builtin_amdgcn_mfma_f32_16x16x32_f16(a, b, c, 0, 0, 0)

__device__ __forceinline__ float blockReduceSum256(float v) {
  #pragma unroll
  for (int m = 32; m >= 1; m >>= 1) v += __shfl_xor(v, m);
  __shared__ float sh_[4];
  int w = threadIdx.x >> 6;
  if ((threadIdx.x & 63) == 0) sh_[w] = v;
  __syncthreads();
  v = (sh_[0] + sh_[1]) + (sh_[2] + sh_[3]);
  __syncthreads();
  return v;
}

// ---------------- elementwise / small kernels ----------------

__global__ __launch_bounds__(256) void cast_bf16_k(const float* __restrict__ in,
                                                   u16* __restrict__ out, long n4) {
  long i = (long)blockIdx.x * 256 + threadIdx.x;
  long stride = (long)gridDim.x * 256;
  for (; i < n4; i += stride) {
    f32x4 v = ((const f32x4*)in)[i];
    u16x4 o; o[0] = f2bf(v[0]); o[1] = f2bf(v[1]); o[2] = f2bf(v[2]); o[3] = f2bf(v[3]);
    ((u16x4*)out)[i] = o;
  }
}

__global__ __launch_bounds__(256) void cast_h_k(const float* __restrict__ in,
                                                u16* __restrict__ out, long n4) {
  long i = (long)blockIdx.x * 256 + threadIdx.x;
  long stride = (long)gridDim.x * 256;
  for (; i < n4; i += stride) {
    f32x4 v = ((const f32x4*)in)[i];
    u16x4 o; o[0] = f2h(v[0]); o[1] = f2h(v[1]); o[2] = f2h(v[2]); o[3] = f2h(v[3]);
    ((u16x4*)out)[i] = o;
  }
}

// f32 -> 2 fp16 planes (uniform x64 scale)
__global__ __launch_bounds__(256) void split2h_k(const float* __restrict__ in,
    u16* __restrict__ out, long planeStride, long n4) {
  long i = (long)blockIdx.x * 256 + threadIdx.x;
  long stride = (long)gridDim.x * 256;
  u16* o1 = out + planeStride;
  for (; i < n4; i += stride) {
    f32x4 v = ((const f32x4*)in)[i];
    u16x4 a, b;
    #pragma unroll
    for (int j = 0; j < 4; ++j) {
      u16 h, m; split2s(v[j], h, m);
      a[j] = h; b[j] = m;
    }
    ((u16x4*)out)[i] = a; ((u16x4*)o1)[i] = b;
  }
}

__global__ __launch_bounds__(256) void embed_rms_k(const int* __restrict__ idx,
    const float* __restrict__ wte, const float* __restrict__ wpe, float* __restrict__ x) {
  int tok = blockIdx.x, t = threadIdx.x;
  int id = idx[tok];
  int tt = tok & (kT - 1);
  f32x4 a = ((const f32x4*)(wte + (long)id * kD))[t];
  f32x4 p = ((const f32x4*)(wpe + (long)tt * kD))[t];
  f32x4 vv = a + p;
  float ss = vv[0]*vv[0] + vv[1]*vv[1] + vv[2]*vv[2] + vv[3]*vv[3];
  ss = blockReduceSum256(ss);
  float sc = rsqrtf(ss * (1.0f / kD) + 1e-5f);
  vv *= sc;
  ((f32x4*)(x + (long)tok * kD))[t] = vv;
}

// rmsnorm -> f32 + bf16 (fallback path)
__global__ __launch_bounds__(256) void rmsnorm2_k(const float* __restrict__ x,
    float* __restrict__ xnf, u16* __restrict__ xnb) {
  int tok = blockIdx.x, t = threadIdx.x;
  f32x4 vv = ((const f32x4*)(x + (long)tok * kD))[t];
  float ss = blockReduceSum256(vv[0]*vv[0] + vv[1]*vv[1] + vv[2]*vv[2] + vv[3]*vv[3]);
  float sc = rsqrtf(ss * (1.0f / kD) + 1e-5f);
  vv *= sc;
  ((f32x4*)(xnf + (long)tok * kD))[t] = vv;
  u16x4 o;
  o[0] = f2bf(vv[0]); o[1] = f2bf(vv[1]); o[2] = f2bf(vv[2]); o[3] = f2bf(vv[3]);
  ((u16x4*)(xnb + (long)tok * kD))[t] = o;
}

// rmsnorm -> 2 fp16 planes (fast path, x64 scale)
__global__ __launch_bounds__(256) void rmsnorm2h_k(const float* __restrict__ x,
    u16* __restrict__ xnP, long plane) {
  int tok = blockIdx.x, t = threadIdx.x;
  f32x4 vv = ((const f32x4*)(x + (long)tok * kD))[t];
  float ss = blockReduceSum256(vv[0]*vv[0] + vv[1]*vv[1] + vv[2]*vv[2] + vv[3]*vv[3]);
  float sc = rsqrtf(ss * (1.0f / kD) + 1e-5f);
  vv *= sc;
  u16x4 a, b;
  #pragma unroll
  for (int j = 0; j < 4; ++j) {
    u16 h, m; split2s(vv[j], h, m);
    a[j] = h; b[j] = m;
  }
  long o = (long)tok * kD / 4 + t;
  ((u16x4*)xnP)[o] = a;
  ((u16x4*)(xnP + plane))[o] = b;
}

// gating in f32 (bf16 would flip top-2 selections on near-ties)
__global__ __launch_bounds__(256) void gate_topk_k(const float* __restrict__ x,
    const float* __restrict__ gate_l, float* __restrict__ probs, int* __restrict__ top2e,
    float* __restrict__ top2w, int* __restrict__ counts) {
  int tok = blockIdx.x, t = threadIdx.x;
  f32x4 xv = ((const f32x4*)(x + (long)tok * kD))[t];
  float ss = blockReduceSum256(xv[0]*xv[0] + xv[1]*xv[1] + xv[2]*xv[2] + xv[3]*xv[3]);
  float sc = rsqrtf(ss * (1.0f / kD) + 1e-5f);
  float a[kE];
  #pragma unroll
  for (int e = 0; e < kE; ++e) {
    f32x4 gv = ((const f32x4*)(gate_l + (long)e * kD))[t];
    a[e] = xv[0]*gv[0] + xv[1]*gv[1] + xv[2]*gv[2] + xv[3]*gv[3];
  }
  __shared__ float sh8[kE][4];
  int w = t >> 6, l = t & 63;
  #pragma unroll
  for (int e = 0; e < kE; ++e) {
    float v = a[e];
    #pragma unroll
    for (int m = 32; m >= 1; m >>= 1) v += __shfl_xor(v, m);
    if (l == 0) sh8[e][w] = v;
  }
  __syncthreads();
  if (t == 0) {
    float lg[kE], mx = -1e30f;
    #pragma unroll
    for (int e = 0; e < kE; ++e) {
      lg[e] = (sh8[e][0] + sh8[e][1] + sh8[e][2] + sh8[e][3]) * sc;
      mx = fmaxf(mx, lg[e]);
    }
    float pe[kE], s = 0.f;
    #pragma unroll
    for (int e = 0; e < kE; ++e) { pe[e] = __expf(lg[e] - mx); s += pe[e]; }
    float inv = 1.f / s;
    int i1 = 0;
    #pragma unroll
    for (int e = 1; e < kE; ++e) if (lg[e] > lg[i1]) i1 = e;
    int i2 = (i1 == 0) ? 1 : 0;
    #pragma unroll
    for (int e = 0; e < kE; ++e) if (e != i1 && lg[e] > lg[i2]) i2 = e;
    #pragma unroll
    for (int e = 0; e < kE; ++e) probs[(long)tok * kE + e] = pe[e] * inv;
    float p1 = pe[i1] * inv, p2 = pe[i2] * inv;
    float wn = p1 + p2;
    top2e[tok*2] = i1; top2e[tok*2+1] = i2;
    top2w[tok*2] = p1 / wn; top2w[tok*2+1] = p2 / wn;
    atomicAdd(&counts[i1], 1); atomicAdd(&counts[i2], 1);
  }
}

__global__ void calc_offsets_k(const int* __restrict__ counts, int* __restrict__ offsets) {
  if (threadIdx.x == 0) {
    int o = 0;
    #pragma unroll
    for (int e = 0; e < kE; ++e) { offsets[e] = o; o += (counts[e] + 127) & ~127; }
    offsets[kE] = o;
  }
}

__global__ __launch_bounds__(256) void fill_slots_k(const int* __restrict__ top2e,
    const int* __restrict__ offsets, int* __restrict__ cursors,
    int* __restrict__ rows, int* __restrict__ slotOf) {
  int tok = blockIdx.x * 256 + threadIdx.x;
  if (tok >= kBT) return;
  #pragma unroll
  for (int j = 0; j < 2; ++j) {
    int e = top2e[tok*2 + j];
    int pos = atomicAdd(&cursors[e], 1);
    int slot = offsets[e] + pos;
    rows[slot] = tok;
    slotOf[tok*2 + j] = slot;
  }
}

__global__ __launch_bounds__(256) void moe_combine_k(float* __restrict__ x,
    const float* __restrict__ outs, const int* __restrict__ slotOf,
    const float* __restrict__ top2w) {
  int tok = blockIdx.x, t = threadIdx.x;
  int s0 = slotOf[tok*2], s1 = slotOf[tok*2+1];
  float w0 = top2w[tok*2], w1 = top2w[tok*2+1];
  f32x4 a = ((const f32x4*)(outs + (long)s0 * kD))[t];
  f32x4 b = ((const f32x4*)(outs + (long)s1 * kD))[t];
  f32x4 xv = ((f32x4*)(x + (long)tok * kD))[t];
  xv += a * w0 + b * w1;
  ((f32x4*)(x + (long)tok * kD))[t] = xv;
}

__global__ __launch_bounds__(256) void aux_reduce_k(const float* __restrict__ probs,
                                                    float* __restrict__ aux) {
  int t = threadIdx.x;
  float part[kE] = {};
  for (int i = t; i < kBT; i += 256) {
    #pragma unroll
    for (int e = 0; e < kE; ++e) part[e] += probs[(long)i * kE + e];
  }
  __shared__ float sh8[kE][4];
  int w = t >> 6, l = t & 63;
  #pragma unroll
  for (int e = 0; e < kE; ++e) {
    float v = part[e];
    #pragma unroll
    for (int m = 32; m >= 1; m >>= 1) v += __shfl_xor(v, m);
    if (l == 0) sh8[e][w] = v;
  }
  __syncthreads();
  if (t == 0) {
    float acc = 0.f;
    #pragma unroll
    for (int e = 0; e < kE; ++e) {
      float frac = (sh8[e][0] + sh8[e][1] + sh8[e][2] + sh8[e][3]) * (1.0f / kBT);
      acc += frac * frac;
    }
    aux[0] += (float)kE * acc;
  }
}

__global__ void write_aux_k(const float* __restrict__ aux, float* __restrict__ out) {
  if (threadIdx.x == 0) out[0] = 0.01f * aux[0] / (float)kL;
}

enum { P_BF16 = 0, P_BF16_RELU = 1, P_F32 = 2, P_F32_RESID = 3, P_F32_RELU = 4,
       P_SPLIT2_RELU = 5, P_F16_RELU = 6 };

// ------- fused fp16 split-2 MFMA GEMM, single accumulator (uniform x64 planes) -------
// 1D grid + XCD swizzle; m-fastest within XCD chunk (B-panel reuse in per-XCD L2).

template <int POST, bool GATHER, bool EXPERT>
__global__ __launch_bounds__(256) void gemm2h_bt_k(
    const u16* __restrict__ A0, long planeA,
    const u16* __restrict__ B0, long planeB,
    void* __restrict__ C, long planeC,
    const float* __restrict__ resid,
    const int* __restrict__ rows, const int* __restrict__ offsets,
    int N, int K, int lda, long eBstride, int mBlocks) {
  constexpr int BM = 128, BK = 32;
  int swz = xcd_swz(blockIdx.x, gridDim.x);
  int m0 = (swz % mBlocks) * BM;
  int n0 = (swz / mBlocks) * BM;
  if (EXPERT) {
    int total = offsets[kE];
    if (m0 >= total) return;
    int e = 0;
    while (offsets[e + 1] <= m0) ++e;
    B0 += (long)e * eBstride;
  }
  __shared__ __align__(16) u16 Ac[BM][64];
  __shared__ __align__(16) u16 Bc[BM][64];
  int t = threadIdx.x;
  int l = t & 63, lr = l & 15, lg = l >> 4;
  int wid = t >> 6;
  int wm = (wid >> 1) * 64, wn = (wid & 1) * 64;

  long asrc[4], bsrc[4];
  int ldst[4];
  #pragma unroll
  for (int it = 0; it < 4; ++it) {
    int d = it * 256 + t;                 // 16B-chunk index within tile
    int row = d >> 3, pc = d & 7;         // physical chunk
    int lc = pc ^ (row & 7);              // logical chunk (involution)
    int p = lc >> 2, c = lc & 3;          // plane, k-chunk
    int grow = GATHER ? rows[m0 + row] : (m0 + row);
    asrc[it] = (long)p * planeA + (long)grow * lda + c * 8;
    bsrc[it] = (long)p * planeB + (long)(n0 + row) * K + c * 8;
    ldst[it] = (it * 256 + (t & ~63)) * 8;   // linear dest, u16 units
  }
  int sa = lr & 7;
  int cH = (lg ^ sa) * 8;                 // hi-plane read col (u16 units)
  int cM = ((4 + lg) ^ sa) * 8;           // mid-plane read col

  f32x4 acc[4][4];
  #pragma unroll
  for (int i = 0; i < 4; ++i)
    #pragma unroll
    for (int j = 0; j < 4; ++j) acc[i][j] = 0.f;

  for (int k0 = 0; k0 < K; k0 += BK) {
    #pragma unroll
    for (int it = 0; it < 4; ++it) {
      ld_lds16(A0 + asrc[it] + k0, &Ac[0][0] + ldst[it]);
      ld_lds16(B0 + bsrc[it] + k0, &Bc[0][0] + ldst[it]);
    }
    __syncthreads();
    f16x8 ah[4], am[4];
    #pragma unroll
    for (int i = 0; i < 4; ++i) {
      ah[i] = *(const f16x8*)&Ac[wm + i*16 + lr][cH];
      am[i] = *(const f16x8*)&Ac[wm + i*16 + lr][cM];
    }
    #pragma unroll
    for (int j = 0; j < 4; ++j) {
      f16x8 bh = *(const f16x8*)&Bc[wn + j*16 + lr][cH];
      f16x8 bm = *(const f16x8*)&Bc[wn + j*16 + lr][cM];
      #pragma unroll
      for (int i = 0; i < 4; ++i) {
        acc[i][j] = MFMAH(ah[i], bh, acc[i][j]);
        acc[i][j] = MFMAH(am[i], bh, acc[i][j]);
        acc[i][j] = MFMAH(ah[i], bm, acc[i][j]);
      }
    }
    __syncthreads();
  }
  #pragma unroll
  for (int i = 0; i < 4; ++i) {
    #pragma unroll
    for (int r = 0; r < 4; ++r) {
      long m = m0 + wm + i*16 + lg*4 + r;
      #pragma unroll
      for (int j = 0; j < 4; ++j) {
        int n = n0 + wn + j*16 + lr;
        float val = acc[i][j][r] * (1.0f / 4096.0f);
        if (POST == P_F32) {
          ((float*)C)[m * N + n] = val;
        } else if (POST == P_F32_RESID) {
          ((float*)C)[m * N + n] = val + resid[m * N + n];
        } else if (POST == P_SPLIT2_RELU) {
          val = fmaxf(val, 0.f);
          u16 h, mm; split2s(val, h, mm);
          u16* Cp = (u16*)C;
          Cp[m * N + n] = h;
          Cp[planeC + m * N + n] = mm;
        }
      }
    }
  }
}

// ---------------- single-plane MFMA GEMM ----------------
// HALF: f16 math (else bf16). BCONV: B is f32, converted in staging;
// else B is u16 (same dtype as A), staged via global_load_lds with XOR swizzle.
// 1D grid + XCD swizzle, m-fastest in chunk.

template <int POST, bool EXPERT, bool GATHER, bool HALF, bool BCONV>
__global__ __launch_bounds__(256) void gemm_bt_k(
    const u16* __restrict__ A, const void* __restrict__ Bv, void* __restrict__ C,
    const int* __restrict__ rows, const int* __restrict__ offsets,
    int N, int K, int lda, long eBstride, float oscale, int mBlocks) {
  constexpr int BM = 128, BK = 64;
  int swz = xcd_swz(blockIdx.x, gridDim.x);
  int m0 = (swz % mBlocks) * BM;
  int n0 = (swz / mBlocks) * BM;
  const float* Bf = (const float*)Bv;
  const u16*   Bh = (const u16*)Bv;
  if (EXPERT) {
    int total = offsets[kE];
    if (m0 >= total) return;
    int e = 0;
    while (offsets[e + 1] <= m0) ++e;
    if (BCONV) Bf += (long)e * eBstride; else Bh += (long)e * eBstride;
  }
  __shared__ __align__(16) u16 As[BM][BK];
  __shared__ __align__(16) u16 Bs[BM][BK + (BCONV ? 8 : 0)];
  int t = threadIdx.x;
  int l = t & 63, lr = l & 15, lg = l >> 4;
  int wid = t >> 6;
  int wm = (wid >> 1) * 64, wn = (wid & 1) * 64;

  long asrc[4], bsrc[4];
  int ldst[4];
  #pragma unroll
  for (int it = 0; it < 4; ++it) {
    int d = it * 256 + t;
    int row = d >> 3, pc = d & 7;
    int c = pc ^ (row & 7);               // XOR-8 pre-swizzled source chunk
    int grow = GATHER ? rows[m0 + row] : (m0 + row);
    asrc[it] = (long)grow * lda + c * 8;
    bsrc[it] = (long)(n0 + row) * K + c * 8;
    ldst[it] = (it * 256 + (t & ~63)) * 8;
  }
  f32x4 acc[4][4];
  #pragma unroll
  for (int i = 0; i < 4; ++i)
    #pragma unroll
    for (int j = 0; j < 4; ++j) acc[i][j] = 0.f;

  for (int k0 = 0; k0 < K; k0 += BK) {
    #pragma unroll
    for (int it = 0; it < 4; ++it)
      ld_lds16(A + asrc[it] + k0, &As[0][0] + ldst[it]);
    if (!BCONV) {
      #pragma unroll
      for (int it = 0; it < 4; ++it)
        ld_lds16(Bh + bsrc[it] + k0, &Bs[0][0] + ldst[it]);
    } else {
      #pragma unroll
      for (int it = 0; it < 8; ++it) {
        int c = it * 256 + t;
        int row = c >> 4, col = (c & 15) * 4;
        f32x4 v = *(const f32x4*)(Bf + (long)(n0 + row) * K + k0 + col);
        u16x4 o;
        #pragma unroll
        for (int j = 0; j < 4; ++j) o[j] = HALF ? f2h(v[j]) : f2bf(v[j]);
        *(u16x4*)&Bs[row][col] = o;
      }
    }
    __syncthreads();
    #pragma unroll
    for (int kk = 0; kk < 2; ++kk) {
      int ca = ((kk * 4 + lg) ^ (lr & 7)) * 8;        // swizzled A col
      int cb = BCONV ? (kk * 32 + lg * 8) : ca;       // B col
      #pragma unroll
      for (int i = 0; i < 4; ++i)
        #pragma unroll
        for (int j = 0; j < 4; ++j) {
          if (HALF) {
            f16x8 af = *(const f16x8*)&As[wm + i*16 + lr][ca];
            f16x8 bq = *(const f16x8*)&Bs[wn + j*16 + lr][cb];
            acc[i][j] = MFMAH(af, bq, acc[i][j]);
          } else {
            bf16x8 af = *(const bf16x8*)&As[wm + i*16 + lr][ca];
            bf16x8 bq = *(const bf16x8*)&Bs[wn + j*16 + lr][cb];
            acc[i][j] = MFMA16(af, bq, acc[i][j]);
          }
        }
    }
    __syncthreads();
  }
  #pragma unroll
  for (int i = 0; i < 4; ++i) {
    #pragma unroll
    for (int r = 0; r < 4; ++r) {
      long m = m0 + wm + i*16 + lg*4 + r;
      #pragma unroll
      for (int j = 0; j < 4; ++j) {
        int n = n0 + wn + j*16 + lr;
        float val = acc[i][j][r] * oscale;
        if (POST == P_BF16_RELU)       ((u16*)C)[m * N + n] = f2bf(fmaxf(val, 0.f));
        else if (POST == P_F16_RELU)   ((u16*)C)[m * N + n] = f2h(fmaxf(val, 0.f));
        else if (POST == P_F32)        ((float*)C)[m * N + n] = val;
      }
    }
  }
}

// ---------------- f32 SGEMM (fallback path only) ----------------

template <int POST, bool GATHER, bool EXPERT>
__global__ __launch_bounds__(256) void sgemm_bt_k(
    const float* __restrict__ A, const float* __restrict__ B, float* __restrict__ C,
    const float* __restrict__ resid, const int* __restrict__ rows,
    const int* __restrict__ offsets, int N, int K, int lda, long eBstride) {
  constexpr int BM = 128, BN = 128, BK = 32;
  int m0 = blockIdx.x * BM, n0 = blockIdx.y * BN;
  if (EXPERT) {
    int total = offsets[kE];
    if (m0 >= total) return;
    int e = 0;
    while (offsets[e + 1] <= m0) ++e;
    B += (long)e * eBstride;
  }
  __shared__ float Ast[BK][BM];
  __shared__ float Bst[BK][BN];
  int t = threadIdx.x, tx = t & 15, ty = t >> 4;
  long asrc[4], bsrc[4];
  #pragma unroll
  for (int it = 0; it < 4; ++it) {
    int c = it * 256 + t;
    int row = c >> 3, kc = (c & 7) * 4;
    int gr = GATHER ? rows[m0 + row] : (m0 + row);
    asrc[it] = (long)gr * lda + kc;
    bsrc[it] = (long)(n0 + row) * K + kc;
  }
  f32x4 accv[8][2];
  #pragma unroll
  for (int i = 0; i < 8; ++i) { accv[i][0] = 0.f; accv[i][1] = 0.f; }

  for (int k0 = 0; k0 < K; k0 += BK) {
    #pragma unroll
    for (int it = 0; it < 4; ++it) {
      int c = it * 256 + t;
      int row = c >> 3, kc = (c & 7) * 4;
      f32x4 av = *(const f32x4*)(A + asrc[it] + k0);
      f32x4 bv = *(const f32x4*)(B + bsrc[it] + k0);
      #pragma unroll
      for (int j = 0; j < 4; ++j) { Ast[kc + j][row] = av[j]; Bst[kc + j][row] = bv[j]; }
    }
    __syncthreads();
    #pragma unroll
    for (int kk = 0; kk < BK; ++kk) {
      f32x4 a0 = *(const f32x4*)&Ast[kk][ty * 4];
      f32x4 a1 = *(const f32x4*)&Ast[kk][64 + ty * 4];
      f32x4 b0 = *(const f32x4*)&Bst[kk][tx * 4];
      f32x4 b1 = *(const f32x4*)&Bst[kk][64 + tx * 4];
      float as[8] = {a0[0], a0[1], a0[2], a0[3], a1[0], a1[1], a1[2], a1[3]};
      #pragma unroll
      for (int i = 0; i < 8; ++i) {
        accv[i][0] += b0 * as[i];
        accv[i][1] += b1 * as[i];
      }
    }
    __syncthreads();
  }
  #pragma unroll
  for (int ih = 0; ih < 2; ++ih)
    #pragma unroll
    for (int i = 0; i < 4; ++i) {
      long m = m0 + ih * 64 + ty * 4 + i;
      #pragma unroll
      for (int jh = 0; jh < 2; ++jh) {
        long n = n0 + jh * 64 + tx * 4;
        f32x4 val = accv[ih * 4 + i][jh];
        if (POST == P_F32_RELU) {
          #pragma unroll
          for (int j = 0; j < 4; ++j) val[j] = fmaxf(val[j], 0.f);
        }
        if (POST == P_F32_RESID) val += *(const f32x4*)&resid[m * N + n];
        *(f32x4*)&C[m * N + n] = val;
      }
    }
}

// ---------------- f32 causal flash attention (HD=64, 64-row Q tile) ----------------

__global__ __launch_bounds__(256) void attn_f32_k(const float* __restrict__ q,
    const float* __restrict__ k, const float* __restrict__ v, float* __restrict__ o,
    int ldq) {
  int qt = blockIdx.x;                 // q tile of 64
  int bh = blockIdx.y;                 // b*16+h
  int b = bh >> 4, h = bh & 15;
  long hbq = (long)b * kT * ldq + h * kHD;
  long hbo = (long)b * kT * kD + h * kHD;
  int t = threadIdx.x, qr = t >> 2, sub = t & 3;

  __shared__ float Qs[64][68], Ks[64][68], Vs[64][68], Ps[64][68];

  #pragma unroll
  for (int it = 0; it < 4; ++it) {
    int c = it * 256 + t, row = c >> 4, c4 = (c & 15) * 4;
    f32x4 qv = *(const f32x4*)(q + hbq + (long)(qt * 64 + row) * ldq + c4);
    #pragma unroll
    for (int j = 0; j < 4; ++j) Qs[row][c4 + j] = qv[j];
  }
  __syncthreads();
  f32x4 qreg[16];
  #pragma unroll
  for (int d4 = 0; d4 < 16; ++d4) qreg[d4] = *(const f32x4*)&Qs[qr][d4 * 4];
  int qg = qt * 64 + qr;

  float mrow = -1e30f, lsum = 0.f;
  f32x4 accO[4];
  #pragma unroll
  for (int i = 0; i < 4; ++i) accO[i] = 0.f;

  for (int itl = 0; itl <= qt; ++itl) {
    #pragma unroll
    for (int it = 0; it < 4; ++it) {
      int c = it * 256 + t, row = c >> 4, c4 = (c & 15) * 4;
      f32x4 kv = *(const f32x4*)(k + hbq + (long)(itl * 64 + row) * ldq + c4);
      f32x4 vv = *(const f32x4*)(v + hbq + (long)(itl * 64 + row) * ldq + c4);
      #pragma unroll
      for (int j = 0; j < 4; ++j) { Ks[row][c4 + j] = kv[j]; Vs[row][c4 + j] = vv[j]; }
    }
    __syncthreads();

    float s[16];
    #pragma unroll
    for (int kk = 0; kk < 16; ++kk) {
      int key = kk * 4 + sub;
      f32x4 a = {0.f, 0.f, 0.f, 0.f};
      #pragma unroll
      for (int d4 = 0; d4 < 16; ++d4) a += qreg[d4] * *(const f32x4*)&Ks[key][d4 * 4];
      float sv = (a[0] + a[1] + a[2] + a[3]) * 0.125f;
      if (itl * 64 + key > qg) sv = -1e30f;
      s[kk] = sv;
    }
    float mx = s[0];
    #pragma unroll
    for (int kk = 1; kk < 16; ++kk) mx = fmaxf(mx, s[kk]);
    mx = fmaxf(mx, __shfl_xor(mx, 1));
    mx = fmaxf(mx, __shfl_xor(mx, 2));
    float mi = fmaxf(mrow, mx);
    float alpha = __expf(mrow - mi);
    mrow = mi;
    float rs = 0.f;
    #pragma unroll
    for (int kk = 0; kk < 16; ++kk) {
      float p = __expf(s[kk] - mi);
      rs += p;
      Ps[qr][kk * 4 + sub] = p;
    }
    rs += __shfl_xor(rs, 1);
    rs += __shfl_xor(rs, 2);
    lsum = lsum * alpha + rs;
    #pragma unroll
    for (int i = 0; i < 4; ++i) accO[i] *= alpha;
    #pragma unroll
    for (int key2 = 0; key2 < 64; ++key2) {
      float p = Ps[qr][key2];
      #pragma unroll
      for (int i4 = 0; i4 < 4; ++i4)
        accO[i4] += p * *(const f32x4*)&Vs[key2][sub * 16 + i4 * 4];
    }
    __syncthreads();
  }
  float inv = 1.f / lsum;
  #pragma unroll
  for (int i4 = 0; i4 < 4; ++i4) {
    f32x4 ov = accO[i4] * inv;
    *(f32x4*)(o + hbo + (long)qg * kD + sub * 16 + i4 * 4) = ov;
  }
}

// ---------------- host ----------------

extern "C" void kernel_launch(void* const* d_in, const int* in_sizes, int n_in,
                              void* d_out, int out_size, void* d_ws, size_t ws_size,
                              hipStream_t stream) {
  const int*   idx  = (const int*)  d_in[0];
  const float* wte  = (const float*)d_in[1];
  const float* wpe  = (const float*)d_in[2];
  const float* wq   = (const float*)d_in[3];
  const float* wk   = (const float*)d_in[4];
  const float* wv   = (const float*)d_in[5];
  const float* wo   = (const float*)d_in[6];
  const float* gate = (const float*)d_in[7];
  const float* f1   = (const float*)d_in[8];
  const float* f2   = (const float*)d_in[9];
  const float* lmh  = (const float*)d_in[10];
  float* out = (float*)d_out;

  char* ws = (char*)d_ws;
  size_t off = 0;
  auto alloc = [&](size_t b) -> char* {
    char* p = ws + off;
    off += (b + 255) & ~(size_t)255;
    return p;
  };

  constexpr long PLN_XN = (long)kBT * kD;
  constexpr long PLN_QKV = (long)3 * kD * kD;
  constexpr long PLN_WO = (long)kD * kD;
  constexpr long PLN_FF = (long)kE * kFF * kD;
  constexpr long PLN_H = (long)kSLOTS * kFF;

  // shared small buffers
  float* x     = (float*)alloc((size_t)kBT * kD * 4);
  float* outs  = (float*)alloc((size_t)kSLOTS * kD * 4);
  float* probs = (float*)alloc((size_t)kBT * kE * 4);
  int*   top2e = (int*)  alloc((size_t)kBT * 2 * 4);
  float* top2w = (float*)alloc((size_t)kBT * 2 * 4);
  int*   meta  = (int*)  alloc(64 * 4);
  int* counts = meta; int* cursors = meta + 8; int* offs = meta + 16;
  int*   rows  = (int*)  alloc((size_t)kSLOTS * 4);
  int*   slotOf= (int*)  alloc((size_t)kBT * 2 * 4);
  float* aux   = (float*)alloc(256);
  size_t off_shared = off;

  // fast-path buffers
  u16*   xnP   = (u16*)  alloc((size_t)2 * PLN_XN * 2);
  float* qkvf  = (float*)alloc((size_t)kBT * 3 * kD * 4);
  float* of    = (float*)alloc((size_t)kBT * kD * 4);
  u16*   ofP   = (u16*)  alloc((size_t)2 * PLN_XN * 2);
  u16*   hP    = (u16*)  alloc((size_t)2 * PLN_H * 2);
  u16*   wqkvP = (u16*)  alloc((size_t)kL * 2 * PLN_QKV * 2);
  u16*   woP   = (u16*)  alloc((size_t)kL * 2 * PLN_WO * 2);
  u16*   f1P   = (u16*)  alloc((size_t)2 * PLN_FF * 2);   // reused per layer
  u16*   f2P   = (u16*)  alloc((size_t)2 * PLN_FF * 2);
  u16*   lmb   = (u16*)  alloc((size_t)kV * kD * 2);      // f16 lm_head weights
  bool fast = (off <= ws_size);

  dim3 gAttn(kT / 64, 2 * kH);
  // 1D swizzled grids (all % 8 == 0)
  int nQKV = (kBT / 128) * (3 * kD / 128);     // 16*24 = 384, mB=16
  int nWO  = (kBT / 128) * (kD / 128);         // 16*8 = 128, mB=16
  int nF1  = (kSLOTS / 128) * (kFF / 128);     // 40*32 = 1280, mB=40
  int nF2  = (kSLOTS / 128) * (kD / 128);      // 40*8 = 320, mB=40
  int nLM  = (kBT / 128) * (kV / 128);         // 16*250 = 4000, mB=16

  if (fast) {
    for (int li = 0; li < kL; ++li) {
      u16* dst = wqkvP + (size_t)li * 2 * PLN_QKV;
      split2h_k<<<1024, 256, 0, stream>>>(wq + (size_t)li * kD * kD, dst, PLN_QKV, (long)kD * kD / 4);
      split2h_k<<<1024, 256, 0, stream>>>(wk + (size_t)li * kD * kD, dst + (long)kD * kD, PLN_QKV, (long)kD * kD / 4);
      split2h_k<<<1024, 256, 0, stream>>>(wv + (size_t)li * kD * kD, dst + (long)2 * kD * kD, PLN_QKV, (long)kD * kD / 4);
      split2h_k<<<1024, 256, 0, stream>>>(wo + (size_t)li * kD * kD, woP + (size_t)li * 2 * PLN_WO, PLN_WO, (long)kD * kD / 4);
    }
    cast_h_k<<<4096, 256, 0, stream>>>(lmh, lmb, (long)kV * kD / 4);
    hipMemsetAsync(aux, 0, 4, stream);
    embed_rms_k<<<kBT, 256, 0, stream>>>(idx, wte, wpe, x);

    for (int li = 0; li < kL; ++li) {
      rmsnorm2h_k<<<kBT, 256, 0, stream>>>(x, xnP, PLN_XN);
      gemm2h_bt_k<P_F32, false, false><<<nQKV, 256, 0, stream>>>(
          xnP, PLN_XN, wqkvP + (size_t)li * 2 * PLN_QKV, PLN_QKV,
          qkvf, 0, nullptr, nullptr, nullptr, 3 * kD, kD, kD, 0, kBT / 128);
      attn_f32_k<<<gAttn, 256, 0, stream>>>(qkvf, qkvf + kD, qkvf + 2 * kD, of, 3 * kD);
      split2h_k<<<2048, 256, 0, stream>>>(of, ofP, PLN_XN, PLN_XN / 4);
      gemm2h_bt_k<P_F32_RESID, false, false><<<nWO, 256, 0, stream>>>(
          ofP, PLN_XN, woP + (size_t)li * 2 * PLN_WO, PLN_WO,
          x, 0, x, nullptr, nullptr, kD, kD, kD, 0, kBT / 128);
      rmsnorm2h_k<<<kBT, 256, 0, stream>>>(x, xnP, PLN_XN);
      hipMemsetAsync(meta, 0, 64, stream);
      gate_topk_k<<<kBT, 256, 0, stream>>>(x, gate + (size_t)li * kE * kD,
                                           probs, top2e, top2w, counts);
      calc_offsets_k<<<1, 64, 0, stream>>>(counts, offs);
      hipMemsetAsync(rows, 0, (size_t)kSLOTS * 4, stream);
      fill_slots_k<<<kBT / 256, 256, 0, stream>>>(top2e, offs, cursors, rows, slotOf);
      size_t fd = (size_t)li * PLN_FF;
      if (li < 2) {
        split2h_k<<<4096, 256, 0, stream>>>(f1 + fd, f1P, PLN_FF, PLN_FF / 4);
        split2h_k<<<4096, 256, 0, stream>>>(f2 + fd, f2P, PLN_FF, PLN_FF / 4);
        gemm2h_bt_k<P_SPLIT2_RELU, true, true><<<nF1, 256, 0, stream>>>(
            xnP, PLN_XN, f1P, PLN_FF, hP, PLN_H, nullptr, rows, offs,
            kFF, kD, kD, (long)kFF * kD, kSLOTS / 128);
        gemm2h_bt_k<P_F32, false, true><<<nF2, 256, 0, stream>>>(
            hP, PLN_H, f2P, PLN_FF, outs, 0, nullptr, nullptr, offs,
            kD, kFF, kFF, (long)kD * kFF, kSLOTS / 128);
      } else {
        // last layer: single-f16 suffices; pre-convert weights, stage via lds
        cast_h_k<<<4096, 256, 0, stream>>>(f1 + fd, f1P, PLN_FF / 4);
        cast_h_k<<<4096, 256, 0, stream>>>(f2 + fd, f2P, PLN_FF / 4);
        gemm_bt_k<P_F16_RELU, true, true, true, false><<<nF1, 256, 0, stream>>>(
            xnP, f1P, hP, rows, offs, kFF, kD, kD, (long)kFF * kD,
            1.0f / 64.0f, kSLOTS / 128);
        gemm_bt_k<P_F32, true, false, true, false><<<nF2, 256, 0, stream>>>(
            hP, f2P, outs, nullptr, offs, kD, kFF, kFF, (long)kD * kFF,
            1.0f, kSLOTS / 128);
      }
      moe_combine_k<<<kBT, 256, 0, stream>>>(x, outs, slotOf, top2w);
      aux_reduce_k<<<1, 256, 0, stream>>>(probs, aux);
    }
    cast_h_k<<<2048, 256, 0, stream>>>(x, xnP, PLN_XN / 4);
    gemm_bt_k<P_F32, false, false, true, false><<<nLM, 256, 0, stream>>>(
        xnP, lmb, out, nullptr, nullptr, kV, kD, kD, 0, 1.0f, kBT / 128);
    write_aux_k<<<1, 64, 0, stream>>>(aux, out + (size_t)kBT * kV);
    return;
  }

  // ---------- fallback: f32 path ----------
  off = off_shared;
  float* xnf   = (float*)alloc((size_t)kBT * kD * 4);
  u16*   xnb   = (u16*)  alloc((size_t)kBT * kD * 2);
  float* qf    = (float*)alloc((size_t)kBT * kD * 4);
  float* kf    = (float*)alloc((size_t)kBT * kD * 4);
  float* vf    = (float*)alloc((size_t)kBT * kD * 4);
  float* off32 = (float*)alloc((size_t)kBT * kD * 4);
  float* hbuf  = (float*)alloc((size_t)kSLOTS * kFF * 4);
  u16* hbuf16 = (u16*)hbuf;

  hipMemsetAsync(aux, 0, 4, stream);
  embed_rms_k<<<kBT, 256, 0, stream>>>(idx, wte, wpe, x);
  dim3 gF1s(kSLOTS / 128, kFF / 128);
  dim3 gF2s(kSLOTS / 128, kD / 128);
  for (int li = 0; li < kL; ++li) {
    size_t dd = (size_t)li * kD * kD;
    rmsnorm2_k<<<kBT, 256, 0, stream>>>(x, xnf, xnb);
    dim3 gP(kBT / 128, kD / 128);
    sgemm_bt_k<P_F32, false, false><<<gP, 256, 0, stream>>>(
        xnf, wq + dd, qf, nullptr, nullptr, nullptr, kD, kD, kD, 0);
    sgemm_bt_k<P_F32, false, false><<<gP, 256, 0, stream>>>(
        xnf, wk + dd, kf, nullptr, nullptr, nullptr, kD, kD, kD, 0);
    sgemm_bt_k<P_F32, false, false><<<gP, 256, 0, stream>>>(
        xnf, wv + dd, vf, nullptr, nullptr, nullptr, kD, kD, kD, 0);
    attn_f32_k<<<gAttn, 256, 0, stream>>>(qf, kf, vf, off32, kD);
    sgemm_bt_k<P_F32_RESID, false, false><<<gP, 256, 0, stream>>>(
        off32, wo + dd, x, x, nullptr, nullptr, kD, kD, kD, 0);
    rmsnorm2_k<<<kBT, 256, 0, stream>>>(x, xnf, xnb);
    hipMemsetAsync(meta, 0, 64, stream);
    gate_topk_k<<<kBT, 256, 0, stream>>>(x, gate + (size_t)li * kE * kD,
                                         probs, top2e, top2w, counts);
    calc_offsets_k<<<1, 64, 0, stream>>>(counts, offs);
    hipMemsetAsync(rows, 0, (size_t)kSLOTS * 4, stream);
    fill_slots_k<<<kBT / 256, 256, 0, stream>>>(top2e, offs, cursors, rows, slotOf);
    size_t fd = (size_t)li * kE * kFF * kD;
    if (li < 2) {
      sgemm_bt_k<P_F32_RELU, true, true><<<gF1s, 256, 0, stream>>>(
          xnf, f1 + fd, hbuf, nullptr, rows, offs, kFF, kD, kD, (long)kFF * kD);
      sgemm_bt_k<P_F32, false, true><<<gF2s, 256, 0, stream>>>(
          hbuf, f2 + fd, outs, nullptr, nullptr, offs, kD, kFF, kFF, (long)kD * kFF);
    } else {
      gemm_bt_k<P_BF16_RELU, true, true, false, true><<<nF1, 256, 0, stream>>>(
          xnb, f1 + fd, hbuf16, rows, offs, kFF, kD, kD, (long)kFF * kD,
          1.0f, kSLOTS / 128);
      gemm_bt_k<P_F32, true, false, false, true><<<nF2, 256, 0, stream>>>(
          hbuf16, f2 + fd, outs, nullptr, offs, kD, kFF, kFF, (long)kD * kFF,
          1.0f, kSLOTS / 128);
    }
    moe_combine_k<<<kBT, 256, 0, stream>>>(x, outs, slotOf, top2w);
    aux_reduce_k<<<1, 256, 0, stream>>>(probs, aux);
  }
  cast_bf16_k<<<2048, 256, 0, stream>>>(x, xnb, (long)kBT * kD / 4);
  gemm_bt_k<P_F32, false, false, false, true><<<nLM, 256, 0, stream>>>(
      xnb, lmh, out, nullptr, nullptr, kV, kD, kD, 0, 1.0f, kBT / 128);
  write_aux_k<<<1, 64, 0, stream>>>(aux, out + (size_t)kBT * kV);
}